// Round 4
// baseline (518.534 us; speedup 1.0000x reference)
//
#include <hip/hip_runtime.h>
#include <hip/hip_bf16.h>

#define NN 50000
#define NE 600000
#define FD 128
#define NG 512
#define NC 10
static constexpr float EPS_BN = 1e-5f;

typedef __bf16 bf16x8 __attribute__((ext_vector_type(8)));
typedef float f32x4 __attribute__((ext_vector_type(4)));

__device__ __forceinline__ unsigned short f2bf(float x) {
  unsigned u = __float_as_uint(x);
  u = (u + 0x7FFFu + ((u >> 16) & 1u)) >> 16;
  return (unsigned short)u;
}
__device__ __forceinline__ float bf2f(unsigned short h) {
  return __uint_as_float(((unsigned)h) << 16);
}

// ---------------- degree ----------------
__global__ __launch_bounds__(256) void k_init_deg(float* __restrict__ deg) {
  int i = blockIdx.x * 256 + threadIdx.x;
  if (i < NN) deg[i] = 1.0f;   // self-loop
}

__global__ __launch_bounds__(256) void k_deg_scatter(const int* __restrict__ dst, float* __restrict__ deg) {
  int e = blockIdx.x * 256 + threadIdx.x;
  if (e < NE) unsafeAtomicAdd(&deg[dst[e]], 1.0f);
}

// ---------------- CSR build: multi-block exclusive scan of (deg-1) ----------------
#define NB 196   // ceil(50000/256)
__global__ __launch_bounds__(256) void k_bsum(const float* __restrict__ deg, int* __restrict__ bsum) {
  __shared__ int s[256];
  int t = threadIdx.x, i = blockIdx.x * 256 + t;
  s[t] = (i < NN) ? (int)deg[i] - 1 : 0;
  __syncthreads();
  for (int o = 128; o > 0; o >>= 1) { if (t < o) s[t] += s[t + o]; __syncthreads(); }
  if (t == 0) bsum[blockIdx.x] = s[0];
}

__global__ __launch_bounds__(256) void k_bscan(const int* __restrict__ bsum, int* __restrict__ bbase) {
  __shared__ int s[256];
  int t = threadIdx.x;
  int v = (t < NB) ? bsum[t] : 0;
  s[t] = v; __syncthreads();
  for (int o = 1; o < 256; o <<= 1) {
    int a = (t >= o) ? s[t - o] : 0; __syncthreads();
    s[t] += a; __syncthreads();
  }
  if (t < NB) bbase[t] = s[t] - v;
}

__global__ __launch_bounds__(256) void k_rowoff(const float* __restrict__ deg, const int* __restrict__ bbase,
                                                int* __restrict__ row_off, int* __restrict__ cursor) {
  __shared__ int s[256];
  int t = threadIdx.x, i = blockIdx.x * 256 + t;
  int c = (i < NN) ? (int)deg[i] - 1 : 0;
  s[t] = c; __syncthreads();
  for (int o = 1; o < 256; o <<= 1) {
    int a = (t >= o) ? s[t - o] : 0; __syncthreads();
    s[t] += a; __syncthreads();
  }
  int excl = s[t] - c + bbase[blockIdx.x];
  if (i <= NN) {
    row_off[i] = excl;
    if (i < NN) cursor[i] = excl;
  }
}

// csr entry: (src, norm) packed as int2; norm = rsqrt(deg[s]*deg[d])
__global__ __launch_bounds__(256) void k_fill(const int* __restrict__ src, const int* __restrict__ dst,
                                              const float* __restrict__ deg, int* __restrict__ cursor,
                                              int2* __restrict__ csr) {
  int e = blockIdx.x * 256 + threadIdx.x;
  if (e >= NE) return;
  int s = src[e], d = dst[e];
  float nrm = rsqrtf(deg[s] * deg[d]);
  int pos = atomicAdd(&cursor[d], 1);
  csr[pos] = make_int2(s, __float_as_int(nrm));
}

// ---------------- conversions fp32 -> bf16 hi/lo ----------------
__device__ __forceinline__ void cvt4(float4 v, ushort4* hp, ushort4* lp) {
  ushort4 hv, lv;
  hv.x = f2bf(v.x); lv.x = f2bf(v.x - bf2f(hv.x));
  hv.y = f2bf(v.y); lv.y = f2bf(v.y - bf2f(hv.y));
  hv.z = f2bf(v.z); lv.z = f2bf(v.z - bf2f(hv.z));
  hv.w = f2bf(v.w); lv.w = f2bf(v.w - bf2f(hv.w));
  *hp = hv; *lp = lv;
}

__global__ __launch_bounds__(256) void k_cvt_x(const float* __restrict__ x,
                                               unsigned short* __restrict__ xhi, unsigned short* __restrict__ xlo) {
  int i = blockIdx.x * 256 + threadIdx.x;
  if (i >= NN * FD / 4) return;
  float4 v = ((const float4*)x)[i];
  ushort4 hv, lv; cvt4(v, &hv, &lv);
  ((ushort4*)xhi)[i] = hv;
  ((ushort4*)xlo)[i] = lv;
}

__global__ __launch_bounds__(256) void k_cvt_w(const float* __restrict__ W1, const float* __restrict__ W2,
                                               const float* __restrict__ W3,
                                               unsigned short* __restrict__ whi, unsigned short* __restrict__ wlo) {
  int m = blockIdx.y;
  const float* W = (m == 0) ? W1 : ((m == 1) ? W2 : W3);
  int i = blockIdx.x * 256 + threadIdx.x;
  if (i >= FD * FD / 4) return;
  float4 v = ((const float4*)W)[i];
  ushort4 hv, lv; cvt4(v, &hv, &lv);
  ((ushort4*)(whi + m * FD * FD))[i] = hv;
  ((ushort4*)(wlo + m * FD * FD))[i] = lv;
}

// ---------------- MFMA GEMM: out[r][c] = sum_k in[r][k] * W[c][k] ----------------
__global__ __launch_bounds__(256) void k_gemm(const unsigned short* __restrict__ xhi,
                                              const unsigned short* __restrict__ xlo,
                                              const unsigned short* __restrict__ whi,
                                              const unsigned short* __restrict__ wlo,
                                              float* __restrict__ out) {
  int t = threadIdx.x;
  int w = t >> 6, l = t & 63;
  int rt = blockIdx.x * 4 + w;
  if (rt >= NN / 16) return;
  int row0 = rt * 16;
  int r = l & 15, g = l >> 4;
  int ko = g * 8;
  f32x4 acc[8];
#pragma unroll
  for (int ct = 0; ct < 8; ++ct) acc[ct] = (f32x4){0.f, 0.f, 0.f, 0.f};

#pragma unroll
  for (int kk = 0; kk < FD; kk += 32) {
    bf16x8 ah = *(const bf16x8*)(xhi + (size_t)(row0 + r) * FD + kk + ko);
    bf16x8 al = *(const bf16x8*)(xlo + (size_t)(row0 + r) * FD + kk + ko);
#pragma unroll
    for (int ct = 0; ct < 8; ++ct) {
      bf16x8 bh = *(const bf16x8*)(whi + (size_t)(ct * 16 + r) * FD + kk + ko);
      bf16x8 bl = *(const bf16x8*)(wlo + (size_t)(ct * 16 + r) * FD + kk + ko);
      acc[ct] = __builtin_amdgcn_mfma_f32_16x16x32_bf16(ah, bh, acc[ct], 0, 0, 0);
      acc[ct] = __builtin_amdgcn_mfma_f32_16x16x32_bf16(ah, bl, acc[ct], 0, 0, 0);
      acc[ct] = __builtin_amdgcn_mfma_f32_16x16x32_bf16(al, bh, acc[ct], 0, 0, 0);
    }
  }
#pragma unroll
  for (int ct = 0; ct < 8; ++ct)
#pragma unroll
    for (int i = 0; i < 4; ++i)
      out[(size_t)(row0 + g * 4 + i) * FD + ct * 16 + r] = acc[ct][i];
}

// ---------------- aggregation (gather, unroll-4) + fused BN partial stats ----------------
// out[n] = bias + h[n]/deg[n] + sum_j nrm_j * h[src_j];  8 nodes/block (exact: 6250*8=50000)
__global__ __launch_bounds__(256) void k_agg(const float* __restrict__ h, const float* __restrict__ deg,
                                             const float* __restrict__ bias, const int* __restrict__ row_off,
                                             const int2* __restrict__ csr, float* __restrict__ out,
                                             float* __restrict__ bnsum8, float* __restrict__ bnsq8,
                                             int do_stats) {
  __shared__ float ssum[FD], ssq[FD];
  int t = threadIdx.x;
  if (do_stats) {
    if (t < FD) { ssum[t] = 0.f; ssq[t] = 0.f; }
    __syncthreads();
  }
  int n = blockIdx.x * 8 + (t >> 5);
  int q = t & 31;
  const float4* h4 = (const float4*)h;
  float4 hv = h4[(size_t)n * 32 + q];
  float s2 = 1.0f / deg[n];
  float4 acc = ((const float4*)bias)[q];
  acc.x = fmaf(s2, hv.x, acc.x);
  acc.y = fmaf(s2, hv.y, acc.y);
  acc.z = fmaf(s2, hv.z, acc.z);
  acc.w = fmaf(s2, hv.w, acc.w);
  int lo = row_off[n], hi = row_off[n + 1];
  int j = lo;
  for (; j + 4 <= hi; j += 4) {
    int2 e0 = csr[j], e1 = csr[j + 1], e2 = csr[j + 2], e3 = csr[j + 3];
    float4 v0 = h4[(size_t)e0.x * 32 + q];
    float4 v1 = h4[(size_t)e1.x * 32 + q];
    float4 v2 = h4[(size_t)e2.x * 32 + q];
    float4 v3 = h4[(size_t)e3.x * 32 + q];
    float w0 = __int_as_float(e0.y), w1 = __int_as_float(e1.y);
    float w2 = __int_as_float(e2.y), w3 = __int_as_float(e3.y);
    acc.x = fmaf(w0, v0.x, acc.x); acc.y = fmaf(w0, v0.y, acc.y);
    acc.z = fmaf(w0, v0.z, acc.z); acc.w = fmaf(w0, v0.w, acc.w);
    acc.x = fmaf(w1, v1.x, acc.x); acc.y = fmaf(w1, v1.y, acc.y);
    acc.z = fmaf(w1, v1.z, acc.z); acc.w = fmaf(w1, v1.w, acc.w);
    acc.x = fmaf(w2, v2.x, acc.x); acc.y = fmaf(w2, v2.y, acc.y);
    acc.z = fmaf(w2, v2.z, acc.z); acc.w = fmaf(w2, v2.w, acc.w);
    acc.x = fmaf(w3, v3.x, acc.x); acc.y = fmaf(w3, v3.y, acc.y);
    acc.z = fmaf(w3, v3.z, acc.z); acc.w = fmaf(w3, v3.w, acc.w);
  }
  for (; j < hi; ++j) {
    int2 e = csr[j];
    float4 v = h4[(size_t)e.x * 32 + q];
    float w = __int_as_float(e.y);
    acc.x = fmaf(w, v.x, acc.x); acc.y = fmaf(w, v.y, acc.y);
    acc.z = fmaf(w, v.z, acc.z); acc.w = fmaf(w, v.w, acc.w);
  }
  ((float4*)out)[(size_t)n * 32 + q] = acc;

  if (do_stats) {
    int f = q * 4;
    atomicAdd(&ssum[f + 0], acc.x); atomicAdd(&ssum[f + 1], acc.y);
    atomicAdd(&ssum[f + 2], acc.z); atomicAdd(&ssum[f + 3], acc.w);
    atomicAdd(&ssq[f + 0], acc.x * acc.x); atomicAdd(&ssq[f + 1], acc.y * acc.y);
    atomicAdd(&ssq[f + 2], acc.z * acc.z); atomicAdd(&ssq[f + 3], acc.w * acc.w);
    __syncthreads();
    if (t < FD) {
      int c = (blockIdx.x & 7) * FD + t;
      unsafeAtomicAdd(&bnsum8[c], ssum[t]);
      unsafeAtomicAdd(&bnsq8[c], ssq[t]);
    }
  }
}

// ---------------- BN normalize + ReLU -> bf16 hi/lo (reads 8 replicated partials) ----------------
__global__ __launch_bounds__(256) void k_bn_apply_cvt(const float* __restrict__ h,
                                                      const float* __restrict__ bnsum8, const float* __restrict__ bnsq8,
                                                      unsigned short* __restrict__ xhi, unsigned short* __restrict__ xlo) {
  int i = blockIdx.x * 256 + threadIdx.x;
  if (i >= NN * FD / 4) return;
  int q = i & 31;
  float4 sm = make_float4(0.f, 0.f, 0.f, 0.f), sq = make_float4(0.f, 0.f, 0.f, 0.f);
#pragma unroll
  for (int c = 0; c < 8; ++c) {
    float4 a = ((const float4*)(bnsum8 + c * FD))[q];
    float4 b = ((const float4*)(bnsq8 + c * FD))[q];
    sm.x += a.x; sm.y += a.y; sm.z += a.z; sm.w += a.w;
    sq.x += b.x; sq.y += b.y; sq.z += b.z; sq.w += b.w;
  }
  float4 v = ((const float4*)h)[i];
  const float inv = 1.0f / NN;
  float4 o;
  float m, va, sc;
  m = sm.x * inv; va = fmaxf(sq.x * inv - m * m, 0.f); sc = rsqrtf(va + EPS_BN);
  o.x = fmaxf((v.x - m) * sc, 0.f);
  m = sm.y * inv; va = fmaxf(sq.y * inv - m * m, 0.f); sc = rsqrtf(va + EPS_BN);
  o.y = fmaxf((v.y - m) * sc, 0.f);
  m = sm.z * inv; va = fmaxf(sq.z * inv - m * m, 0.f); sc = rsqrtf(va + EPS_BN);
  o.z = fmaxf((v.z - m) * sc, 0.f);
  m = sm.w * inv; va = fmaxf(sq.w * inv - m * m, 0.f); sc = rsqrtf(va + EPS_BN);
  o.w = fmaxf((v.w - m) * sc, 0.f);
  ushort4 hv, lv; cvt4(o, &hv, &lv);
  ((ushort4*)xhi)[i] = hv;
  ((ushort4*)xlo)[i] = lv;
}

// ---------------- graph boundaries + fused pool/head ----------------
__global__ __launch_bounds__(128) void k_gstart(const int* __restrict__ batch, int* __restrict__ gstart) {
  int g = blockIdx.x * 128 + threadIdx.x;
  if (g > NG) return;
  int lo = 0, hi = NN;
  while (lo < hi) {
    int mid = (lo + hi) >> 1;
    if (batch[mid] < g) lo = mid + 1; else hi = mid;
  }
  gstart[g] = lo;
}

__global__ __launch_bounds__(128) void k_poolfinal(const float* __restrict__ h, const int* __restrict__ gstart,
                                                   const float* __restrict__ Wlin, const float* __restrict__ blin,
                                                   float* __restrict__ out) {
  __shared__ float p[FD];
  int g = blockIdx.x, f = threadIdx.x;
  int lo = gstart[g], hi = gstart[g + 1];
  float s = 0.f;
  for (int n = lo; n < hi; ++n) s += h[n * FD + f];
  p[f] = s * (1.0f / fmaxf((float)(hi - lo), 1.0f));
  __syncthreads();
  if (f < NC) {
    float a = blin[f];
    for (int k = 0; k < FD; ++k) a = fmaf(p[k], Wlin[f * FD + k], a);
    out[g * NC + f] = a;
  }
}

// ---------------- launch ----------------
extern "C" void kernel_launch(void* const* d_in, const int* in_sizes, int n_in,
                              void* d_out, int out_size, void* d_ws, size_t ws_size,
                              hipStream_t stream) {
  const float* x    = (const float*)d_in[0];
  const int*   ei   = (const int*)d_in[1];
  const int*   batch= (const int*)d_in[2];
  const float* W1   = (const float*)d_in[3];
  const float* b1   = (const float*)d_in[4];
  const float* W2   = (const float*)d_in[5];
  const float* b2   = (const float*)d_in[6];
  const float* W3   = (const float*)d_in[7];
  const float* b3   = (const float*)d_in[8];
  const float* Wlin = (const float*)d_in[9];
  const float* blin = (const float*)d_in[10];
  float* out = (float*)d_out;
  float* ws  = (float*)d_ws;

  const int* srcI = ei;
  const int* dstI = ei + NE;

  float* deg    = ws;                      // NN (raw degree incl self-loop)
  float* bufA   = ws + 50048;              // NN*FD
  float* bufB   = bufA + NN * FD;          // NN*FD
  float* bnA    = bufB + NN * FD;          // 2*8*FD (sum8, sq8) layer1
  float* bnB    = bnA + 2048;              // 2*8*FD layer2
  int2*  csr    = (int2*)(bnB + 2048);     // NE int2
  int*   row_off= (int*)(csr + NE);        // NN+1
  int*   cursor = row_off + 50048;         // NN
  int*   gstart = cursor + 50048;          // NG+1 (pad 1024)
  int*   bsum   = gstart + 1024;           // NB (pad 256)
  int*   bbase  = bsum + 256;              // NB (pad 256)
  unsigned short* xhi = (unsigned short*)(bbase + 256);  // NN*FD
  unsigned short* xlo = xhi + NN * FD;                    // NN*FD
  unsigned short* whi = xlo + NN * FD;                    // 3*FD*FD
  unsigned short* wlo = whi + 3 * FD * FD;                // 3*FD*FD

  dim3 B(256);
  const int gN    = (NN + 255) / 256;
  const int gE    = (NE + 255) / 256;
  const int gGemm = (NN / 16 + 3) / 4;
  const int gEl4  = (NN * FD / 4 + 255) / 256;
  const int gAgg  = NN / 8;   // 6250 exact

  // zero replicated BN accumulators (both layers) once
  hipMemsetAsync(bnA, 0, 4096 * sizeof(float), stream);

  // degree -> CSR
  k_init_deg<<<gN, B, 0, stream>>>(deg);
  k_deg_scatter<<<gE, B, 0, stream>>>(dstI, deg);
  k_bsum<<<NB, B, 0, stream>>>(deg, bsum);
  k_bscan<<<1, B, 0, stream>>>(bsum, bbase);
  k_rowoff<<<NB, B, 0, stream>>>(deg, bbase, row_off, cursor);
  k_fill<<<gE, B, 0, stream>>>(srcI, dstI, deg, cursor, csr);
  k_gstart<<<5, 128, 0, stream>>>(batch, gstart);
  k_cvt_w<<<dim3(16, 3), B, 0, stream>>>(W1, W2, W3, whi, wlo);
  k_cvt_x<<<gEl4, B, 0, stream>>>(x, xhi, xlo);

  // layer 1
  k_gemm<<<gGemm, B, 0, stream>>>(xhi, xlo, whi, wlo, bufA);
  k_agg<<<gAgg, B, 0, stream>>>(bufA, deg, b1, row_off, csr, bufB, bnA, bnA + 1024, 1);
  k_bn_apply_cvt<<<gEl4, B, 0, stream>>>(bufB, bnA, bnA + 1024, xhi, xlo);

  // layer 2
  k_gemm<<<gGemm, B, 0, stream>>>(xhi, xlo, whi + FD * FD, wlo + FD * FD, bufA);
  k_agg<<<gAgg, B, 0, stream>>>(bufA, deg, b2, row_off, csr, bufB, bnB, bnB + 1024, 1);
  k_bn_apply_cvt<<<gEl4, B, 0, stream>>>(bufB, bnB, bnB + 1024, xhi, xlo);

  // layer 3 (no BN/ReLU)
  k_gemm<<<gGemm, B, 0, stream>>>(xhi, xlo, whi + 2 * FD * FD, wlo + 2 * FD * FD, bufA);
  k_agg<<<gAgg, B, 0, stream>>>(bufA, deg, b3, row_off, csr, bufB, (float*)nullptr, (float*)nullptr, 0);

  // pool + head
  k_poolfinal<<<NG, 128, 0, stream>>>(bufB, gstart, Wlin, blin, out);
}

// Round 5
// 449.503 us; speedup vs baseline: 1.1536x; 1.1536x over previous
//
#include <hip/hip_runtime.h>
#include <hip/hip_bf16.h>

#define NN 50000
#define NE 600000
#define FD 128
#define NG 512
#define NC 10
static constexpr float EPS_BN = 1e-5f;

typedef __bf16 bf16x8 __attribute__((ext_vector_type(8)));
typedef float f32x4 __attribute__((ext_vector_type(4)));

__device__ __forceinline__ unsigned short f2bf(float x) {
  unsigned u = __float_as_uint(x);
  u = (u + 0x7FFFu + ((u >> 16) & 1u)) >> 16;
  return (unsigned short)u;
}
__device__ __forceinline__ float bf2f(unsigned short h) {
  return __uint_as_float(((unsigned)h) << 16);
}

// ---------------- degree ----------------
__global__ __launch_bounds__(256) void k_init_deg(float* __restrict__ deg) {
  int i = blockIdx.x * 256 + threadIdx.x;
  if (i < NN) deg[i] = 1.0f;   // self-loop
}

__global__ __launch_bounds__(256) void k_deg_scatter(const int* __restrict__ dst, float* __restrict__ deg) {
  int e = blockIdx.x * 256 + threadIdx.x;
  if (e < NE) unsafeAtomicAdd(&deg[dst[e]], 1.0f);
}

__global__ __launch_bounds__(256) void k_rsqrt(float* __restrict__ deg) {
  int i = blockIdx.x * 256 + threadIdx.x;
  if (i < NN) deg[i] = rsqrtf(deg[i]);   // deg >= 1 always
}

// ---------------- CSR build: multi-block exclusive scan of (deg-1) ----------------
#define NB 196   // ceil(50000/256)
__global__ __launch_bounds__(256) void k_bsum(const float* __restrict__ deg, int* __restrict__ bsum) {
  __shared__ int s[256];
  int t = threadIdx.x, i = blockIdx.x * 256 + t;
  s[t] = (i < NN) ? (int)deg[i] - 1 : 0;
  __syncthreads();
  for (int o = 128; o > 0; o >>= 1) { if (t < o) s[t] += s[t + o]; __syncthreads(); }
  if (t == 0) bsum[blockIdx.x] = s[0];
}

__global__ __launch_bounds__(256) void k_bscan(const int* __restrict__ bsum, int* __restrict__ bbase) {
  __shared__ int s[256];
  int t = threadIdx.x;
  int v = (t < NB) ? bsum[t] : 0;
  s[t] = v; __syncthreads();
  for (int o = 1; o < 256; o <<= 1) {
    int a = (t >= o) ? s[t - o] : 0; __syncthreads();
    s[t] += a; __syncthreads();
  }
  if (t < NB) bbase[t] = s[t] - v;
}

__global__ __launch_bounds__(256) void k_rowoff(const float* __restrict__ deg, const int* __restrict__ bbase,
                                                int* __restrict__ row_off, int* __restrict__ cursor) {
  __shared__ int s[256];
  int t = threadIdx.x, i = blockIdx.x * 256 + t;
  int c = (i < NN) ? (int)deg[i] - 1 : 0;
  s[t] = c; __syncthreads();
  for (int o = 1; o < 256; o <<= 1) {
    int a = (t >= o) ? s[t - o] : 0; __syncthreads();
    s[t] += a; __syncthreads();
  }
  int excl = s[t] - c + bbase[blockIdx.x];
  if (i <= NN) {
    row_off[i] = excl;
    if (i < NN) cursor[i] = excl;
  }
}

__global__ __launch_bounds__(256) void k_fill(const int* __restrict__ src, const int* __restrict__ dst,
                                              const float* __restrict__ dinv, int* __restrict__ cursor,
                                              int* __restrict__ csr_src, float* __restrict__ csr_nrm) {
  int e = blockIdx.x * 256 + threadIdx.x;
  if (e >= NE) return;
  int s = src[e], d = dst[e];
  int pos = atomicAdd(&cursor[d], 1);
  csr_src[pos] = s;
  csr_nrm[pos] = dinv[s] * dinv[d];
}

// ---------------- conversions fp32 -> bf16 hi/lo ----------------
__device__ __forceinline__ void cvt4(float4 v, ushort4* hp, ushort4* lp) {
  ushort4 hv, lv;
  hv.x = f2bf(v.x); lv.x = f2bf(v.x - bf2f(hv.x));
  hv.y = f2bf(v.y); lv.y = f2bf(v.y - bf2f(hv.y));
  hv.z = f2bf(v.z); lv.z = f2bf(v.z - bf2f(hv.z));
  hv.w = f2bf(v.w); lv.w = f2bf(v.w - bf2f(hv.w));
  *hp = hv; *lp = lv;
}

__global__ __launch_bounds__(256) void k_cvt_x(const float* __restrict__ x,
                                               unsigned short* __restrict__ xhi, unsigned short* __restrict__ xlo) {
  int i = blockIdx.x * 256 + threadIdx.x;
  if (i >= NN * FD / 4) return;
  float4 v = ((const float4*)x)[i];
  ushort4 hv, lv; cvt4(v, &hv, &lv);
  ((ushort4*)xhi)[i] = hv;
  ((ushort4*)xlo)[i] = lv;
}

__global__ __launch_bounds__(256) void k_cvt_w(const float* __restrict__ W1, const float* __restrict__ W2,
                                               const float* __restrict__ W3,
                                               unsigned short* __restrict__ whi, unsigned short* __restrict__ wlo) {
  int m = blockIdx.y;
  const float* W = (m == 0) ? W1 : ((m == 1) ? W2 : W3);
  int i = blockIdx.x * 256 + threadIdx.x;
  if (i >= FD * FD / 4) return;
  float4 v = ((const float4*)W)[i];
  ushort4 hv, lv; cvt4(v, &hv, &lv);
  ((ushort4*)(whi + m * FD * FD))[i] = hv;
  ((ushort4*)(wlo + m * FD * FD))[i] = lv;
}

// ---------------- MFMA GEMM: out[r][c] = sum_k in[r][k] * W[c][k] ----------------
__global__ __launch_bounds__(256) void k_gemm(const unsigned short* __restrict__ xhi,
                                              const unsigned short* __restrict__ xlo,
                                              const unsigned short* __restrict__ whi,
                                              const unsigned short* __restrict__ wlo,
                                              float* __restrict__ out) {
  int t = threadIdx.x;
  int w = t >> 6, l = t & 63;
  int rt = blockIdx.x * 4 + w;
  if (rt >= NN / 16) return;
  int row0 = rt * 16;
  int r = l & 15, g = l >> 4;
  int ko = g * 8;
  f32x4 acc[8];
#pragma unroll
  for (int ct = 0; ct < 8; ++ct) acc[ct] = (f32x4){0.f, 0.f, 0.f, 0.f};

#pragma unroll
  for (int kk = 0; kk < FD; kk += 32) {
    bf16x8 ah = *(const bf16x8*)(xhi + (size_t)(row0 + r) * FD + kk + ko);
    bf16x8 al = *(const bf16x8*)(xlo + (size_t)(row0 + r) * FD + kk + ko);
#pragma unroll
    for (int ct = 0; ct < 8; ++ct) {
      bf16x8 bh = *(const bf16x8*)(whi + (size_t)(ct * 16 + r) * FD + kk + ko);
      bf16x8 bl = *(const bf16x8*)(wlo + (size_t)(ct * 16 + r) * FD + kk + ko);
      acc[ct] = __builtin_amdgcn_mfma_f32_16x16x32_bf16(ah, bh, acc[ct], 0, 0, 0);
      acc[ct] = __builtin_amdgcn_mfma_f32_16x16x32_bf16(ah, bl, acc[ct], 0, 0, 0);
      acc[ct] = __builtin_amdgcn_mfma_f32_16x16x32_bf16(al, bh, acc[ct], 0, 0, 0);
    }
  }
#pragma unroll
  for (int ct = 0; ct < 8; ++ct)
#pragma unroll
    for (int i = 0; i < 4; ++i)
      out[(size_t)(row0 + g * 4 + i) * FD + ct * 16 + r] = acc[ct][i];
}

// ---------------- aggregation (R3 gather form) + optional fused BN stats ----------------
// out[n] = bias + dinv[n]^2*h[n] + sum_j nrm_j*h[src_j];  8 nodes/block, 6250*8 = 50000 exact
template <int STATS>
__global__ __launch_bounds__(256) void k_agg(const float* __restrict__ h, const float* __restrict__ dinv,
                                             const float* __restrict__ bias, const int* __restrict__ row_off,
                                             const int* __restrict__ csr_src, const float* __restrict__ csr_nrm,
                                             float* __restrict__ out,
                                             float* __restrict__ bnsum8, float* __restrict__ bnsq8) {
  int t = threadIdx.x;
  int n = blockIdx.x * 8 + (t >> 5);
  int q = t & 31;
  const float4* h4 = (const float4*)h;
  float dv = dinv[n];
  float s2 = dv * dv;
  float4 acc = ((const float4*)bias)[q];
  float4 hv = h4[(size_t)n * 32 + q];
  acc.x = fmaf(s2, hv.x, acc.x);
  acc.y = fmaf(s2, hv.y, acc.y);
  acc.z = fmaf(s2, hv.z, acc.z);
  acc.w = fmaf(s2, hv.w, acc.w);
  int lo = row_off[n], hi = row_off[n + 1];
  for (int j = lo; j < hi; ++j) {
    int s = csr_src[j];
    float w = csr_nrm[j];
    float4 v = h4[(size_t)s * 32 + q];
    acc.x = fmaf(w, v.x, acc.x);
    acc.y = fmaf(w, v.y, acc.y);
    acc.z = fmaf(w, v.z, acc.z);
    acc.w = fmaf(w, v.w, acc.w);
  }
  ((float4*)out)[(size_t)n * 32 + q] = acc;

  if constexpr (STATS != 0) {
    __shared__ float red_s[8][FD], red_q[8][FD];
    int slot = t >> 5, f = q * 4;
    red_s[slot][f + 0] = acc.x; red_s[slot][f + 1] = acc.y;
    red_s[slot][f + 2] = acc.z; red_s[slot][f + 3] = acc.w;
    red_q[slot][f + 0] = acc.x * acc.x; red_q[slot][f + 1] = acc.y * acc.y;
    red_q[slot][f + 2] = acc.z * acc.z; red_q[slot][f + 3] = acc.w * acc.w;
    __syncthreads();
    if (t < FD) {
      float s = 0.f, qq = 0.f;
#pragma unroll
      for (int m = 0; m < 8; ++m) { s += red_s[m][t]; qq += red_q[m][t]; }
      int c = (blockIdx.x & 7) * FD + t;
      unsafeAtomicAdd(&bnsum8[c], s);
      unsafeAtomicAdd(&bnsq8[c], qq);
    }
  }
}

// ---------------- BN normalize + ReLU -> bf16 hi/lo (reads 8 replicated partials) ----------------
__global__ __launch_bounds__(256) void k_bn_apply_cvt(const float* __restrict__ h,
                                                      const float* __restrict__ bnsum8, const float* __restrict__ bnsq8,
                                                      unsigned short* __restrict__ xhi, unsigned short* __restrict__ xlo) {
  int i = blockIdx.x * 256 + threadIdx.x;
  if (i >= NN * FD / 4) return;
  int q = i & 31;
  float4 sm = make_float4(0.f, 0.f, 0.f, 0.f), sq = make_float4(0.f, 0.f, 0.f, 0.f);
#pragma unroll
  for (int c = 0; c < 8; ++c) {
    float4 a = ((const float4*)(bnsum8 + c * FD))[q];
    float4 b = ((const float4*)(bnsq8 + c * FD))[q];
    sm.x += a.x; sm.y += a.y; sm.z += a.z; sm.w += a.w;
    sq.x += b.x; sq.y += b.y; sq.z += b.z; sq.w += b.w;
  }
  float4 v = ((const float4*)h)[i];
  const float inv = 1.0f / NN;
  float4 o;
  float m, va, sc;
  m = sm.x * inv; va = fmaxf(sq.x * inv - m * m, 0.f); sc = rsqrtf(va + EPS_BN);
  o.x = fmaxf((v.x - m) * sc, 0.f);
  m = sm.y * inv; va = fmaxf(sq.y * inv - m * m, 0.f); sc = rsqrtf(va + EPS_BN);
  o.y = fmaxf((v.y - m) * sc, 0.f);
  m = sm.z * inv; va = fmaxf(sq.z * inv - m * m, 0.f); sc = rsqrtf(va + EPS_BN);
  o.z = fmaxf((v.z - m) * sc, 0.f);
  m = sm.w * inv; va = fmaxf(sq.w * inv - m * m, 0.f); sc = rsqrtf(va + EPS_BN);
  o.w = fmaxf((v.w - m) * sc, 0.f);
  ushort4 hv, lv; cvt4(o, &hv, &lv);
  ((ushort4*)xhi)[i] = hv;
  ((ushort4*)xlo)[i] = lv;
}

// ---------------- graph boundaries + fused pool/head ----------------
__global__ __launch_bounds__(128) void k_gstart(const int* __restrict__ batch, int* __restrict__ gstart) {
  int g = blockIdx.x * 128 + threadIdx.x;
  if (g > NG) return;
  int lo = 0, hi = NN;
  while (lo < hi) {
    int mid = (lo + hi) >> 1;
    if (batch[mid] < g) lo = mid + 1; else hi = mid;
  }
  gstart[g] = lo;
}

__global__ __launch_bounds__(128) void k_poolfinal(const float* __restrict__ h, const int* __restrict__ gstart,
                                                   const float* __restrict__ Wlin, const float* __restrict__ blin,
                                                   float* __restrict__ out) {
  __shared__ float p[FD];
  int g = blockIdx.x, f = threadIdx.x;
  int lo = gstart[g], hi = gstart[g + 1];
  float s = 0.f;
  for (int n = lo; n < hi; ++n) s += h[n * FD + f];
  p[f] = s * (1.0f / fmaxf((float)(hi - lo), 1.0f));
  __syncthreads();
  if (f < NC) {
    float a = blin[f];
    for (int k = 0; k < FD; ++k) a = fmaf(p[k], Wlin[f * FD + k], a);
    out[g * NC + f] = a;
  }
}

// ---------------- launch ----------------
extern "C" void kernel_launch(void* const* d_in, const int* in_sizes, int n_in,
                              void* d_out, int out_size, void* d_ws, size_t ws_size,
                              hipStream_t stream) {
  const float* x    = (const float*)d_in[0];
  const int*   ei   = (const int*)d_in[1];
  const int*   batch= (const int*)d_in[2];
  const float* W1   = (const float*)d_in[3];
  const float* b1   = (const float*)d_in[4];
  const float* W2   = (const float*)d_in[5];
  const float* b2   = (const float*)d_in[6];
  const float* W3   = (const float*)d_in[7];
  const float* b3   = (const float*)d_in[8];
  const float* Wlin = (const float*)d_in[9];
  const float* blin = (const float*)d_in[10];
  float* out = (float*)d_out;
  float* ws  = (float*)d_ws;

  const int* srcI = ei;
  const int* dstI = ei + NE;

  float* deg    = ws;                      // NN (dinv after k_rsqrt)
  float* bufA   = ws + 50048;              // NN*FD
  float* bufB   = bufA + NN * FD;          // NN*FD
  float* bnA    = bufB + NN * FD;          // 2*8*FD layer1 (sum8, sq8)
  float* bnB    = bnA + 2048;              // 2*8*FD layer2
  float* csr_nrm= bnB + 2048;              // NE
  int*   csr_src= (int*)(csr_nrm + NE);    // NE
  int*   row_off= csr_src + NE;            // NN+1
  int*   cursor = row_off + 50048;         // NN
  int*   gstart = cursor + 50048;          // NG+1 (pad 1024)
  int*   bsum   = gstart + 1024;           // NB (pad 256)
  int*   bbase  = bsum + 256;              // NB (pad 256)
  unsigned short* xhi = (unsigned short*)(bbase + 256);  // NN*FD
  unsigned short* xlo = xhi + NN * FD;                    // NN*FD
  unsigned short* whi = xlo + NN * FD;                    // 3*FD*FD
  unsigned short* wlo = whi + 3 * FD * FD;                // 3*FD*FD

  dim3 B(256);
  const int gN    = (NN + 255) / 256;
  const int gE    = (NE + 255) / 256;
  const int gGemm = (NN / 16 + 3) / 4;
  const int gEl4  = (NN * FD / 4 + 255) / 256;
  const int gAgg  = NN / 8;   // 6250 exact

  // zero replicated BN accumulators (both layers) once
  hipMemsetAsync(bnA, 0, 4096 * sizeof(float), stream);

  // degree -> CSR -> dinv
  k_init_deg<<<gN, B, 0, stream>>>(deg);
  k_deg_scatter<<<gE, B, 0, stream>>>(dstI, deg);
  k_bsum<<<NB, B, 0, stream>>>(deg, bsum);
  k_bscan<<<1, B, 0, stream>>>(bsum, bbase);
  k_rowoff<<<NB, B, 0, stream>>>(deg, bbase, row_off, cursor);
  k_rsqrt<<<gN, B, 0, stream>>>(deg);
  k_fill<<<gE, B, 0, stream>>>(srcI, dstI, deg, cursor, csr_src, csr_nrm);
  k_gstart<<<5, 128, 0, stream>>>(batch, gstart);
  k_cvt_w<<<dim3(16, 3), B, 0, stream>>>(W1, W2, W3, whi, wlo);
  k_cvt_x<<<gEl4, B, 0, stream>>>(x, xhi, xlo);

  // layer 1
  k_gemm<<<gGemm, B, 0, stream>>>(xhi, xlo, whi, wlo, bufA);
  k_agg<1><<<gAgg, B, 0, stream>>>(bufA, deg, b1, row_off, csr_src, csr_nrm, bufB, bnA, bnA + 1024);
  k_bn_apply_cvt<<<gEl4, B, 0, stream>>>(bufB, bnA, bnA + 1024, xhi, xlo);

  // layer 2
  k_gemm<<<gGemm, B, 0, stream>>>(xhi, xlo, whi + FD * FD, wlo + FD * FD, bufA);
  k_agg<1><<<gAgg, B, 0, stream>>>(bufA, deg, b2, row_off, csr_src, csr_nrm, bufB, bnB, bnB + 1024);
  k_bn_apply_cvt<<<gEl4, B, 0, stream>>>(bufB, bnB, bnB + 1024, xhi, xlo);

  // layer 3 (no BN/ReLU)
  k_gemm<<<gGemm, B, 0, stream>>>(xhi, xlo, whi + 2 * FD * FD, wlo + 2 * FD * FD, bufA);
  k_agg<0><<<gAgg, B, 0, stream>>>(bufA, deg, b3, row_off, csr_src, csr_nrm, bufB, nullptr, nullptr);

  // pool + head
  k_poolfinal<<<NG, 128, 0, stream>>>(bufB, gstart, Wlin, blin, out);
}

// Round 6
// 395.078 us; speedup vs baseline: 1.3125x; 1.1378x over previous
//
#include <hip/hip_runtime.h>
#include <hip/hip_bf16.h>

#define NN 50000
#define NE 600000
#define FD 128
#define NG 512
#define NC 10
static constexpr float EPS_BN = 1e-5f;

typedef __bf16 bf16x8 __attribute__((ext_vector_type(8)));
typedef float f32x4 __attribute__((ext_vector_type(4)));

__device__ __forceinline__ unsigned short f2bf(float x) {
  unsigned u = __float_as_uint(x);
  u = (u + 0x7FFFu + ((u >> 16) & 1u)) >> 16;
  return (unsigned short)u;
}
__device__ __forceinline__ float bf2f(unsigned short h) {
  return __uint_as_float(((unsigned)h) << 16);
}

// ---------------- degree (deg starts memset to 0; holds in-edge count) ----------------
__global__ __launch_bounds__(256) void k_deg_scatter(const int* __restrict__ dst, float* __restrict__ deg) {
  int e = blockIdx.x * 256 + threadIdx.x;
  if (e < NE) unsafeAtomicAdd(&deg[dst[e]], 1.0f);
}

// ---------------- CSR build: multi-block exclusive scan of in-edge counts ----------------
#define NB 196   // ceil(50000/256)
__global__ __launch_bounds__(256) void k_bsum(const float* __restrict__ deg, int* __restrict__ bsum) {
  __shared__ int s[256];
  int t = threadIdx.x, i = blockIdx.x * 256 + t;
  s[t] = (i < NN) ? (int)deg[i] : 0;
  __syncthreads();
  for (int o = 128; o > 0; o >>= 1) { if (t < o) s[t] += s[t + o]; __syncthreads(); }
  if (t == 0) bsum[blockIdx.x] = s[0];
}

__global__ __launch_bounds__(256) void k_bscan(const int* __restrict__ bsum, int* __restrict__ bbase) {
  __shared__ int s[256];
  int t = threadIdx.x;
  int v = (t < NB) ? bsum[t] : 0;
  s[t] = v; __syncthreads();
  for (int o = 1; o < 256; o <<= 1) {
    int a = (t >= o) ? s[t - o] : 0; __syncthreads();
    s[t] += a; __syncthreads();
  }
  if (t < NB) bbase[t] = s[t] - v;
}

// also transforms deg (count) -> dinv = rsqrt(count+1)
__global__ __launch_bounds__(256) void k_rowoff(float* __restrict__ deg, const int* __restrict__ bbase,
                                                int* __restrict__ row_off, int* __restrict__ cursor) {
  __shared__ int s[256];
  int t = threadIdx.x, i = blockIdx.x * 256 + t;
  float dv = (i < NN) ? deg[i] : 0.f;
  int c = (int)dv;
  s[t] = c; __syncthreads();
  for (int o = 1; o < 256; o <<= 1) {
    int a = (t >= o) ? s[t - o] : 0; __syncthreads();
    s[t] += a; __syncthreads();
  }
  int excl = s[t] - c + bbase[blockIdx.x];
  if (i <= NN) {
    row_off[i] = excl;
    if (i < NN) {
      cursor[i] = excl;
      deg[i] = rsqrtf(dv + 1.0f);
    }
  }
}

__global__ __launch_bounds__(256) void k_fill(const int* __restrict__ src, const int* __restrict__ dst,
                                              const float* __restrict__ dinv, int* __restrict__ cursor,
                                              int* __restrict__ csr_src, float* __restrict__ csr_nrm) {
  int e = blockIdx.x * 256 + threadIdx.x;
  if (e >= NE) return;
  int s = src[e], d = dst[e];
  int pos = atomicAdd(&cursor[d], 1);
  csr_src[pos] = s;
  csr_nrm[pos] = dinv[s] * dinv[d];
}

// ---------------- weights fp32 -> bf16 hi/lo ----------------
__global__ __launch_bounds__(256) void k_cvt_w(const float* __restrict__ W1, const float* __restrict__ W2,
                                               const float* __restrict__ W3,
                                               unsigned short* __restrict__ whi, unsigned short* __restrict__ wlo) {
  int m = blockIdx.y;
  const float* W = (m == 0) ? W1 : ((m == 1) ? W2 : W3);
  int i = blockIdx.x * 256 + threadIdx.x;
  if (i >= FD * FD / 4) return;
  float4 v = ((const float4*)W)[i];
  ushort4 hv, lv;
  hv.x = f2bf(v.x); lv.x = f2bf(v.x - bf2f(hv.x));
  hv.y = f2bf(v.y); lv.y = f2bf(v.y - bf2f(hv.y));
  hv.z = f2bf(v.z); lv.z = f2bf(v.z - bf2f(hv.z));
  hv.w = f2bf(v.w); lv.w = f2bf(v.w - bf2f(hv.w));
  ((ushort4*)(whi + m * FD * FD))[i] = hv;
  ((ushort4*)(wlo + m * FD * FD))[i] = lv;
}

// ---------------- MFMA GEMM with fused input-BN+ReLU+bf16 split ----------------
// out[r][c] = sum_k f(in[r][k]) * W[c][k],  f = BN? relu((v-mu)*scale) : v
// 2 row-tiles per wave sharing B loads; musc = [mu[128] | scale[128]]
template <int BN>
__global__ __launch_bounds__(256) void k_gemm(const float* __restrict__ in, const float* __restrict__ musc,
                                              const unsigned short* __restrict__ whi,
                                              const unsigned short* __restrict__ wlo,
                                              float* __restrict__ out) {
  int t = threadIdx.x;
  int w = t >> 6, l = t & 63;
  int rt0 = blockIdx.x * 8 + w;
  int rt1 = rt0 + 4;
  bool v0 = rt0 < NN / 16, v1 = rt1 < NN / 16;
  if (!v0) return;
  int r = l & 15, g = l >> 4;
  int ko = g * 8;
  f32x4 acc0[8], acc1[8];
#pragma unroll
  for (int ct = 0; ct < 8; ++ct) {
    acc0[ct] = (f32x4){0.f, 0.f, 0.f, 0.f};
    acc1[ct] = (f32x4){0.f, 0.f, 0.f, 0.f};
  }

#pragma unroll
  for (int kk = 0; kk < FD; kk += 32) {
    float a0[8], a1[8];
    {
      const float* p0 = in + (size_t)(rt0 * 16 + r) * FD + kk + ko;
      float4 x0 = *(const float4*)p0;
      float4 x1 = *(const float4*)(p0 + 4);
      a0[0] = x0.x; a0[1] = x0.y; a0[2] = x0.z; a0[3] = x0.w;
      a0[4] = x1.x; a0[5] = x1.y; a0[6] = x1.z; a0[7] = x1.w;
    }
    if (v1) {
      const float* p1 = in + (size_t)(rt1 * 16 + r) * FD + kk + ko;
      float4 x0 = *(const float4*)p1;
      float4 x1 = *(const float4*)(p1 + 4);
      a1[0] = x0.x; a1[1] = x0.y; a1[2] = x0.z; a1[3] = x0.w;
      a1[4] = x1.x; a1[5] = x1.y; a1[6] = x1.z; a1[7] = x1.w;
    }
    if constexpr (BN != 0) {
      float mu[8], sc[8];
      {
        const float* mp = musc + kk + ko;
        float4 m0 = *(const float4*)mp, m1 = *(const float4*)(mp + 4);
        float4 s0 = *(const float4*)(mp + FD), s1 = *(const float4*)(mp + FD + 4);
        mu[0] = m0.x; mu[1] = m0.y; mu[2] = m0.z; mu[3] = m0.w;
        mu[4] = m1.x; mu[5] = m1.y; mu[6] = m1.z; mu[7] = m1.w;
        sc[0] = s0.x; sc[1] = s0.y; sc[2] = s0.z; sc[3] = s0.w;
        sc[4] = s1.x; sc[5] = s1.y; sc[6] = s1.z; sc[7] = s1.w;
      }
#pragma unroll
      for (int i = 0; i < 8; ++i) {
        a0[i] = fmaxf((a0[i] - mu[i]) * sc[i], 0.f);
        a1[i] = v1 ? fmaxf((a1[i] - mu[i]) * sc[i], 0.f) : 0.f;
      }
    }
    bf16x8 ah0, al0, ah1, al1;
#pragma unroll
    for (int i = 0; i < 8; ++i) {
      __bf16 h0 = (__bf16)a0[i];
      ah0[i] = h0; al0[i] = (__bf16)(a0[i] - (float)h0);
      __bf16 h1 = (__bf16)a1[i];
      ah1[i] = h1; al1[i] = (__bf16)(a1[i] - (float)h1);
    }
#pragma unroll
    for (int ct = 0; ct < 8; ++ct) {
      bf16x8 bh = *(const bf16x8*)(whi + (size_t)(ct * 16 + r) * FD + kk + ko);
      bf16x8 bl = *(const bf16x8*)(wlo + (size_t)(ct * 16 + r) * FD + kk + ko);
      acc0[ct] = __builtin_amdgcn_mfma_f32_16x16x32_bf16(ah0, bh, acc0[ct], 0, 0, 0);
      acc0[ct] = __builtin_amdgcn_mfma_f32_16x16x32_bf16(ah0, bl, acc0[ct], 0, 0, 0);
      acc0[ct] = __builtin_amdgcn_mfma_f32_16x16x32_bf16(al0, bh, acc0[ct], 0, 0, 0);
      if (v1) {
        acc1[ct] = __builtin_amdgcn_mfma_f32_16x16x32_bf16(ah1, bh, acc1[ct], 0, 0, 0);
        acc1[ct] = __builtin_amdgcn_mfma_f32_16x16x32_bf16(ah1, bl, acc1[ct], 0, 0, 0);
        acc1[ct] = __builtin_amdgcn_mfma_f32_16x16x32_bf16(al1, bh, acc1[ct], 0, 0, 0);
      }
    }
  }
  // C/D layout: col = lane&15 (=r), row = g*4 + reg
#pragma unroll
  for (int ct = 0; ct < 8; ++ct)
#pragma unroll
    for (int i = 0; i < 4; ++i) {
      out[(size_t)(rt0 * 16 + g * 4 + i) * FD + ct * 16 + r] = acc0[ct][i];
      if (v1) out[(size_t)(rt1 * 16 + g * 4 + i) * FD + ct * 16 + r] = acc1[ct][i];
    }
}

// ---------------- aggregation (R3/R5 measured-good gather form) + optional BN stats ----------------
template <int STATS>
__global__ __launch_bounds__(256) void k_agg(const float* __restrict__ h, const float* __restrict__ dinv,
                                             const float* __restrict__ bias, const int* __restrict__ row_off,
                                             const int* __restrict__ csr_src, const float* __restrict__ csr_nrm,
                                             float* __restrict__ out,
                                             float* __restrict__ bnsum8, float* __restrict__ bnsq8) {
  int t = threadIdx.x;
  int n = blockIdx.x * 8 + (t >> 5);
  int q = t & 31;
  const float4* h4 = (const float4*)h;
  float dv = dinv[n];
  float s2 = dv * dv;
  float4 acc = ((const float4*)bias)[q];
  float4 hv = h4[(size_t)n * 32 + q];
  acc.x = fmaf(s2, hv.x, acc.x);
  acc.y = fmaf(s2, hv.y, acc.y);
  acc.z = fmaf(s2, hv.z, acc.z);
  acc.w = fmaf(s2, hv.w, acc.w);
  int lo = row_off[n], hi = row_off[n + 1];
  for (int j = lo; j < hi; ++j) {
    int s = csr_src[j];
    float w = csr_nrm[j];
    float4 v = h4[(size_t)s * 32 + q];
    acc.x = fmaf(w, v.x, acc.x);
    acc.y = fmaf(w, v.y, acc.y);
    acc.z = fmaf(w, v.z, acc.z);
    acc.w = fmaf(w, v.w, acc.w);
  }
  ((float4*)out)[(size_t)n * 32 + q] = acc;

  if constexpr (STATS != 0) {
    __shared__ float red_s[8][FD], red_q[8][FD];
    int slot = t >> 5, f = q * 4;
    red_s[slot][f + 0] = acc.x; red_s[slot][f + 1] = acc.y;
    red_s[slot][f + 2] = acc.z; red_s[slot][f + 3] = acc.w;
    red_q[slot][f + 0] = acc.x * acc.x; red_q[slot][f + 1] = acc.y * acc.y;
    red_q[slot][f + 2] = acc.z * acc.z; red_q[slot][f + 3] = acc.w * acc.w;
    __syncthreads();
    if (t < FD) {
      float s = 0.f, qq = 0.f;
#pragma unroll
      for (int m = 0; m < 8; ++m) { s += red_s[m][t]; qq += red_q[m][t]; }
      int c = (blockIdx.x & 7) * FD + t;
      unsafeAtomicAdd(&bnsum8[c], s);
      unsafeAtomicAdd(&bnsq8[c], qq);
    }
  }
}

// ---------------- reduce 8-replica stats -> mu | scale ----------------
__global__ __launch_bounds__(128) void k_bn_final(const float* __restrict__ bn8, float* __restrict__ musc) {
  int f = threadIdx.x;
  float s = 0.f, q = 0.f;
#pragma unroll
  for (int c = 0; c < 8; ++c) { s += bn8[c * FD + f]; q += bn8[1024 + c * FD + f]; }
  float m = s * (1.0f / NN);
  float v = fmaxf(q * (1.0f / NN) - m * m, 0.f);
  musc[f] = m;
  musc[FD + f] = rsqrtf(v + EPS_BN);
}

// ---------------- graph boundaries + fused pool/head ----------------
__global__ __launch_bounds__(128) void k_gstart(const int* __restrict__ batch, int* __restrict__ gstart) {
  int g = blockIdx.x * 128 + threadIdx.x;
  if (g > NG) return;
  int lo = 0, hi = NN;
  while (lo < hi) {
    int mid = (lo + hi) >> 1;
    if (batch[mid] < g) lo = mid + 1; else hi = mid;
  }
  gstart[g] = lo;
}

__global__ __launch_bounds__(512) void k_poolfinal(const float* __restrict__ h, const int* __restrict__ gstart,
                                                   const float* __restrict__ Wlin, const float* __restrict__ blin,
                                                   float* __restrict__ out) {
  __shared__ float ps[4][FD];
  __shared__ float pp[FD];
  int g = blockIdx.x, t = threadIdx.x;
  int part = t >> 7, f = t & 127;
  int lo = gstart[g], hi = gstart[g + 1];
  float s = 0.f;
  for (int n = lo + part; n < hi; n += 4) s += h[(size_t)n * FD + f];
  ps[part][f] = s;
  __syncthreads();
  if (t < FD) {
    float tot = ps[0][t] + ps[1][t] + ps[2][t] + ps[3][t];
    pp[t] = tot * (1.0f / fmaxf((float)(hi - lo), 1.0f));
  }
  __syncthreads();
  if (t < NC) {
    float a = blin[t];
    for (int k = 0; k < FD; ++k) a = fmaf(pp[k], Wlin[t * FD + k], a);
    out[g * NC + t] = a;
  }
}

// ---------------- launch ----------------
extern "C" void kernel_launch(void* const* d_in, const int* in_sizes, int n_in,
                              void* d_out, int out_size, void* d_ws, size_t ws_size,
                              hipStream_t stream) {
  const float* x    = (const float*)d_in[0];
  const int*   ei   = (const int*)d_in[1];
  const int*   batch= (const int*)d_in[2];
  const float* W1   = (const float*)d_in[3];
  const float* b1   = (const float*)d_in[4];
  const float* W2   = (const float*)d_in[5];
  const float* b2   = (const float*)d_in[6];
  const float* W3   = (const float*)d_in[7];
  const float* b3   = (const float*)d_in[8];
  const float* Wlin = (const float*)d_in[9];
  const float* blin = (const float*)d_in[10];
  float* out = (float*)d_out;
  float* ws  = (float*)d_ws;

  const int* srcI = ei;
  const int* dstI = ei + NE;

  float* deg    = ws;                      // NN; in-edge count, then dinv
  float* bnA    = ws + 50048;              // 2048 (sum8 | sq8) layer1
  float* bnB    = bnA + 2048;              // 2048 layer2
  float* musc1  = bnB + 2048;              // 256 (mu | scale)
  float* musc2  = musc1 + 256;             // 256
  float* bufA   = musc2 + 256;             // NN*FD
  float* bufB   = bufA + NN * FD;          // NN*FD
  float* csr_nrm= bufB + NN * FD;          // NE
  int*   csr_src= (int*)(csr_nrm + NE);    // NE
  int*   row_off= csr_src + NE;            // NN+1
  int*   cursor = row_off + 50048;         // NN
  int*   gstart = cursor + 50048;          // NG+1 (pad 1024)
  int*   bsum   = gstart + 1024;           // NB (pad 256)
  int*   bbase  = bsum + 256;              // NB (pad 256)
  unsigned short* whi = (unsigned short*)(bbase + 256);  // 3*FD*FD
  unsigned short* wlo = whi + 3 * FD * FD;                // 3*FD*FD

  dim3 B(256);
  const int gE    = (NE + 255) / 256;
  const int gGemm = (NN / 16 + 7) / 8;   // 391 blocks, 8 row-tiles each
  const int gAgg  = NN / 8;              // 6250 exact

  // zero deg + bn accumulators + musc in one shot
  hipMemsetAsync(ws, 0, (50048 + 4096 + 512) * sizeof(float), stream);

  // degree -> CSR -> dinv
  k_deg_scatter<<<gE, B, 0, stream>>>(dstI, deg);
  k_bsum<<<NB, B, 0, stream>>>(deg, bsum);
  k_bscan<<<1, B, 0, stream>>>(bsum, bbase);
  k_rowoff<<<NB, B, 0, stream>>>(deg, bbase, row_off, cursor);
  k_fill<<<gE, B, 0, stream>>>(srcI, dstI, deg, cursor, csr_src, csr_nrm);
  k_gstart<<<5, 128, 0, stream>>>(batch, gstart);
  k_cvt_w<<<dim3(16, 3), B, 0, stream>>>(W1, W2, W3, whi, wlo);

  // layer 1
  k_gemm<0><<<gGemm, B, 0, stream>>>(x, nullptr, whi, wlo, bufA);
  k_agg<1><<<gAgg, B, 0, stream>>>(bufA, deg, b1, row_off, csr_src, csr_nrm, bufB, bnA, bnA + 1024);
  k_bn_final<<<1, 128, 0, stream>>>(bnA, musc1);

  // layer 2 (BN+ReLU fused into GEMM input path)
  k_gemm<1><<<gGemm, B, 0, stream>>>(bufB, musc1, whi + FD * FD, wlo + FD * FD, bufA);
  k_agg<1><<<gAgg, B, 0, stream>>>(bufA, deg, b2, row_off, csr_src, csr_nrm, bufB, bnB, bnB + 1024);
  k_bn_final<<<1, 128, 0, stream>>>(bnB, musc2);

  // layer 3
  k_gemm<1><<<gGemm, B, 0, stream>>>(bufB, musc2, whi + 2 * FD * FD, wlo + 2 * FD * FD, bufA);
  k_agg<0><<<gAgg, B, 0, stream>>>(bufA, deg, b3, row_off, csr_src, csr_nrm, bufB, nullptr, nullptr);

  // pool + head
  k_poolfinal<<<NG, 512, 0, stream>>>(bufB, gstart, Wlin, blin, out);
}

// Round 7
// 382.987 us; speedup vs baseline: 1.3539x; 1.0316x over previous
//
#include <hip/hip_runtime.h>
#include <hip/hip_bf16.h>

#define NN 50000
#define NE 600000
#define FD 128
#define NG 512
#define NC 10
static constexpr float EPS_BN = 1e-5f;

typedef __bf16 bf16x8 __attribute__((ext_vector_type(8)));
typedef float f32x4 __attribute__((ext_vector_type(4)));

__device__ __forceinline__ unsigned short f2bf(float x) {
  unsigned u = __float_as_uint(x);
  u = (u + 0x7FFFu + ((u >> 16) & 1u)) >> 16;
  return (unsigned short)u;
}
__device__ __forceinline__ float bf2f(unsigned short h) {
  return __uint_as_float(((unsigned)h) << 16);
}

// ---------------- degree (deg starts memset to 0; holds in-edge count) ----------------
__global__ __launch_bounds__(256) void k_deg_scatter(const int* __restrict__ dst, float* __restrict__ deg) {
  int e = blockIdx.x * 256 + threadIdx.x;
  if (e < NE) unsafeAtomicAdd(&deg[dst[e]], 1.0f);
}

// ---------------- CSR build: multi-block exclusive scan of in-edge counts ----------------
#define NB 196   // ceil(50000/256)
__global__ __launch_bounds__(256) void k_bsum(const float* __restrict__ deg, int* __restrict__ bsum) {
  __shared__ int s[256];
  int t = threadIdx.x, i = blockIdx.x * 256 + t;
  s[t] = (i < NN) ? (int)deg[i] : 0;
  __syncthreads();
  for (int o = 128; o > 0; o >>= 1) { if (t < o) s[t] += s[t + o]; __syncthreads(); }
  if (t == 0) bsum[blockIdx.x] = s[0];
}

__global__ __launch_bounds__(256) void k_bscan(const int* __restrict__ bsum, int* __restrict__ bbase) {
  __shared__ int s[256];
  int t = threadIdx.x;
  int v = (t < NB) ? bsum[t] : 0;
  s[t] = v; __syncthreads();
  for (int o = 1; o < 256; o <<= 1) {
    int a = (t >= o) ? s[t - o] : 0; __syncthreads();
    s[t] += a; __syncthreads();
  }
  if (t < NB) bbase[t] = s[t] - v;
}

// also transforms deg (count) -> dinv = rsqrt(count+1)
__global__ __launch_bounds__(256) void k_rowoff(float* __restrict__ deg, const int* __restrict__ bbase,
                                                int* __restrict__ row_off, int* __restrict__ cursor) {
  __shared__ int s[256];
  int t = threadIdx.x, i = blockIdx.x * 256 + t;
  float dv = (i < NN) ? deg[i] : 0.f;
  int c = (int)dv;
  s[t] = c; __syncthreads();
  for (int o = 1; o < 256; o <<= 1) {
    int a = (t >= o) ? s[t - o] : 0; __syncthreads();
    s[t] += a; __syncthreads();
  }
  int excl = s[t] - c + bbase[blockIdx.x];
  if (i <= NN) {
    row_off[i] = excl;
    if (i < NN) {
      cursor[i] = excl;
      deg[i] = rsqrtf(dv + 1.0f);
    }
  }
}

__global__ __launch_bounds__(256) void k_fill(const int* __restrict__ src, const int* __restrict__ dst,
                                              const float* __restrict__ dinv, int* __restrict__ cursor,
                                              int* __restrict__ csr_src, float* __restrict__ csr_nrm) {
  int e = blockIdx.x * 256 + threadIdx.x;
  if (e >= NE) return;
  int s = src[e], d = dst[e];
  int pos = atomicAdd(&cursor[d], 1);
  csr_src[pos] = s;
  csr_nrm[pos] = dinv[s] * dinv[d];
}

// ---------------- weights fp32 -> bf16 hi/lo ----------------
__global__ __launch_bounds__(256) void k_cvt_w(const float* __restrict__ W1, const float* __restrict__ W2,
                                               const float* __restrict__ W3,
                                               unsigned short* __restrict__ whi, unsigned short* __restrict__ wlo) {
  int m = blockIdx.y;
  const float* W = (m == 0) ? W1 : ((m == 1) ? W2 : W3);
  int i = blockIdx.x * 256 + threadIdx.x;
  if (i >= FD * FD / 4) return;
  float4 v = ((const float4*)W)[i];
  ushort4 hv, lv;
  hv.x = f2bf(v.x); lv.x = f2bf(v.x - bf2f(hv.x));
  hv.y = f2bf(v.y); lv.y = f2bf(v.y - bf2f(hv.y));
  hv.z = f2bf(v.z); lv.z = f2bf(v.z - bf2f(hv.z));
  hv.w = f2bf(v.w); lv.w = f2bf(v.w - bf2f(hv.w));
  ((ushort4*)(whi + m * FD * FD))[i] = hv;
  ((ushort4*)(wlo + m * FD * FD))[i] = lv;
}

// ---------------- MFMA GEMM with fused input-BN+ReLU+bf16 split ----------------
// 1 row-tile per wave (grid 782 blocks -> ~3 waves/SIMD for latency overlap)
template <int BN>
__global__ __launch_bounds__(256) void k_gemm(const float* __restrict__ in, const float* __restrict__ musc,
                                              const unsigned short* __restrict__ whi,
                                              const unsigned short* __restrict__ wlo,
                                              float* __restrict__ out) {
  int t = threadIdx.x;
  int w = t >> 6, l = t & 63;
  int rt = blockIdx.x * 4 + w;
  if (rt >= NN / 16) return;
  int r = l & 15, g = l >> 4;
  int ko = g * 8;
  f32x4 acc[8];
#pragma unroll
  for (int ct = 0; ct < 8; ++ct) acc[ct] = (f32x4){0.f, 0.f, 0.f, 0.f};

#pragma unroll
  for (int kk = 0; kk < FD; kk += 32) {
    float a0[8];
    {
      const float* p0 = in + (size_t)(rt * 16 + r) * FD + kk + ko;
      float4 x0 = *(const float4*)p0;
      float4 x1 = *(const float4*)(p0 + 4);
      a0[0] = x0.x; a0[1] = x0.y; a0[2] = x0.z; a0[3] = x0.w;
      a0[4] = x1.x; a0[5] = x1.y; a0[6] = x1.z; a0[7] = x1.w;
    }
    if constexpr (BN != 0) {
      const float* mp = musc + kk + ko;
      float4 m0 = *(const float4*)mp, m1 = *(const float4*)(mp + 4);
      float4 s0 = *(const float4*)(mp + FD), s1 = *(const float4*)(mp + FD + 4);
      a0[0] = fmaxf((a0[0] - m0.x) * s0.x, 0.f);
      a0[1] = fmaxf((a0[1] - m0.y) * s0.y, 0.f);
      a0[2] = fmaxf((a0[2] - m0.z) * s0.z, 0.f);
      a0[3] = fmaxf((a0[3] - m0.w) * s0.w, 0.f);
      a0[4] = fmaxf((a0[4] - m1.x) * s1.x, 0.f);
      a0[5] = fmaxf((a0[5] - m1.y) * s1.y, 0.f);
      a0[6] = fmaxf((a0[6] - m1.z) * s1.z, 0.f);
      a0[7] = fmaxf((a0[7] - m1.w) * s1.w, 0.f);
    }
    bf16x8 ah, al;
#pragma unroll
    for (int i = 0; i < 8; ++i) {
      __bf16 h0 = (__bf16)a0[i];
      ah[i] = h0; al[i] = (__bf16)(a0[i] - (float)h0);
    }
#pragma unroll
    for (int ct = 0; ct < 8; ++ct) {
      bf16x8 bh = *(const bf16x8*)(whi + (size_t)(ct * 16 + r) * FD + kk + ko);
      bf16x8 bl = *(const bf16x8*)(wlo + (size_t)(ct * 16 + r) * FD + kk + ko);
      acc[ct] = __builtin_amdgcn_mfma_f32_16x16x32_bf16(ah, bh, acc[ct], 0, 0, 0);
      acc[ct] = __builtin_amdgcn_mfma_f32_16x16x32_bf16(ah, bl, acc[ct], 0, 0, 0);
      acc[ct] = __builtin_amdgcn_mfma_f32_16x16x32_bf16(al, bh, acc[ct], 0, 0, 0);
    }
  }
  // C/D layout: col = lane&15 (=r), row = g*4 + reg
#pragma unroll
  for (int ct = 0; ct < 8; ++ct)
#pragma unroll
    for (int i = 0; i < 4; ++i)
      out[(size_t)(rt * 16 + g * 4 + i) * FD + ct * 16 + r] = acc[ct][i];
}

// ---------------- aggregation: 16 lanes/node, 2 independent float4 loads per edge ----------------
// out[n] = bias + dinv[n]^2*h[n] + sum_j nrm_j*h[src_j];  16 nodes/block, 3125*16 = 50000 exact
template <int STATS>
__global__ __launch_bounds__(256) void k_agg(const float* __restrict__ h, const float* __restrict__ dinv,
                                             const float* __restrict__ bias, const int* __restrict__ row_off,
                                             const int* __restrict__ csr_src, const float* __restrict__ csr_nrm,
                                             float* __restrict__ out,
                                             float* __restrict__ bnsum8, float* __restrict__ bnsq8) {
  int t = threadIdx.x;
  int n = blockIdx.x * 16 + (t >> 4);
  int q = t & 15;
  const float4* h4 = (const float4*)h;
  float dv = dinv[n];
  float s2 = dv * dv;
  float4 acc0 = ((const float4*)bias)[q * 2];
  float4 acc1 = ((const float4*)bias)[q * 2 + 1];
  {
    float4 hv0 = h4[(size_t)n * 32 + q * 2];
    float4 hv1 = h4[(size_t)n * 32 + q * 2 + 1];
    acc0.x = fmaf(s2, hv0.x, acc0.x); acc0.y = fmaf(s2, hv0.y, acc0.y);
    acc0.z = fmaf(s2, hv0.z, acc0.z); acc0.w = fmaf(s2, hv0.w, acc0.w);
    acc1.x = fmaf(s2, hv1.x, acc1.x); acc1.y = fmaf(s2, hv1.y, acc1.y);
    acc1.z = fmaf(s2, hv1.z, acc1.z); acc1.w = fmaf(s2, hv1.w, acc1.w);
  }
  int lo = row_off[n], hi = row_off[n + 1];
  for (int j = lo; j < hi; ++j) {
    int s = csr_src[j];
    float w = csr_nrm[j];
    float4 v0 = h4[(size_t)s * 32 + q * 2];
    float4 v1 = h4[(size_t)s * 32 + q * 2 + 1];
    acc0.x = fmaf(w, v0.x, acc0.x); acc0.y = fmaf(w, v0.y, acc0.y);
    acc0.z = fmaf(w, v0.z, acc0.z); acc0.w = fmaf(w, v0.w, acc0.w);
    acc1.x = fmaf(w, v1.x, acc1.x); acc1.y = fmaf(w, v1.y, acc1.y);
    acc1.z = fmaf(w, v1.z, acc1.z); acc1.w = fmaf(w, v1.w, acc1.w);
  }
  ((float4*)out)[(size_t)n * 32 + q * 2] = acc0;
  ((float4*)out)[(size_t)n * 32 + q * 2 + 1] = acc1;

  if constexpr (STATS != 0) {
    __shared__ float red_s[16][FD], red_q[16][FD];
    int slot = t >> 4, f = q * 8;
    red_s[slot][f + 0] = acc0.x; red_s[slot][f + 1] = acc0.y;
    red_s[slot][f + 2] = acc0.z; red_s[slot][f + 3] = acc0.w;
    red_s[slot][f + 4] = acc1.x; red_s[slot][f + 5] = acc1.y;
    red_s[slot][f + 6] = acc1.z; red_s[slot][f + 7] = acc1.w;
    red_q[slot][f + 0] = acc0.x * acc0.x; red_q[slot][f + 1] = acc0.y * acc0.y;
    red_q[slot][f + 2] = acc0.z * acc0.z; red_q[slot][f + 3] = acc0.w * acc0.w;
    red_q[slot][f + 4] = acc1.x * acc1.x; red_q[slot][f + 5] = acc1.y * acc1.y;
    red_q[slot][f + 6] = acc1.z * acc1.z; red_q[slot][f + 7] = acc1.w * acc1.w;
    __syncthreads();
    if (t < FD) {
      float s = 0.f, qq = 0.f;
#pragma unroll
      for (int m = 0; m < 16; ++m) { s += red_s[m][t]; qq += red_q[m][t]; }
      int c = (blockIdx.x & 7) * FD + t;
      unsafeAtomicAdd(&bnsum8[c], s);
      unsafeAtomicAdd(&bnsq8[c], qq);
    }
  }
}

// ---------------- reduce 8-replica stats -> mu | scale ----------------
__global__ __launch_bounds__(128) void k_bn_final(const float* __restrict__ bn8, float* __restrict__ musc) {
  int f = threadIdx.x;
  float s = 0.f, q = 0.f;
#pragma unroll
  for (int c = 0; c < 8; ++c) { s += bn8[c * FD + f]; q += bn8[1024 + c * FD + f]; }
  float m = s * (1.0f / NN);
  float v = fmaxf(q * (1.0f / NN) - m * m, 0.f);
  musc[f] = m;
  musc[FD + f] = rsqrtf(v + EPS_BN);
}

// ---------------- graph boundaries + fused pool/head ----------------
__global__ __launch_bounds__(128) void k_gstart(const int* __restrict__ batch, int* __restrict__ gstart) {
  int g = blockIdx.x * 128 + threadIdx.x;
  if (g > NG) return;
  int lo = 0, hi = NN;
  while (lo < hi) {
    int mid = (lo + hi) >> 1;
    if (batch[mid] < g) lo = mid + 1; else hi = mid;
  }
  gstart[g] = lo;
}

__global__ __launch_bounds__(512) void k_poolfinal(const float* __restrict__ h, const int* __restrict__ gstart,
                                                   const float* __restrict__ Wlin, const float* __restrict__ blin,
                                                   float* __restrict__ out) {
  __shared__ float ps[4][FD];
  __shared__ float pp[FD];
  int g = blockIdx.x, t = threadIdx.x;
  int part = t >> 7, f = t & 127;
  int lo = gstart[g], hi = gstart[g + 1];
  float s = 0.f;
  for (int n = lo + part; n < hi; n += 4) s += h[(size_t)n * FD + f];
  ps[part][f] = s;
  __syncthreads();
  if (t < FD) {
    float tot = ps[0][t] + ps[1][t] + ps[2][t] + ps[3][t];
    pp[t] = tot * (1.0f / fmaxf((float)(hi - lo), 1.0f));
  }
  __syncthreads();
  if (t < NC) {
    float a = blin[t];
    for (int k = 0; k < FD; ++k) a = fmaf(pp[k], Wlin[t * FD + k], a);
    out[g * NC + t] = a;
  }
}

// ---------------- launch ----------------
extern "C" void kernel_launch(void* const* d_in, const int* in_sizes, int n_in,
                              void* d_out, int out_size, void* d_ws, size_t ws_size,
                              hipStream_t stream) {
  const float* x    = (const float*)d_in[0];
  const int*   ei   = (const int*)d_in[1];
  const int*   batch= (const int*)d_in[2];
  const float* W1   = (const float*)d_in[3];
  const float* b1   = (const float*)d_in[4];
  const float* W2   = (const float*)d_in[5];
  const float* b2   = (const float*)d_in[6];
  const float* W3   = (const float*)d_in[7];
  const float* b3   = (const float*)d_in[8];
  const float* Wlin = (const float*)d_in[9];
  const float* blin = (const float*)d_in[10];
  float* out = (float*)d_out;
  float* ws  = (float*)d_ws;

  const int* srcI = ei;
  const int* dstI = ei + NE;

  float* deg    = ws;                      // NN; in-edge count, then dinv
  float* bnA    = ws + 50048;              // 2048 (sum8 | sq8) layer1
  float* bnB    = bnA + 2048;              // 2048 layer2
  float* musc1  = bnB + 2048;              // 256 (mu | scale)
  float* musc2  = musc1 + 256;             // 256
  float* bufA   = musc2 + 256;             // NN*FD
  float* bufB   = bufA + NN * FD;          // NN*FD
  float* csr_nrm= bufB + NN * FD;          // NE
  int*   csr_src= (int*)(csr_nrm + NE);    // NE
  int*   row_off= csr_src + NE;            // NN+1
  int*   cursor = row_off + 50048;         // NN
  int*   gstart = cursor + 50048;          // NG+1 (pad 1024)
  int*   bsum   = gstart + 1024;           // NB (pad 256)
  int*   bbase  = bsum + 256;              // NB (pad 256)
  unsigned short* whi = (unsigned short*)(bbase + 256);  // 3*FD*FD
  unsigned short* wlo = whi + 3 * FD * FD;                // 3*FD*FD

  dim3 B(256);
  const int gE    = (NE + 255) / 256;
  const int gGemm = (NN / 16 + 3) / 4;   // 782 blocks, 4 row-tiles each (1/wave)
  const int gAgg  = NN / 16;             // 3125 exact

  // zero deg + bn accumulators + musc in one shot
  hipMemsetAsync(ws, 0, (50048 + 4096 + 512) * sizeof(float), stream);

  // degree -> CSR -> dinv
  k_deg_scatter<<<gE, B, 0, stream>>>(dstI, deg);
  k_bsum<<<NB, B, 0, stream>>>(deg, bsum);
  k_bscan<<<1, B, 0, stream>>>(bsum, bbase);
  k_rowoff<<<NB, B, 0, stream>>>(deg, bbase, row_off, cursor);
  k_fill<<<gE, B, 0, stream>>>(srcI, dstI, deg, cursor, csr_src, csr_nrm);
  k_gstart<<<5, 128, 0, stream>>>(batch, gstart);
  k_cvt_w<<<dim3(16, 3), B, 0, stream>>>(W1, W2, W3, whi, wlo);

  // layer 1
  k_gemm<0><<<gGemm, B, 0, stream>>>(x, nullptr, whi, wlo, bufA);
  k_agg<1><<<gAgg, B, 0, stream>>>(bufA, deg, b1, row_off, csr_src, csr_nrm, bufB, bnA, bnA + 1024);
  k_bn_final<<<1, 128, 0, stream>>>(bnA, musc1);

  // layer 2 (BN+ReLU fused into GEMM input path)
  k_gemm<1><<<gGemm, B, 0, stream>>>(bufB, musc1, whi + FD * FD, wlo + FD * FD, bufA);
  k_agg<1><<<gAgg, B, 0, stream>>>(bufA, deg, b2, row_off, csr_src, csr_nrm, bufB, bnB, bnB + 1024);
  k_bn_final<<<1, 128, 0, stream>>>(bnB, musc2);

  // layer 3
  k_gemm<1><<<gGemm, B, 0, stream>>>(bufB, musc2, whi + 2 * FD * FD, wlo + 2 * FD * FD, bufA);
  k_agg<0><<<gAgg, B, 0, stream>>>(bufA, deg, b3, row_off, csr_src, csr_nrm, bufB, nullptr, nullptr);

  // pool + head
  k_poolfinal<<<NG, 512, 0, stream>>>(bufB, gstart, Wlin, blin, out);
}

// Round 8
// 356.204 us; speedup vs baseline: 1.4557x; 1.0752x over previous
//
#include <hip/hip_runtime.h>
#include <hip/hip_bf16.h>

#define NN 50000
#define NE 600000
#define FD 128
#define NG 512
#define NC 10
static constexpr float EPS_BN = 1e-5f;

typedef __bf16 bf16x8 __attribute__((ext_vector_type(8)));
typedef float f32x4 __attribute__((ext_vector_type(4)));

__device__ __forceinline__ unsigned short f2bf(float x) {
  unsigned u = __float_as_uint(x);
  u = (u + 0x7FFFu + ((u >> 16) & 1u)) >> 16;
  return (unsigned short)u;
}
__device__ __forceinline__ float bf2f(unsigned short h) {
  return __uint_as_float(((unsigned)h) << 16);
}

// ---------------- degree (deg starts memset to 0; holds in-edge count) ----------------
__global__ __launch_bounds__(256) void k_deg_scatter(const int* __restrict__ dst, float* __restrict__ deg) {
  int e = blockIdx.x * 256 + threadIdx.x;
  if (e < NE) unsafeAtomicAdd(&deg[dst[e]], 1.0f);
}

// ---------------- CSR build: multi-block exclusive scan of in-edge counts ----------------
#define NB 196   // ceil(50000/256)
__global__ __launch_bounds__(256) void k_bsum(const float* __restrict__ deg, int* __restrict__ bsum) {
  __shared__ int s[256];
  int t = threadIdx.x, i = blockIdx.x * 256 + t;
  s[t] = (i < NN) ? (int)deg[i] : 0;
  __syncthreads();
  for (int o = 128; o > 0; o >>= 1) { if (t < o) s[t] += s[t + o]; __syncthreads(); }
  if (t == 0) bsum[blockIdx.x] = s[0];
}

__global__ __launch_bounds__(256) void k_bscan(const int* __restrict__ bsum, int* __restrict__ bbase) {
  __shared__ int s[256];
  int t = threadIdx.x;
  int v = (t < NB) ? bsum[t] : 0;
  s[t] = v; __syncthreads();
  for (int o = 1; o < 256; o <<= 1) {
    int a = (t >= o) ? s[t - o] : 0; __syncthreads();
    s[t] += a; __syncthreads();
  }
  if (t < NB) bbase[t] = s[t] - v;
}

// also transforms deg (count) -> dinv = rsqrt(count+1)
__global__ __launch_bounds__(256) void k_rowoff(float* __restrict__ deg, const int* __restrict__ bbase,
                                                int* __restrict__ row_off, int* __restrict__ cursor) {
  __shared__ int s[256];
  int t = threadIdx.x, i = blockIdx.x * 256 + t;
  float dv = (i < NN) ? deg[i] : 0.f;
  int c = (int)dv;
  s[t] = c; __syncthreads();
  for (int o = 1; o < 256; o <<= 1) {
    int a = (t >= o) ? s[t - o] : 0; __syncthreads();
    s[t] += a; __syncthreads();
  }
  int excl = s[t] - c + bbase[blockIdx.x];
  if (i <= NN) {
    row_off[i] = excl;
    if (i < NN) {
      cursor[i] = excl;
      deg[i] = rsqrtf(dv + 1.0f);
    }
  }
}

__global__ __launch_bounds__(256) void k_fill(const int* __restrict__ src, const int* __restrict__ dst,
                                              const float* __restrict__ dinv, int* __restrict__ cursor,
                                              int* __restrict__ csr_src, float* __restrict__ csr_nrm) {
  int e = blockIdx.x * 256 + threadIdx.x;
  if (e >= NE) return;
  int s = src[e], d = dst[e];
  int pos = atomicAdd(&cursor[d], 1);
  csr_src[pos] = s;
  csr_nrm[pos] = dinv[s] * dinv[d];
}

// ---------------- weights fp32 -> bf16 hi/lo ----------------
__global__ __launch_bounds__(256) void k_cvt_w(const float* __restrict__ W1, const float* __restrict__ W2,
                                               const float* __restrict__ W3,
                                               unsigned short* __restrict__ whi, unsigned short* __restrict__ wlo) {
  int m = blockIdx.y;
  const float* W = (m == 0) ? W1 : ((m == 1) ? W2 : W3);
  int i = blockIdx.x * 256 + threadIdx.x;
  if (i >= FD * FD / 4) return;
  float4 v = ((const float4*)W)[i];
  ushort4 hv, lv;
  hv.x = f2bf(v.x); lv.x = f2bf(v.x - bf2f(hv.x));
  hv.y = f2bf(v.y); lv.y = f2bf(v.y - bf2f(hv.y));
  hv.z = f2bf(v.z); lv.z = f2bf(v.z - bf2f(hv.z));
  hv.w = f2bf(v.w); lv.w = f2bf(v.w - bf2f(hv.w));
  ((ushort4*)(whi + m * FD * FD))[i] = hv;
  ((ushort4*)(wlo + m * FD * FD))[i] = lv;
}

// ---------------- MFMA GEMM: W staged in LDS (XOR-swizzled), fused input-BN+ReLU+bf16 split ----
// out[r][c] = sum_k f(in[r][k]) * W[c][k]; 2 row-tiles/wave; grid 391 blocks x 8 rt
template <int BN>
__global__ __launch_bounds__(256) void k_gemm(const float* __restrict__ in, const float* __restrict__ musc,
                                              const unsigned short* __restrict__ whi,
                                              const unsigned short* __restrict__ wlo,
                                              float* __restrict__ out) {
  __shared__ unsigned short w_lds[2 * FD * FD];   // 64KB: [half][row][col] with 16B XOR swizzle
  int t = threadIdx.x;
  // stage whi+wlo: 2048 chunks of 16B per half, 8 chunks/thread, coalesced
#pragma unroll
  for (int half = 0; half < 2; ++half) {
    const unsigned short* src = half ? wlo : whi;
#pragma unroll
    for (int c = 0; c < 8; ++c) {
      int chunk = c * 256 + t;              // 0..2047
      int row = chunk >> 4, c8 = (chunk & 15) * 8;
      uint4 v = *(const uint4*)(src + chunk * 8);
      *(uint4*)(w_lds + half * FD * FD + row * FD + (c8 ^ ((row & 7) << 3))) = v;
    }
  }
  __syncthreads();

  int w = t >> 6, l = t & 63;
  int rt0 = blockIdx.x * 8 + w;
  int rt1 = rt0 + 4;
  bool v1 = rt1 < NN / 16;
  if (rt0 >= NN / 16) return;
  int r = l & 15, g = l >> 4;
  int ko = g * 8;
  f32x4 acc0[8], acc1[8];
#pragma unroll
  for (int ct = 0; ct < 8; ++ct) {
    acc0[ct] = (f32x4){0.f, 0.f, 0.f, 0.f};
    acc1[ct] = (f32x4){0.f, 0.f, 0.f, 0.f};
  }

#pragma unroll
  for (int kk = 0; kk < FD; kk += 32) {
    float a0[8], a1[8];
    {
      const float* p0 = in + (size_t)(rt0 * 16 + r) * FD + kk + ko;
      float4 x0 = *(const float4*)p0;
      float4 x1 = *(const float4*)(p0 + 4);
      a0[0] = x0.x; a0[1] = x0.y; a0[2] = x0.z; a0[3] = x0.w;
      a0[4] = x1.x; a0[5] = x1.y; a0[6] = x1.z; a0[7] = x1.w;
    }
    if (v1) {
      const float* p1 = in + (size_t)(rt1 * 16 + r) * FD + kk + ko;
      float4 x0 = *(const float4*)p1;
      float4 x1 = *(const float4*)(p1 + 4);
      a1[0] = x0.x; a1[1] = x0.y; a1[2] = x0.z; a1[3] = x0.w;
      a1[4] = x1.x; a1[5] = x1.y; a1[6] = x1.z; a1[7] = x1.w;
    } else {
#pragma unroll
      for (int i = 0; i < 8; ++i) a1[i] = 0.f;
    }
    if constexpr (BN != 0) {
      const float* mp = musc + kk + ko;
      float4 m0 = *(const float4*)mp, m1 = *(const float4*)(mp + 4);
      float4 s0 = *(const float4*)(mp + FD), s1 = *(const float4*)(mp + FD + 4);
      float mu[8] = {m0.x, m0.y, m0.z, m0.w, m1.x, m1.y, m1.z, m1.w};
      float sc[8] = {s0.x, s0.y, s0.z, s0.w, s1.x, s1.y, s1.z, s1.w};
#pragma unroll
      for (int i = 0; i < 8; ++i) {
        a0[i] = fmaxf((a0[i] - mu[i]) * sc[i], 0.f);
        a1[i] = fmaxf((a1[i] - mu[i]) * sc[i], 0.f);
      }
    }
    bf16x8 ah0, al0, ah1, al1;
#pragma unroll
    for (int i = 0; i < 8; ++i) {
      __bf16 h0 = (__bf16)a0[i];
      ah0[i] = h0; al0[i] = (__bf16)(a0[i] - (float)h0);
      __bf16 h1 = (__bf16)a1[i];
      ah1[i] = h1; al1[i] = (__bf16)(a1[i] - (float)h1);
    }
#pragma unroll
    for (int ct = 0; ct < 8; ++ct) {
      int row = ct * 16 + r;
      int idx = row * FD + ((kk + ko) ^ ((r & 7) << 3));
      bf16x8 bh = *(const bf16x8*)(w_lds + idx);
      bf16x8 bl = *(const bf16x8*)(w_lds + FD * FD + idx);
      acc0[ct] = __builtin_amdgcn_mfma_f32_16x16x32_bf16(ah0, bh, acc0[ct], 0, 0, 0);
      acc0[ct] = __builtin_amdgcn_mfma_f32_16x16x32_bf16(ah0, bl, acc0[ct], 0, 0, 0);
      acc0[ct] = __builtin_amdgcn_mfma_f32_16x16x32_bf16(al0, bh, acc0[ct], 0, 0, 0);
      if (v1) {
        acc1[ct] = __builtin_amdgcn_mfma_f32_16x16x32_bf16(ah1, bh, acc1[ct], 0, 0, 0);
        acc1[ct] = __builtin_amdgcn_mfma_f32_16x16x32_bf16(ah1, bl, acc1[ct], 0, 0, 0);
        acc1[ct] = __builtin_amdgcn_mfma_f32_16x16x32_bf16(al1, bh, acc1[ct], 0, 0, 0);
      }
    }
  }
  // C/D layout: col = lane&15 (=r), row = g*4 + reg
#pragma unroll
  for (int ct = 0; ct < 8; ++ct)
#pragma unroll
    for (int i = 0; i < 4; ++i) {
      out[(size_t)(rt0 * 16 + g * 4 + i) * FD + ct * 16 + r] = acc0[ct][i];
      if (v1) out[(size_t)(rt1 * 16 + g * 4 + i) * FD + ct * 16 + r] = acc1[ct][i];
    }
}

// ---------------- aggregation: 16 lanes/node (R7 loop, byte-identical) + padded stats ----------------
template <int STATS>
__global__ __launch_bounds__(256) void k_agg(const float* __restrict__ h, const float* __restrict__ dinv,
                                             const float* __restrict__ bias, const int* __restrict__ row_off,
                                             const int* __restrict__ csr_src, const float* __restrict__ csr_nrm,
                                             float* __restrict__ out,
                                             float* __restrict__ bnsum8, float* __restrict__ bnsq8) {
  int t = threadIdx.x;
  int n = blockIdx.x * 16 + (t >> 4);
  int q = t & 15;
  const float4* h4 = (const float4*)h;
  float dv = dinv[n];
  float s2 = dv * dv;
  float4 acc0 = ((const float4*)bias)[q * 2];
  float4 acc1 = ((const float4*)bias)[q * 2 + 1];
  {
    float4 hv0 = h4[(size_t)n * 32 + q * 2];
    float4 hv1 = h4[(size_t)n * 32 + q * 2 + 1];
    acc0.x = fmaf(s2, hv0.x, acc0.x); acc0.y = fmaf(s2, hv0.y, acc0.y);
    acc0.z = fmaf(s2, hv0.z, acc0.z); acc0.w = fmaf(s2, hv0.w, acc0.w);
    acc1.x = fmaf(s2, hv1.x, acc1.x); acc1.y = fmaf(s2, hv1.y, acc1.y);
    acc1.z = fmaf(s2, hv1.z, acc1.z); acc1.w = fmaf(s2, hv1.w, acc1.w);
  }
  int lo = row_off[n], hi = row_off[n + 1];
  for (int j = lo; j < hi; ++j) {
    int s = csr_src[j];
    float w = csr_nrm[j];
    float4 v0 = h4[(size_t)s * 32 + q * 2];
    float4 v1 = h4[(size_t)s * 32 + q * 2 + 1];
    acc0.x = fmaf(w, v0.x, acc0.x); acc0.y = fmaf(w, v0.y, acc0.y);
    acc0.z = fmaf(w, v0.z, acc0.z); acc0.w = fmaf(w, v0.w, acc0.w);
    acc1.x = fmaf(w, v1.x, acc1.x); acc1.y = fmaf(w, v1.y, acc1.y);
    acc1.z = fmaf(w, v1.z, acc1.z); acc1.w = fmaf(w, v1.w, acc1.w);
  }
  ((float4*)out)[(size_t)n * 32 + q * 2] = acc0;
  ((float4*)out)[(size_t)n * 32 + q * 2 + 1] = acc1;

  if constexpr (STATS != 0) {
    __shared__ float red_s[16][FD + 4], red_q[16][FD + 4];
    int slot = t >> 4, f = q * 8;
    red_s[slot][f + 0] = acc0.x; red_s[slot][f + 1] = acc0.y;
    red_s[slot][f + 2] = acc0.z; red_s[slot][f + 3] = acc0.w;
    red_s[slot][f + 4] = acc1.x; red_s[slot][f + 5] = acc1.y;
    red_s[slot][f + 6] = acc1.z; red_s[slot][f + 7] = acc1.w;
    red_q[slot][f + 0] = acc0.x * acc0.x; red_q[slot][f + 1] = acc0.y * acc0.y;
    red_q[slot][f + 2] = acc0.z * acc0.z; red_q[slot][f + 3] = acc0.w * acc0.w;
    red_q[slot][f + 4] = acc1.x * acc1.x; red_q[slot][f + 5] = acc1.y * acc1.y;
    red_q[slot][f + 6] = acc1.z * acc1.z; red_q[slot][f + 7] = acc1.w * acc1.w;
    __syncthreads();
    if (t < FD) {
      float s = 0.f, qq = 0.f;
#pragma unroll
      for (int m = 0; m < 16; ++m) { s += red_s[m][t]; qq += red_q[m][t]; }
      int c = (blockIdx.x & 7) * FD + t;
      unsafeAtomicAdd(&bnsum8[c], s);
      unsafeAtomicAdd(&bnsq8[c], qq);
    }
  }
}

// ---------------- reduce 8-replica stats -> mu | scale ----------------
__global__ __launch_bounds__(128) void k_bn_final(const float* __restrict__ bn8, float* __restrict__ musc) {
  int f = threadIdx.x;
  float s = 0.f, q = 0.f;
#pragma unroll
  for (int c = 0; c < 8; ++c) { s += bn8[c * FD + f]; q += bn8[1024 + c * FD + f]; }
  float m = s * (1.0f / NN);
  float v = fmaxf(q * (1.0f / NN) - m * m, 0.f);
  musc[f] = m;
  musc[FD + f] = rsqrtf(v + EPS_BN);
}

// ---------------- graph boundaries + fused pool/head ----------------
__global__ __launch_bounds__(128) void k_gstart(const int* __restrict__ batch, int* __restrict__ gstart) {
  int g = blockIdx.x * 128 + threadIdx.x;
  if (g > NG) return;
  int lo = 0, hi = NN;
  while (lo < hi) {
    int mid = (lo + hi) >> 1;
    if (batch[mid] < g) lo = mid + 1; else hi = mid;
  }
  gstart[g] = lo;
}

__global__ __launch_bounds__(512) void k_poolfinal(const float* __restrict__ h, const int* __restrict__ gstart,
                                                   const float* __restrict__ Wlin, const float* __restrict__ blin,
                                                   float* __restrict__ out) {
  __shared__ float ps[4][FD];
  __shared__ float pp[FD];
  int g = blockIdx.x, t = threadIdx.x;
  int part = t >> 7, f = t & 127;
  int lo = gstart[g], hi = gstart[g + 1];
  float s = 0.f;
  for (int n = lo + part; n < hi; n += 4) s += h[(size_t)n * FD + f];
  ps[part][f] = s;
  __syncthreads();
  if (t < FD) {
    float tot = ps[0][t] + ps[1][t] + ps[2][t] + ps[3][t];
    pp[t] = tot * (1.0f / fmaxf((float)(hi - lo), 1.0f));
  }
  __syncthreads();
  if (t < NC) {
    float a = blin[t];
    for (int k = 0; k < FD; ++k) a = fmaf(pp[k], Wlin[t * FD + k], a);
    out[g * NC + t] = a;
  }
}

// ---------------- launch ----------------
extern "C" void kernel_launch(void* const* d_in, const int* in_sizes, int n_in,
                              void* d_out, int out_size, void* d_ws, size_t ws_size,
                              hipStream_t stream) {
  const float* x    = (const float*)d_in[0];
  const int*   ei   = (const int*)d_in[1];
  const int*   batch= (const int*)d_in[2];
  const float* W1   = (const float*)d_in[3];
  const float* b1   = (const float*)d_in[4];
  const float* W2   = (const float*)d_in[5];
  const float* b2   = (const float*)d_in[6];
  const float* W3   = (const float*)d_in[7];
  const float* b3   = (const float*)d_in[8];
  const float* Wlin = (const float*)d_in[9];
  const float* blin = (const float*)d_in[10];
  float* out = (float*)d_out;
  float* ws  = (float*)d_ws;

  const int* srcI = ei;
  const int* dstI = ei + NE;

  float* deg    = ws;                      // NN; in-edge count, then dinv
  float* bnA    = ws + 50048;              // 2048 (sum8 | sq8) layer1
  float* bnB    = bnA + 2048;              // 2048 layer2
  float* musc1  = bnB + 2048;              // 256 (mu | scale)
  float* musc2  = musc1 + 256;             // 256
  float* bufA   = musc2 + 256;             // NN*FD
  float* bufB   = bufA + NN * FD;          // NN*FD
  float* csr_nrm= bufB + NN * FD;          // NE
  int*   csr_src= (int*)(csr_nrm + NE);    // NE
  int*   row_off= csr_src + NE;            // NN+1
  int*   cursor = row_off + 50048;         // NN
  int*   gstart = cursor + 50048;          // NG+1 (pad 1024)
  int*   bsum   = gstart + 1024;           // NB (pad 256)
  int*   bbase  = bsum + 256;              // NB (pad 256)
  unsigned short* whi = (unsigned short*)(bbase + 256);  // 3*FD*FD
  unsigned short* wlo = whi + 3 * FD * FD;                // 3*FD*FD

  dim3 B(256);
  const int gE    = (NE + 255) / 256;
  const int gGemm = (NN / 16 + 7) / 8;   // 391 blocks, 8 row-tiles, 2/wave
  const int gAgg  = NN / 16;             // 3125 exact

  // zero deg + bn accumulators + musc in one shot
  hipMemsetAsync(ws, 0, (50048 + 4096 + 512) * sizeof(float), stream);

  // degree -> CSR -> dinv
  k_deg_scatter<<<gE, B, 0, stream>>>(dstI, deg);
  k_bsum<<<NB, B, 0, stream>>>(deg, bsum);
  k_bscan<<<1, B, 0, stream>>>(bsum, bbase);
  k_rowoff<<<NB, B, 0, stream>>>(deg, bbase, row_off, cursor);
  k_fill<<<gE, B, 0, stream>>>(srcI, dstI, deg, cursor, csr_src, csr_nrm);
  k_gstart<<<5, 128, 0, stream>>>(batch, gstart);
  k_cvt_w<<<dim3(16, 3), B, 0, stream>>>(W1, W2, W3, whi, wlo);

  // layer 1
  k_gemm<0><<<gGemm, B, 0, stream>>>(x, nullptr, whi, wlo, bufA);
  k_agg<1><<<gAgg, B, 0, stream>>>(bufA, deg, b1, row_off, csr_src, csr_nrm, bufB, bnA, bnA + 1024);
  k_bn_final<<<1, 128, 0, stream>>>(bnA, musc1);

  // layer 2 (BN+ReLU fused into GEMM input path)
  k_gemm<1><<<gGemm, B, 0, stream>>>(bufB, musc1, whi + FD * FD, wlo + FD * FD, bufA);
  k_agg<1><<<gAgg, B, 0, stream>>>(bufA, deg, b2, row_off, csr_src, csr_nrm, bufB, bnB, bnB + 1024);
  k_bn_final<<<1, 128, 0, stream>>>(bnB, musc2);

  // layer 3
  k_gemm<1><<<gGemm, B, 0, stream>>>(bufB, musc2, whi + 2 * FD * FD, wlo + 2 * FD * FD, bufA);
  k_agg<0><<<gAgg, B, 0, stream>>>(bufA, deg, b3, row_off, csr_src, csr_nrm, bufB, nullptr, nullptr);

  // pool + head
  k_poolfinal<<<NG, 512, 0, stream>>>(bufB, gstart, Wlin, blin, out);
}

// Round 9
// 342.528 us; speedup vs baseline: 1.5138x; 1.0399x over previous
//
#include <hip/hip_runtime.h>
#include <hip/hip_bf16.h>

#define NN 50000
#define NE 600000
#define FD 128
#define NG 512
#define NC 10
static constexpr float EPS_BN = 1e-5f;

typedef __bf16 bf16x8 __attribute__((ext_vector_type(8)));
typedef float f32x4 __attribute__((ext_vector_type(4)));

__device__ __forceinline__ unsigned short f2bf(float x) {
  unsigned u = __float_as_uint(x);
  u = (u + 0x7FFFu + ((u >> 16) & 1u)) >> 16;
  return (unsigned short)u;
}
__device__ __forceinline__ float bf2f(unsigned short h) {
  return __uint_as_float(((unsigned)h) << 16);
}

// ---------------- degree (deg memset to 0; holds in-edge count) ----------------
__global__ __launch_bounds__(256) void k_deg_scatter(const int* __restrict__ dst, float* __restrict__ deg) {
  int e = blockIdx.x * 256 + threadIdx.x;
  if (e < NE) unsafeAtomicAdd(&deg[dst[e]], 1.0f);
}

// ---------------- CSR build: multi-block exclusive scan of in-edge counts ----------------
#define NB 196   // ceil(50000/256)
__global__ __launch_bounds__(256) void k_bsum(const float* __restrict__ deg, int* __restrict__ bsum) {
  __shared__ int s[256];
  int t = threadIdx.x, i = blockIdx.x * 256 + t;
  s[t] = (i < NN) ? (int)deg[i] : 0;
  __syncthreads();
  for (int o = 128; o > 0; o >>= 1) { if (t < o) s[t] += s[t + o]; __syncthreads(); }
  if (t == 0) bsum[blockIdx.x] = s[0];
}

__global__ __launch_bounds__(256) void k_bscan(const int* __restrict__ bsum, int* __restrict__ bbase) {
  __shared__ int s[256];
  int t = threadIdx.x;
  int v = (t < NB) ? bsum[t] : 0;
  s[t] = v; __syncthreads();
  for (int o = 1; o < 256; o <<= 1) {
    int a = (t >= o) ? s[t - o] : 0; __syncthreads();
    s[t] += a; __syncthreads();
  }
  if (t < NB) bbase[t] = s[t] - v;
}

// also transforms deg (count) -> dinv = rsqrt(count+1)
__global__ __launch_bounds__(256) void k_rowoff(float* __restrict__ deg, const int* __restrict__ bbase,
                                                int* __restrict__ row_off, int* __restrict__ cursor) {
  __shared__ int s[256];
  int t = threadIdx.x, i = blockIdx.x * 256 + t;
  float dv = (i < NN) ? deg[i] : 0.f;
  int c = (int)dv;
  s[t] = c; __syncthreads();
  for (int o = 1; o < 256; o <<= 1) {
    int a = (t >= o) ? s[t - o] : 0; __syncthreads();
    s[t] += a; __syncthreads();
  }
  int excl = s[t] - c + bbase[blockIdx.x];
  if (i <= NN) {
    row_off[i] = excl;
    if (i < NN) {
      cursor[i] = excl;
      deg[i] = rsqrtf(dv + 1.0f);
    }
  }
}

// ---------------- fused preamble: CSR fill + weight cvt(pre-swizzled) + gstart ----------------
// blocks [0,2344): fill; [2344,2392): cvt_w; [2392,2395): gstart
#define PRE_FILL 2344
#define PRE_CVT  48
__global__ __launch_bounds__(256) void k_pre(const int* __restrict__ src, const int* __restrict__ dst,
                                             const float* __restrict__ dinv, int* __restrict__ cursor,
                                             int2* __restrict__ csr,
                                             const float* __restrict__ W1, const float* __restrict__ W2,
                                             const float* __restrict__ W3, unsigned short* __restrict__ w2,
                                             const int* __restrict__ batch, int* __restrict__ gstart) {
  int b = blockIdx.x, t = threadIdx.x;
  if (b < PRE_FILL) {
    int e = b * 256 + t;
    if (e >= NE) return;
    int s = src[e], d = dst[e];
    float nrm = dinv[s] * dinv[d];
    int pos = atomicAdd(&cursor[d], 1);
    csr[pos] = make_int2(s, __float_as_int(nrm));
  } else if (b < PRE_FILL + PRE_CVT) {
    int bb = b - PRE_FILL;
    int m = bb >> 4;
    const float* W = (m == 0) ? W1 : ((m == 1) ? W2 : W3);
    int i = (bb & 15) * 256 + t;           // 0..4095, 4 elems each
    float4 v = ((const float4*)W)[i];
    ushort4 hv, lv;
    hv.x = f2bf(v.x); lv.x = f2bf(v.x - bf2f(hv.x));
    hv.y = f2bf(v.y); lv.y = f2bf(v.y - bf2f(hv.y));
    hv.z = f2bf(v.z); lv.z = f2bf(v.z - bf2f(hv.z));
    hv.w = f2bf(v.w); lv.w = f2bf(v.w - bf2f(hv.w));
    int e0 = i * 4, row = e0 >> 7, col = e0 & 127;
    int sc_ = ((col & 120) ^ ((row & 7) << 3)) | (col & 7);   // 16B-group XOR swizzle
    unsigned short* base = w2 + m * 32768 + row * FD + sc_;
    *(ushort4*)base = hv;
    *(ushort4*)(base + 16384) = lv;
  } else {
    int g = (b - PRE_FILL - PRE_CVT) * 256 + t;
    if (g > NG) return;
    int lo = 0, hi = NN;
    while (lo < hi) {
      int mid = (lo + hi) >> 1;
      if (batch[mid] < g) lo = mid + 1; else hi = mid;
    }
    gstart[g] = lo;
  }
}

// ---------------- MFMA GEMM: W LDS-staged (pre-swizzled, linear copy), fused BN+ReLU+split,
//                  fused musc reduction from 8-replica stats ----------------
template <int BN>
__global__ __launch_bounds__(256) void k_gemm(const float* __restrict__ in, const float* __restrict__ bn8,
                                              const unsigned short* __restrict__ wsrc,
                                              float* __restrict__ out) {
  __shared__ unsigned short w_lds[2 * FD * FD];   // 64KB, already swizzled
  __shared__ float s_musc[2 * FD];
  int t = threadIdx.x;
  {
    const uint4* s4 = (const uint4*)wsrc;
    uint4* d4 = (uint4*)w_lds;
#pragma unroll
    for (int c = 0; c < 16; ++c) d4[c * 256 + t] = s4[c * 256 + t];
  }
  if constexpr (BN != 0) {
    if (t < FD) {
      float s = 0.f, q = 0.f;
#pragma unroll
      for (int c = 0; c < 8; ++c) { s += bn8[c * FD + t]; q += bn8[1024 + c * FD + t]; }
      float m = s * (1.0f / NN);
      float v = fmaxf(q * (1.0f / NN) - m * m, 0.f);
      s_musc[t] = m;
      s_musc[FD + t] = rsqrtf(v + EPS_BN);
    }
  }
  __syncthreads();

  int w = t >> 6, l = t & 63;
  int rt0 = blockIdx.x * 8 + w;
  int rt1 = rt0 + 4;
  bool v1 = rt1 < NN / 16;
  if (rt0 >= NN / 16) return;
  int r = l & 15, g = l >> 4;
  int ko = g * 8;
  f32x4 acc0[8], acc1[8];
#pragma unroll
  for (int ct = 0; ct < 8; ++ct) {
    acc0[ct] = (f32x4){0.f, 0.f, 0.f, 0.f};
    acc1[ct] = (f32x4){0.f, 0.f, 0.f, 0.f};
  }

#pragma unroll
  for (int kk = 0; kk < FD; kk += 32) {
    float a0[8], a1[8];
    {
      const float* p0 = in + (size_t)(rt0 * 16 + r) * FD + kk + ko;
      float4 x0 = *(const float4*)p0;
      float4 x1 = *(const float4*)(p0 + 4);
      a0[0] = x0.x; a0[1] = x0.y; a0[2] = x0.z; a0[3] = x0.w;
      a0[4] = x1.x; a0[5] = x1.y; a0[6] = x1.z; a0[7] = x1.w;
    }
    if (v1) {
      const float* p1 = in + (size_t)(rt1 * 16 + r) * FD + kk + ko;
      float4 x0 = *(const float4*)p1;
      float4 x1 = *(const float4*)(p1 + 4);
      a1[0] = x0.x; a1[1] = x0.y; a1[2] = x0.z; a1[3] = x0.w;
      a1[4] = x1.x; a1[5] = x1.y; a1[6] = x1.z; a1[7] = x1.w;
    } else {
#pragma unroll
      for (int i = 0; i < 8; ++i) a1[i] = 0.f;
    }
    if constexpr (BN != 0) {
      const float* mp = s_musc + kk + ko;
      float4 m0 = *(const float4*)mp, m1 = *(const float4*)(mp + 4);
      float4 s0 = *(const float4*)(mp + FD), s1 = *(const float4*)(mp + FD + 4);
      float mu[8] = {m0.x, m0.y, m0.z, m0.w, m1.x, m1.y, m1.z, m1.w};
      float sc[8] = {s0.x, s0.y, s0.z, s0.w, s1.x, s1.y, s1.z, s1.w};
#pragma unroll
      for (int i = 0; i < 8; ++i) {
        a0[i] = fmaxf((a0[i] - mu[i]) * sc[i], 0.f);
        a1[i] = fmaxf((a1[i] - mu[i]) * sc[i], 0.f);
      }
    }
    bf16x8 ah0, al0, ah1, al1;
#pragma unroll
    for (int i = 0; i < 8; ++i) {
      __bf16 h0 = (__bf16)a0[i];
      ah0[i] = h0; al0[i] = (__bf16)(a0[i] - (float)h0);
      __bf16 h1 = (__bf16)a1[i];
      ah1[i] = h1; al1[i] = (__bf16)(a1[i] - (float)h1);
    }
#pragma unroll
    for (int ct = 0; ct < 8; ++ct) {
      int row = ct * 16 + r;
      int idx = row * FD + ((kk + ko) ^ ((r & 7) << 3));
      bf16x8 bh = *(const bf16x8*)(w_lds + idx);
      bf16x8 bl = *(const bf16x8*)(w_lds + FD * FD + idx);
      acc0[ct] = __builtin_amdgcn_mfma_f32_16x16x32_bf16(ah0, bh, acc0[ct], 0, 0, 0);
      acc0[ct] = __builtin_amdgcn_mfma_f32_16x16x32_bf16(ah0, bl, acc0[ct], 0, 0, 0);
      acc0[ct] = __builtin_amdgcn_mfma_f32_16x16x32_bf16(al0, bh, acc0[ct], 0, 0, 0);
      if (v1) {
        acc1[ct] = __builtin_amdgcn_mfma_f32_16x16x32_bf16(ah1, bh, acc1[ct], 0, 0, 0);
        acc1[ct] = __builtin_amdgcn_mfma_f32_16x16x32_bf16(ah1, bl, acc1[ct], 0, 0, 0);
        acc1[ct] = __builtin_amdgcn_mfma_f32_16x16x32_bf16(al1, bh, acc1[ct], 0, 0, 0);
      }
    }
  }
#pragma unroll
  for (int ct = 0; ct < 8; ++ct)
#pragma unroll
    for (int i = 0; i < 4; ++i) {
      out[(size_t)(rt0 * 16 + g * 4 + i) * FD + ct * 16 + r] = acc0[ct][i];
      if (v1) out[(size_t)(rt1 * 16 + g * 4 + i) * FD + ct * 16 + r] = acc1[ct][i];
    }
}

// ---------------- aggregation: 16 lanes/node, int2 CSR, R7 loop shape ----------------
template <int STATS>
__global__ __launch_bounds__(256) void k_agg(const float* __restrict__ h, const float* __restrict__ dinv,
                                             const float* __restrict__ bias, const int* __restrict__ row_off,
                                             const int2* __restrict__ csr, float* __restrict__ out,
                                             float* __restrict__ bn8) {
  int t = threadIdx.x;
  int n = blockIdx.x * 16 + (t >> 4);
  int q = t & 15;
  const float4* h4 = (const float4*)h;
  float dv = dinv[n];
  float s2 = dv * dv;
  float4 acc0 = ((const float4*)bias)[q * 2];
  float4 acc1 = ((const float4*)bias)[q * 2 + 1];
  {
    float4 hv0 = h4[(size_t)n * 32 + q * 2];
    float4 hv1 = h4[(size_t)n * 32 + q * 2 + 1];
    acc0.x = fmaf(s2, hv0.x, acc0.x); acc0.y = fmaf(s2, hv0.y, acc0.y);
    acc0.z = fmaf(s2, hv0.z, acc0.z); acc0.w = fmaf(s2, hv0.w, acc0.w);
    acc1.x = fmaf(s2, hv1.x, acc1.x); acc1.y = fmaf(s2, hv1.y, acc1.y);
    acc1.z = fmaf(s2, hv1.z, acc1.z); acc1.w = fmaf(s2, hv1.w, acc1.w);
  }
  int lo = row_off[n], hi = row_off[n + 1];
  for (int j = lo; j < hi; ++j) {
    int2 e = csr[j];
    float w = __int_as_float(e.y);
    float4 v0 = h4[(size_t)e.x * 32 + q * 2];
    float4 v1 = h4[(size_t)e.x * 32 + q * 2 + 1];
    acc0.x = fmaf(w, v0.x, acc0.x); acc0.y = fmaf(w, v0.y, acc0.y);
    acc0.z = fmaf(w, v0.z, acc0.z); acc0.w = fmaf(w, v0.w, acc0.w);
    acc1.x = fmaf(w, v1.x, acc1.x); acc1.y = fmaf(w, v1.y, acc1.y);
    acc1.z = fmaf(w, v1.z, acc1.z); acc1.w = fmaf(w, v1.w, acc1.w);
  }
  ((float4*)out)[(size_t)n * 32 + q * 2] = acc0;
  ((float4*)out)[(size_t)n * 32 + q * 2 + 1] = acc1;

  if constexpr (STATS != 0) {
    __shared__ float red_s[16][FD + 4], red_q[16][FD + 4];
    int slot = t >> 4, f = q * 8;
    red_s[slot][f + 0] = acc0.x; red_s[slot][f + 1] = acc0.y;
    red_s[slot][f + 2] = acc0.z; red_s[slot][f + 3] = acc0.w;
    red_s[slot][f + 4] = acc1.x; red_s[slot][f + 5] = acc1.y;
    red_s[slot][f + 6] = acc1.z; red_s[slot][f + 7] = acc1.w;
    red_q[slot][f + 0] = acc0.x * acc0.x; red_q[slot][f + 1] = acc0.y * acc0.y;
    red_q[slot][f + 2] = acc0.z * acc0.z; red_q[slot][f + 3] = acc0.w * acc0.w;
    red_q[slot][f + 4] = acc1.x * acc1.x; red_q[slot][f + 5] = acc1.y * acc1.y;
    red_q[slot][f + 6] = acc1.z * acc1.z; red_q[slot][f + 7] = acc1.w * acc1.w;
    __syncthreads();
    if (t < FD) {
      float s = 0.f, qq = 0.f;
#pragma unroll
      for (int m = 0; m < 16; ++m) { s += red_s[m][t]; qq += red_q[m][t]; }
      int c = (blockIdx.x & 7) * FD + t;
      unsafeAtomicAdd(&bn8[c], s);
      unsafeAtomicAdd(&bn8[1024 + c], qq);
    }
  }
}

// ---------------- fused pool/head ----------------
__global__ __launch_bounds__(512) void k_poolfinal(const float* __restrict__ h, const int* __restrict__ gstart,
                                                   const float* __restrict__ Wlin, const float* __restrict__ blin,
                                                   float* __restrict__ out) {
  __shared__ float ps[4][FD];
  __shared__ float pp[FD];
  int g = blockIdx.x, t = threadIdx.x;
  int part = t >> 7, f = t & 127;
  int lo = gstart[g], hi = gstart[g + 1];
  float s = 0.f;
  for (int n = lo + part; n < hi; n += 4) s += h[(size_t)n * FD + f];
  ps[part][f] = s;
  __syncthreads();
  if (t < FD) {
    float tot = ps[0][t] + ps[1][t] + ps[2][t] + ps[3][t];
    pp[t] = tot * (1.0f / fmaxf((float)(hi - lo), 1.0f));
  }
  __syncthreads();
  if (t < NC) {
    float a = blin[t];
    for (int k = 0; k < FD; ++k) a = fmaf(pp[k], Wlin[t * FD + k], a);
    out[g * NC + t] = a;
  }
}

// ---------------- launch ----------------
extern "C" void kernel_launch(void* const* d_in, const int* in_sizes, int n_in,
                              void* d_out, int out_size, void* d_ws, size_t ws_size,
                              hipStream_t stream) {
  const float* x    = (const float*)d_in[0];
  const int*   ei   = (const int*)d_in[1];
  const int*   batch= (const int*)d_in[2];
  const float* W1   = (const float*)d_in[3];
  const float* b1   = (const float*)d_in[4];
  const float* W2   = (const float*)d_in[5];
  const float* b2   = (const float*)d_in[6];
  const float* W3   = (const float*)d_in[7];
  const float* b3   = (const float*)d_in[8];
  const float* Wlin = (const float*)d_in[9];
  const float* blin = (const float*)d_in[10];
  float* out = (float*)d_out;
  float* ws  = (float*)d_ws;

  const int* srcI = ei;
  const int* dstI = ei + NE;

  float* deg    = ws;                       // 50048; count then dinv
  float* bnA    = ws + 50048;               // 2048 (sum8 | sq8)
  float* bnB    = bnA + 2048;               // 2048
  float* bufA   = bnB + 2048;               // NN*FD
  float* bufB   = bufA + NN * FD;           // NN*FD
  int2*  csr    = (int2*)(bufB + NN * FD);  // NE int2
  int*   row_off= (int*)(csr + NE);         // 50048
  int*   cursor = row_off + 50048;          // 50048
  int*   gstart = cursor + 50048;           // 1024
  int*   bsum   = gstart + 1024;            // 256
  int*   bbase  = bsum + 256;               // 256
  unsigned short* w2 = (unsigned short*)(bbase + 256);  // 3*32768 ushorts, pre-swizzled [hi|lo]

  dim3 B(256);
  const int gE    = (NE + 255) / 256;    // 2344
  const int gGemm = (NN / 16 + 7) / 8;   // 391
  const int gAgg  = NN / 16;             // 3125

  // zero deg + bn accumulators
  hipMemsetAsync(ws, 0, (50048 + 4096) * sizeof(float), stream);

  k_deg_scatter<<<gE, B, 0, stream>>>(dstI, deg);
  k_bsum<<<NB, B, 0, stream>>>(deg, bsum);
  k_bscan<<<1, B, 0, stream>>>(bsum, bbase);
  k_rowoff<<<NB, B, 0, stream>>>(deg, bbase, row_off, cursor);
  k_pre<<<PRE_FILL + PRE_CVT + 3, B, 0, stream>>>(srcI, dstI, deg, cursor, csr,
                                                  W1, W2, W3, w2, batch, gstart);

  // layer 1
  k_gemm<0><<<gGemm, B, 0, stream>>>(x, nullptr, w2, bufA);
  k_agg<1><<<gAgg, B, 0, stream>>>(bufA, deg, b1, row_off, csr, bufB, bnA);

  // layer 2 (BN+ReLU+musc-reduce fused into GEMM)
  k_gemm<1><<<gGemm, B, 0, stream>>>(bufB, bnA, w2 + 32768, bufA);
  k_agg<1><<<gAgg, B, 0, stream>>>(bufA, deg, b2, row_off, csr, bufB, bnB);

  // layer 3
  k_gemm<1><<<gGemm, B, 0, stream>>>(bufB, bnB, w2 + 65536, bufA);
  k_agg<0><<<gAgg, B, 0, stream>>>(bufA, deg, b3, row_off, csr, bufB, nullptr);

  // pool + head
  k_poolfinal<<<NG, 512, 0, stream>>>(bufB, gstart, Wlin, blin, out);
}

// Round 10
// 294.632 us; speedup vs baseline: 1.7599x; 1.1626x over previous
//
#include <hip/hip_runtime.h>
#include <hip/hip_bf16.h>

#define NN 50000
#define NE 600000
#define FD 128
#define NG 512
#define NC 10
static constexpr float EPS_BN = 1e-5f;

typedef __bf16 bf16x8 __attribute__((ext_vector_type(8)));
typedef float f32x4 __attribute__((ext_vector_type(4)));

__device__ __forceinline__ unsigned short f2bf(float x) {
  unsigned u = __float_as_uint(x);
  u = (u + 0x7FFFu + ((u >> 16) & 1u)) >> 16;
  return (unsigned short)u;
}
__device__ __forceinline__ float bf2f(unsigned short h) {
  return __uint_as_float(((unsigned)h) << 16);
}

// ---------------- degree (deg memset to 0; holds in-edge count) ----------------
__global__ __launch_bounds__(256) void k_deg_scatter(const int* __restrict__ dst, float* __restrict__ deg) {
  int e = blockIdx.x * 256 + threadIdx.x;
  if (e < NE) unsafeAtomicAdd(&deg[dst[e]], 1.0f);
}

// ---------------- CSR build: multi-block exclusive scan of in-edge counts ----------------
#define NB 196   // ceil(50000/256)
__global__ __launch_bounds__(256) void k_bsum(const float* __restrict__ deg, int* __restrict__ bsum) {
  __shared__ int s[256];
  int t = threadIdx.x, i = blockIdx.x * 256 + t;
  s[t] = (i < NN) ? (int)deg[i] : 0;
  __syncthreads();
  for (int o = 128; o > 0; o >>= 1) { if (t < o) s[t] += s[t + o]; __syncthreads(); }
  if (t == 0) bsum[blockIdx.x] = s[0];
}

__global__ __launch_bounds__(256) void k_bscan(const int* __restrict__ bsum, int* __restrict__ bbase) {
  __shared__ int s[256];
  int t = threadIdx.x;
  int v = (t < NB) ? bsum[t] : 0;
  s[t] = v; __syncthreads();
  for (int o = 1; o < 256; o <<= 1) {
    int a = (t >= o) ? s[t - o] : 0; __syncthreads();
    s[t] += a; __syncthreads();
  }
  if (t < NB) bbase[t] = s[t] - v;
}

// also transforms deg (count) -> dinv = rsqrt(count+1)
__global__ __launch_bounds__(256) void k_rowoff(float* __restrict__ deg, const int* __restrict__ bbase,
                                                int* __restrict__ row_off, int* __restrict__ cursor) {
  __shared__ int s[256];
  int t = threadIdx.x, i = blockIdx.x * 256 + t;
  float dv = (i < NN) ? deg[i] : 0.f;
  int c = (int)dv;
  s[t] = c; __syncthreads();
  for (int o = 1; o < 256; o <<= 1) {
    int a = (t >= o) ? s[t - o] : 0; __syncthreads();
    s[t] += a; __syncthreads();
  }
  int excl = s[t] - c + bbase[blockIdx.x];
  if (i <= NN) {
    row_off[i] = excl;
    if (i < NN) {
      cursor[i] = excl;
      deg[i] = rsqrtf(dv + 1.0f);
    }
  }
}

// ---------------- fused preamble: CSR fill + weight cvt(pre-swizzled) + gstart ----------------
#define PRE_FILL 2344
#define PRE_CVT  48
__global__ __launch_bounds__(256) void k_pre(const int* __restrict__ src, const int* __restrict__ dst,
                                             const float* __restrict__ dinv, int* __restrict__ cursor,
                                             int2* __restrict__ csr,
                                             const float* __restrict__ W1, const float* __restrict__ W2,
                                             const float* __restrict__ W3, unsigned short* __restrict__ w2,
                                             const int* __restrict__ batch, int* __restrict__ gstart) {
  int b = blockIdx.x, t = threadIdx.x;
  if (b < PRE_FILL) {
    int e = b * 256 + t;
    if (e >= NE) return;
    int s = src[e], d = dst[e];
    float nrm = dinv[s] * dinv[d];
    int pos = atomicAdd(&cursor[d], 1);
    csr[pos] = make_int2(s, __float_as_int(nrm));
  } else if (b < PRE_FILL + PRE_CVT) {
    int bb = b - PRE_FILL;
    int m = bb >> 4;
    const float* W = (m == 0) ? W1 : ((m == 1) ? W2 : W3);
    int i = (bb & 15) * 256 + t;           // 0..4095, 4 elems each
    float4 v = ((const float4*)W)[i];
    ushort4 hv, lv;
    hv.x = f2bf(v.x); lv.x = f2bf(v.x - bf2f(hv.x));
    hv.y = f2bf(v.y); lv.y = f2bf(v.y - bf2f(hv.y));
    hv.z = f2bf(v.z); lv.z = f2bf(v.z - bf2f(hv.z));
    hv.w = f2bf(v.w); lv.w = f2bf(v.w - bf2f(hv.w));
    int e0 = i * 4, row = e0 >> 7, col = e0 & 127;
    int sc_ = ((col & 120) ^ ((row & 7) << 3)) | (col & 7);   // 16B-group XOR swizzle
    unsigned short* base = w2 + m * 32768 + row * FD + sc_;
    *(ushort4*)base = hv;
    *(ushort4*)(base + 16384) = lv;
  } else {
    int g = (b - PRE_FILL - PRE_CVT) * 256 + t;
    if (g > NG) return;
    int lo = 0, hi = NN;
    while (lo < hi) {
      int mid = (lo + hi) >> 1;
      if (batch[mid] < g) lo = mid + 1; else hi = mid;
    }
    gstart[g] = lo;
  }
}

// ---------------- MFMA GEMM: W LDS-staged, 1 row-tile/wave, grid 782 (2 blocks/CU resident) ----
template <int BN>
__global__ __launch_bounds__(256) void k_gemm(const float* __restrict__ in, const float* __restrict__ bn8,
                                              const unsigned short* __restrict__ wsrc,
                                              float* __restrict__ out) {
  __shared__ unsigned short w_lds[2 * FD * FD];   // 64KB, already swizzled
  __shared__ float s_musc[2 * FD];
  int t = threadIdx.x;
  {
    const uint4* s4 = (const uint4*)wsrc;
    uint4* d4 = (uint4*)w_lds;
#pragma unroll
    for (int c = 0; c < 16; ++c) d4[c * 256 + t] = s4[c * 256 + t];
  }
  if constexpr (BN != 0) {
    if (t < FD) {
      float s = 0.f, q = 0.f;
#pragma unroll
      for (int c = 0; c < 8; ++c) { s += bn8[c * FD + t]; q += bn8[1024 + c * FD + t]; }
      float m = s * (1.0f / NN);
      float v = fmaxf(q * (1.0f / NN) - m * m, 0.f);
      s_musc[t] = m;
      s_musc[FD + t] = rsqrtf(v + EPS_BN);
    }
  }
  __syncthreads();

  int w = t >> 6, l = t & 63;
  int rt = blockIdx.x * 4 + w;
  if (rt >= NN / 16) return;
  int r = l & 15, g = l >> 4;
  int ko = g * 8;
  f32x4 acc[8];
#pragma unroll
  for (int ct = 0; ct < 8; ++ct) acc[ct] = (f32x4){0.f, 0.f, 0.f, 0.f};

#pragma unroll
  for (int kk = 0; kk < FD; kk += 32) {
    float a0[8];
    {
      const float* p0 = in + (size_t)(rt * 16 + r) * FD + kk + ko;
      float4 x0 = *(const float4*)p0;
      float4 x1 = *(const float4*)(p0 + 4);
      a0[0] = x0.x; a0[1] = x0.y; a0[2] = x0.z; a0[3] = x0.w;
      a0[4] = x1.x; a0[5] = x1.y; a0[6] = x1.z; a0[7] = x1.w;
    }
    if constexpr (BN != 0) {
      const float* mp = s_musc + kk + ko;
      float4 m0 = *(const float4*)mp, m1 = *(const float4*)(mp + 4);
      float4 s0 = *(const float4*)(mp + FD), s1 = *(const float4*)(mp + FD + 4);
      float mu[8] = {m0.x, m0.y, m0.z, m0.w, m1.x, m1.y, m1.z, m1.w};
      float sc[8] = {s0.x, s0.y, s0.z, s0.w, s1.x, s1.y, s1.z, s1.w};
#pragma unroll
      for (int i = 0; i < 8; ++i)
        a0[i] = fmaxf((a0[i] - mu[i]) * sc[i], 0.f);
    }
    bf16x8 ah, al;
#pragma unroll
    for (int i = 0; i < 8; ++i) {
      __bf16 h0 = (__bf16)a0[i];
      ah[i] = h0; al[i] = (__bf16)(a0[i] - (float)h0);
    }
#pragma unroll
    for (int ct = 0; ct < 8; ++ct) {
      int row = ct * 16 + r;
      int idx = row * FD + ((kk + ko) ^ ((r & 7) << 3));
      bf16x8 bh = *(const bf16x8*)(w_lds + idx);
      bf16x8 bl = *(const bf16x8*)(w_lds + FD * FD + idx);
      acc[ct] = __builtin_amdgcn_mfma_f32_16x16x32_bf16(ah, bh, acc[ct], 0, 0, 0);
      acc[ct] = __builtin_amdgcn_mfma_f32_16x16x32_bf16(ah, bl, acc[ct], 0, 0, 0);
      acc[ct] = __builtin_amdgcn_mfma_f32_16x16x32_bf16(al, bh, acc[ct], 0, 0, 0);
    }
  }
  // C/D layout: col = lane&15 (=r), row = g*4 + reg
#pragma unroll
  for (int ct = 0; ct < 8; ++ct)
#pragma unroll
    for (int i = 0; i < 4; ++i)
      out[(size_t)(rt * 16 + g * 4 + i) * FD + ct * 16 + r] = acc[ct][i];
}

// ---------------- aggregation: 16 lanes/node, int2 CSR (R9 measured-good, byte-identical) ----------------
template <int STATS>
__global__ __launch_bounds__(256) void k_agg(const float* __restrict__ h, const float* __restrict__ dinv,
                                             const float* __restrict__ bias, const int* __restrict__ row_off,
                                             const int2* __restrict__ csr, float* __restrict__ out,
                                             float* __restrict__ bn8) {
  int t = threadIdx.x;
  int n = blockIdx.x * 16 + (t >> 4);
  int q = t & 15;
  const float4* h4 = (const float4*)h;
  float dv = dinv[n];
  float s2 = dv * dv;
  float4 acc0 = ((const float4*)bias)[q * 2];
  float4 acc1 = ((const float4*)bias)[q * 2 + 1];
  {
    float4 hv0 = h4[(size_t)n * 32 + q * 2];
    float4 hv1 = h4[(size_t)n * 32 + q * 2 + 1];
    acc0.x = fmaf(s2, hv0.x, acc0.x); acc0.y = fmaf(s2, hv0.y, acc0.y);
    acc0.z = fmaf(s2, hv0.z, acc0.z); acc0.w = fmaf(s2, hv0.w, acc0.w);
    acc1.x = fmaf(s2, hv1.x, acc1.x); acc1.y = fmaf(s2, hv1.y, acc1.y);
    acc1.z = fmaf(s2, hv1.z, acc1.z); acc1.w = fmaf(s2, hv1.w, acc1.w);
  }
  int lo = row_off[n], hi = row_off[n + 1];
  for (int j = lo; j < hi; ++j) {
    int2 e = csr[j];
    float w = __int_as_float(e.y);
    float4 v0 = h4[(size_t)e.x * 32 + q * 2];
    float4 v1 = h4[(size_t)e.x * 32 + q * 2 + 1];
    acc0.x = fmaf(w, v0.x, acc0.x); acc0.y = fmaf(w, v0.y, acc0.y);
    acc0.z = fmaf(w, v0.z, acc0.z); acc0.w = fmaf(w, v0.w, acc0.w);
    acc1.x = fmaf(w, v1.x, acc1.x); acc1.y = fmaf(w, v1.y, acc1.y);
    acc1.z = fmaf(w, v1.z, acc1.z); acc1.w = fmaf(w, v1.w, acc1.w);
  }
  ((float4*)out)[(size_t)n * 32 + q * 2] = acc0;
  ((float4*)out)[(size_t)n * 32 + q * 2 + 1] = acc1;

  if constexpr (STATS != 0) {
    __shared__ float red_s[16][FD + 4], red_q[16][FD + 4];
    int slot = t >> 4, f = q * 8;
    red_s[slot][f + 0] = acc0.x; red_s[slot][f + 1] = acc0.y;
    red_s[slot][f + 2] = acc0.z; red_s[slot][f + 3] = acc0.w;
    red_s[slot][f + 4] = acc1.x; red_s[slot][f + 5] = acc1.y;
    red_s[slot][f + 6] = acc1.z; red_s[slot][f + 7] = acc1.w;
    red_q[slot][f + 0] = acc0.x * acc0.x; red_q[slot][f + 1] = acc0.y * acc0.y;
    red_q[slot][f + 2] = acc0.z * acc0.z; red_q[slot][f + 3] = acc0.w * acc0.w;
    red_q[slot][f + 4] = acc1.x * acc1.x; red_q[slot][f + 5] = acc1.y * acc1.y;
    red_q[slot][f + 6] = acc1.z * acc1.z; red_q[slot][f + 7] = acc1.w * acc1.w;
    __syncthreads();
    if (t < FD) {
      float s = 0.f, qq = 0.f;
#pragma unroll
      for (int m = 0; m < 16; ++m) { s += red_s[m][t]; qq += red_q[m][t]; }
      int c = (blockIdx.x & 7) * FD + t;
      unsafeAtomicAdd(&bn8[c], s);
      unsafeAtomicAdd(&bn8[1024 + c], qq);
    }
  }
}

// ---------------- fused pool/head ----------------
__global__ __launch_bounds__(512) void k_poolfinal(const float* __restrict__ h, const int* __restrict__ gstart,
                                                   const float* __restrict__ Wlin, const float* __restrict__ blin,
                                                   float* __restrict__ out) {
  __shared__ float ps[4][FD];
  __shared__ float pp[FD];
  int g = blockIdx.x, t = threadIdx.x;
  int part = t >> 7, f = t & 127;
  int lo = gstart[g], hi = gstart[g + 1];
  float s = 0.f;
  for (int n = lo + part; n < hi; n += 4) s += h[(size_t)n * FD + f];
  ps[part][f] = s;
  __syncthreads();
  if (t < FD) {
    float tot = ps[0][t] + ps[1][t] + ps[2][t] + ps[3][t];
    pp[t] = tot * (1.0f / fmaxf((float)(hi - lo), 1.0f));
  }
  __syncthreads();
  if (t < NC) {
    float a = blin[t];
    for (int k = 0; k < FD; ++k) a = fmaf(pp[k], Wlin[t * FD + k], a);
    out[g * NC + t] = a;
  }
}

// ---------------- launch ----------------
extern "C" void kernel_launch(void* const* d_in, const int* in_sizes, int n_in,
                              void* d_out, int out_size, void* d_ws, size_t ws_size,
                              hipStream_t stream) {
  const float* x    = (const float*)d_in[0];
  const int*   ei   = (const int*)d_in[1];
  const int*   batch= (const int*)d_in[2];
  const float* W1   = (const float*)d_in[3];
  const float* b1   = (const float*)d_in[4];
  const float* W2   = (const float*)d_in[5];
  const float* b2   = (const float*)d_in[6];
  const float* W3   = (const float*)d_in[7];
  const float* b3   = (const float*)d_in[8];
  const float* Wlin = (const float*)d_in[9];
  const float* blin = (const float*)d_in[10];
  float* out = (float*)d_out;
  float* ws  = (float*)d_ws;

  const int* srcI = ei;
  const int* dstI = ei + NE;

  float* deg    = ws;                       // 50048; count then dinv
  float* bnA    = ws + 50048;               // 2048 (sum8 | sq8)
  float* bnB    = bnA + 2048;               // 2048
  float* bufA   = bnB + 2048;               // NN*FD
  float* bufB   = bufA + NN * FD;           // NN*FD
  int2*  csr    = (int2*)(bufB + NN * FD);  // NE int2
  int*   row_off= (int*)(csr + NE);         // 50048
  int*   cursor = row_off + 50048;          // 50048
  int*   gstart = cursor + 50048;           // 1024
  int*   bsum   = gstart + 1024;            // 256
  int*   bbase  = bsum + 256;               // 256
  unsigned short* w2 = (unsigned short*)(bbase + 256);  // 3*32768, pre-swizzled [hi|lo]

  dim3 B(256);
  const int gE    = (NE + 255) / 256;    // 2344
  const int gGemm = (NN / 16 + 3) / 4;   // 782 blocks, 1 rt/wave
  const int gAgg  = NN / 16;             // 3125

  // zero deg + bn accumulators
  hipMemsetAsync(ws, 0, (50048 + 4096) * sizeof(float), stream);

  k_deg_scatter<<<gE, B, 0, stream>>>(dstI, deg);
  k_bsum<<<NB, B, 0, stream>>>(deg, bsum);
  k_bscan<<<1, B, 0, stream>>>(bsum, bbase);
  k_rowoff<<<NB, B, 0, stream>>>(deg, bbase, row_off, cursor);
  k_pre<<<PRE_FILL + PRE_CVT + 3, B, 0, stream>>>(srcI, dstI, deg, cursor, csr,
                                                  W1, W2, W3, w2, batch, gstart);

  // layer 1
  k_gemm<0><<<gGemm, B, 0, stream>>>(x, nullptr, w2, bufA);
  k_agg<1><<<gAgg, B, 0, stream>>>(bufA, deg, b1, row_off, csr, bufB, bnA);

  // layer 2 (BN+ReLU+musc-reduce fused into GEMM)
  k_gemm<1><<<gGemm, B, 0, stream>>>(bufB, bnA, w2 + 32768, bufA);
  k_agg<1><<<gAgg, B, 0, stream>>>(bufA, deg, b2, row_off, csr, bufB, bnB);

  // layer 3
  k_gemm<1><<<gGemm, B, 0, stream>>>(bufB, bnB, w2 + 65536, bufA);
  k_agg<0><<<gAgg, B, 0, stream>>>(bufA, deg, b3, row_off, csr, bufB, nullptr);

  // pool + head
  k_poolfinal<<<NG, 512, 0, stream>>>(bufB, gstart, Wlin, blin, out);
}

// Round 11
// 259.610 us; speedup vs baseline: 1.9974x; 1.1349x over previous
//
#include <hip/hip_runtime.h>
#include <hip/hip_bf16.h>

#define NN 50000
#define NE 600000
#define FD 128
#define NG 512
#define NC 10
static constexpr float EPS_BN = 1e-5f;

typedef __bf16 bf16x8 __attribute__((ext_vector_type(8)));
typedef float f32x4 __attribute__((ext_vector_type(4)));

__device__ __forceinline__ unsigned short f2bf(float x) {
  unsigned u = __float_as_uint(x);
  u = (u + 0x7FFFu + ((u >> 16) & 1u)) >> 16;
  return (unsigned short)u;
}
__device__ __forceinline__ float bf2f(unsigned short h) {
  return __uint_as_float(((unsigned)h) << 16);
}

// ---------------- degree (deg memset to 0; holds in-edge count) ----------------
__global__ __launch_bounds__(256) void k_deg_scatter(const int* __restrict__ dst, float* __restrict__ deg) {
  int e = blockIdx.x * 256 + threadIdx.x;
  if (e < NE) unsafeAtomicAdd(&deg[dst[e]], 1.0f);
}

// ---------------- CSR build: multi-block exclusive scan of in-edge counts ----------------
#define NB 196   // ceil(50000/256)
__global__ __launch_bounds__(256) void k_bsum(const float* __restrict__ deg, int* __restrict__ bsum) {
  __shared__ int s[256];
  int t = threadIdx.x, i = blockIdx.x * 256 + t;
  s[t] = (i < NN) ? (int)deg[i] : 0;
  __syncthreads();
  for (int o = 128; o > 0; o >>= 1) { if (t < o) s[t] += s[t + o]; __syncthreads(); }
  if (t == 0) bsum[blockIdx.x] = s[0];
}

__global__ __launch_bounds__(256) void k_bscan(const int* __restrict__ bsum, int* __restrict__ bbase) {
  __shared__ int s[256];
  int t = threadIdx.x;
  int v = (t < NB) ? bsum[t] : 0;
  s[t] = v; __syncthreads();
  for (int o = 1; o < 256; o <<= 1) {
    int a = (t >= o) ? s[t - o] : 0; __syncthreads();
    s[t] += a; __syncthreads();
  }
  if (t < NB) bbase[t] = s[t] - v;
}

// also transforms deg (count) -> dinv = rsqrt(count+1)
__global__ __launch_bounds__(256) void k_rowoff(float* __restrict__ deg, const int* __restrict__ bbase,
                                                int* __restrict__ row_off, int* __restrict__ cursor) {
  __shared__ int s[256];
  int t = threadIdx.x, i = blockIdx.x * 256 + t;
  float dv = (i < NN) ? deg[i] : 0.f;
  int c = (int)dv;
  s[t] = c; __syncthreads();
  for (int o = 1; o < 256; o <<= 1) {
    int a = (t >= o) ? s[t - o] : 0; __syncthreads();
    s[t] += a; __syncthreads();
  }
  int excl = s[t] - c + bbase[blockIdx.x];
  if (i <= NN) {
    row_off[i] = excl;
    if (i < NN) {
      cursor[i] = excl;
      deg[i] = rsqrtf(dv + 1.0f);
    }
  }
}

// ---------------- fused preamble: CSR fill + weight cvt(pre-swizzled) + gstart ----------------
#define PRE_FILL 2344
#define PRE_CVT  48
__global__ __launch_bounds__(256) void k_pre(const int* __restrict__ src, const int* __restrict__ dst,
                                             const float* __restrict__ dinv, int* __restrict__ cursor,
                                             int2* __restrict__ csr,
                                             const float* __restrict__ W1, const float* __restrict__ W2,
                                             const float* __restrict__ W3, unsigned short* __restrict__ w2,
                                             const int* __restrict__ batch, int* __restrict__ gstart) {
  int b = blockIdx.x, t = threadIdx.x;
  if (b < PRE_FILL) {
    int e = b * 256 + t;
    if (e >= NE) return;
    int s = src[e], d = dst[e];
    float nrm = dinv[s] * dinv[d];
    int pos = atomicAdd(&cursor[d], 1);
    csr[pos] = make_int2(s, __float_as_int(nrm));
  } else if (b < PRE_FILL + PRE_CVT) {
    int bb = b - PRE_FILL;
    int m = bb >> 4;
    const float* W = (m == 0) ? W1 : ((m == 1) ? W2 : W3);
    int i = (bb & 15) * 256 + t;           // 0..4095, 4 elems each
    float4 v = ((const float4*)W)[i];
    ushort4 hv, lv;
    hv.x = f2bf(v.x); lv.x = f2bf(v.x - bf2f(hv.x));
    hv.y = f2bf(v.y); lv.y = f2bf(v.y - bf2f(hv.y));
    hv.z = f2bf(v.z); lv.z = f2bf(v.z - bf2f(hv.z));
    hv.w = f2bf(v.w); lv.w = f2bf(v.w - bf2f(hv.w));
    int e0 = i * 4, row = e0 >> 7, col = e0 & 127;
    int sc_ = ((col & 120) ^ ((row & 7) << 3)) | (col & 7);   // 16B-group XOR swizzle
    unsigned short* base = w2 + m * 32768 + row * FD + sc_;
    *(ushort4*)base = hv;
    *(ushort4*)(base + 16384) = lv;
  } else {
    int g = (b - PRE_FILL - PRE_CVT) * 256 + t;
    if (g > NG) return;
    int lo = 0, hi = NN;
    while (lo < hi) {
      int mid = (lo + hi) >> 1;
      if (batch[mid] < g) lo = mid + 1; else hi = mid;
    }
    gstart[g] = lo;
  }
}

// ---------------- MFMA GEMM: W LDS-staged, 1 row-tile/wave; writes fp32 h + bf16 copy hb ----
template <int BN>
__global__ __launch_bounds__(256) void k_gemm(const float* __restrict__ in, const float* __restrict__ bn8,
                                              const unsigned short* __restrict__ wsrc,
                                              float* __restrict__ out, unsigned short* __restrict__ hb) {
  __shared__ unsigned short w_lds[2 * FD * FD];   // 64KB, already swizzled
  __shared__ float s_musc[2 * FD];
  int t = threadIdx.x;
  {
    const uint4* s4 = (const uint4*)wsrc;
    uint4* d4 = (uint4*)w_lds;
#pragma unroll
    for (int c = 0; c < 16; ++c) d4[c * 256 + t] = s4[c * 256 + t];
  }
  if constexpr (BN != 0) {
    if (t < FD) {
      float s = 0.f, q = 0.f;
#pragma unroll
      for (int c = 0; c < 8; ++c) { s += bn8[c * FD + t]; q += bn8[1024 + c * FD + t]; }
      float m = s * (1.0f / NN);
      float v = fmaxf(q * (1.0f / NN) - m * m, 0.f);
      s_musc[t] = m;
      s_musc[FD + t] = rsqrtf(v + EPS_BN);
    }
  }
  __syncthreads();

  int w = t >> 6, l = t & 63;
  int rt = blockIdx.x * 4 + w;
  if (rt >= NN / 16) return;
  int r = l & 15, g = l >> 4;
  int ko = g * 8;
  f32x4 acc[8];
#pragma unroll
  for (int ct = 0; ct < 8; ++ct) acc[ct] = (f32x4){0.f, 0.f, 0.f, 0.f};

#pragma unroll
  for (int kk = 0; kk < FD; kk += 32) {
    float a0[8];
    {
      const float* p0 = in + (size_t)(rt * 16 + r) * FD + kk + ko;
      float4 x0 = *(const float4*)p0;
      float4 x1 = *(const float4*)(p0 + 4);
      a0[0] = x0.x; a0[1] = x0.y; a0[2] = x0.z; a0[3] = x0.w;
      a0[4] = x1.x; a0[5] = x1.y; a0[6] = x1.z; a0[7] = x1.w;
    }
    if constexpr (BN != 0) {
      const float* mp = s_musc + kk + ko;
      float4 m0 = *(const float4*)mp, m1 = *(const float4*)(mp + 4);
      float4 s0 = *(const float4*)(mp + FD), s1 = *(const float4*)(mp + FD + 4);
      float mu[8] = {m0.x, m0.y, m0.z, m0.w, m1.x, m1.y, m1.z, m1.w};
      float sc[8] = {s0.x, s0.y, s0.z, s0.w, s1.x, s1.y, s1.z, s1.w};
#pragma unroll
      for (int i = 0; i < 8; ++i)
        a0[i] = fmaxf((a0[i] - mu[i]) * sc[i], 0.f);
    }
    bf16x8 ah, al;
#pragma unroll
    for (int i = 0; i < 8; ++i) {
      __bf16 h0 = (__bf16)a0[i];
      ah[i] = h0; al[i] = (__bf16)(a0[i] - (float)h0);
    }
#pragma unroll
    for (int ct = 0; ct < 8; ++ct) {
      int row = ct * 16 + r;
      int idx = row * FD + ((kk + ko) ^ ((r & 7) << 3));
      bf16x8 bh = *(const bf16x8*)(w_lds + idx);
      bf16x8 bl = *(const bf16x8*)(w_lds + FD * FD + idx);
      acc[ct] = __builtin_amdgcn_mfma_f32_16x16x32_bf16(ah, bh, acc[ct], 0, 0, 0);
      acc[ct] = __builtin_amdgcn_mfma_f32_16x16x32_bf16(ah, bl, acc[ct], 0, 0, 0);
      acc[ct] = __builtin_amdgcn_mfma_f32_16x16x32_bf16(al, bh, acc[ct], 0, 0, 0);
    }
  }
  // C/D layout: col = lane&15 (=r), row = g*4 + reg
#pragma unroll
  for (int ct = 0; ct < 8; ++ct)
#pragma unroll
    for (int i = 0; i < 4; ++i) {
      float v = acc[ct][i];
      size_t off = (size_t)(rt * 16 + g * 4 + i) * FD + ct * 16 + r;
      out[off] = v;
      hb[off] = f2bf(v);
    }
}

// ---------------- aggregation: 16 lanes/node; edge gathers from bf16 copy (half bytes) ----------------
template <int STATS>
__global__ __launch_bounds__(256) void k_agg(const float* __restrict__ h, const unsigned short* __restrict__ hb,
                                             const float* __restrict__ dinv,
                                             const float* __restrict__ bias, const int* __restrict__ row_off,
                                             const int2* __restrict__ csr, float* __restrict__ out,
                                             float* __restrict__ bn8) {
  int t = threadIdx.x;
  int n = blockIdx.x * 16 + (t >> 4);
  int q = t & 15;
  const float4* h4 = (const float4*)h;
  const uint4* hb4 = (const uint4*)hb;
  float dv = dinv[n];
  float s2 = dv * dv;
  float4 acc0 = ((const float4*)bias)[q * 2];
  float4 acc1 = ((const float4*)bias)[q * 2 + 1];
  {
    float4 hv0 = h4[(size_t)n * 32 + q * 2];
    float4 hv1 = h4[(size_t)n * 32 + q * 2 + 1];
    acc0.x = fmaf(s2, hv0.x, acc0.x); acc0.y = fmaf(s2, hv0.y, acc0.y);
    acc0.z = fmaf(s2, hv0.z, acc0.z); acc0.w = fmaf(s2, hv0.w, acc0.w);
    acc1.x = fmaf(s2, hv1.x, acc1.x); acc1.y = fmaf(s2, hv1.y, acc1.y);
    acc1.z = fmaf(s2, hv1.z, acc1.z); acc1.w = fmaf(s2, hv1.w, acc1.w);
  }
  int lo = row_off[n], hi = row_off[n + 1];
  for (int j = lo; j < hi; ++j) {
    int2 e = csr[j];
    float w = __int_as_float(e.y);
    uint4 pv = hb4[(size_t)e.x * 16 + q];
    acc0.x = fmaf(w, __uint_as_float(pv.x << 16), acc0.x);
    acc0.y = fmaf(w, __uint_as_float(pv.x & 0xffff0000u), acc0.y);
    acc0.z = fmaf(w, __uint_as_float(pv.y << 16), acc0.z);
    acc0.w = fmaf(w, __uint_as_float(pv.y & 0xffff0000u), acc0.w);
    acc1.x = fmaf(w, __uint_as_float(pv.z << 16), acc1.x);
    acc1.y = fmaf(w, __uint_as_float(pv.z & 0xffff0000u), acc1.y);
    acc1.z = fmaf(w, __uint_as_float(pv.w << 16), acc1.z);
    acc1.w = fmaf(w, __uint_as_float(pv.w & 0xffff0000u), acc1.w);
  }
  ((float4*)out)[(size_t)n * 32 + q * 2] = acc0;
  ((float4*)out)[(size_t)n * 32 + q * 2 + 1] = acc1;

  if constexpr (STATS != 0) {
    __shared__ float red_s[16][FD + 4], red_q[16][FD + 4];
    int slot = t >> 4, f = q * 8;
    red_s[slot][f + 0] = acc0.x; red_s[slot][f + 1] = acc0.y;
    red_s[slot][f + 2] = acc0.z; red_s[slot][f + 3] = acc0.w;
    red_s[slot][f + 4] = acc1.x; red_s[slot][f + 5] = acc1.y;
    red_s[slot][f + 6] = acc1.z; red_s[slot][f + 7] = acc1.w;
    red_q[slot][f + 0] = acc0.x * acc0.x; red_q[slot][f + 1] = acc0.y * acc0.y;
    red_q[slot][f + 2] = acc0.z * acc0.z; red_q[slot][f + 3] = acc0.w * acc0.w;
    red_q[slot][f + 4] = acc1.x * acc1.x; red_q[slot][f + 5] = acc1.y * acc1.y;
    red_q[slot][f + 6] = acc1.z * acc1.z; red_q[slot][f + 7] = acc1.w * acc1.w;
    __syncthreads();
    if (t < FD) {
      float s = 0.f, qq = 0.f;
#pragma unroll
      for (int m = 0; m < 16; ++m) { s += red_s[m][t]; qq += red_q[m][t]; }
      int c = (blockIdx.x & 7) * FD + t;
      unsafeAtomicAdd(&bn8[c], s);
      unsafeAtomicAdd(&bn8[1024 + c], qq);
    }
  }
}

// ---------------- fused pool/head ----------------
__global__ __launch_bounds__(512) void k_poolfinal(const float* __restrict__ h, const int* __restrict__ gstart,
                                                   const float* __restrict__ Wlin, const float* __restrict__ blin,
                                                   float* __restrict__ out) {
  __shared__ float ps[4][FD];
  __shared__ float pp[FD];
  int g = blockIdx.x, t = threadIdx.x;
  int part = t >> 7, f = t & 127;
  int lo = gstart[g], hi = gstart[g + 1];
  float s = 0.f;
  for (int n = lo + part; n < hi; n += 4) s += h[(size_t)n * FD + f];
  ps[part][f] = s;
  __syncthreads();
  if (t < FD) {
    float tot = ps[0][t] + ps[1][t] + ps[2][t] + ps[3][t];
    pp[t] = tot * (1.0f / fmaxf((float)(hi - lo), 1.0f));
  }
  __syncthreads();
  if (t < NC) {
    float a = blin[t];
    for (int k = 0; k < FD; ++k) a = fmaf(pp[k], Wlin[t * FD + k], a);
    out[g * NC + t] = a;
  }
}

// ---------------- launch ----------------
extern "C" void kernel_launch(void* const* d_in, const int* in_sizes, int n_in,
                              void* d_out, int out_size, void* d_ws, size_t ws_size,
                              hipStream_t stream) {
  const float* x    = (const float*)d_in[0];
  const int*   ei   = (const int*)d_in[1];
  const int*   batch= (const int*)d_in[2];
  const float* W1   = (const float*)d_in[3];
  const float* b1   = (const float*)d_in[4];
  const float* W2   = (const float*)d_in[5];
  const float* b2   = (const float*)d_in[6];
  const float* W3   = (const float*)d_in[7];
  const float* b3   = (const float*)d_in[8];
  const float* Wlin = (const float*)d_in[9];
  const float* blin = (const float*)d_in[10];
  float* out = (float*)d_out;
  float* ws  = (float*)d_ws;

  const int* srcI = ei;
  const int* dstI = ei + NE;

  float* deg    = ws;                       // 50048; count then dinv
  float* bnA    = ws + 50048;               // 2048 (sum8 | sq8)
  float* bnB    = bnA + 2048;               // 2048
  float* bufA   = bnB + 2048;               // NN*FD
  float* bufB   = bufA + NN * FD;           // NN*FD
  int2*  csr    = (int2*)(bufB + NN * FD);  // NE int2
  int*   row_off= (int*)(csr + NE);         // 50048
  int*   cursor = row_off + 50048;          // 50048
  int*   gstart = cursor + 50048;           // 1024
  int*   bsum   = gstart + 1024;            // 256
  int*   bbase  = bsum + 256;               // 256
  unsigned short* w2 = (unsigned short*)(bbase + 256);  // 3*32768, pre-swizzled [hi|lo]
  unsigned short* hb = w2 + 3 * 32768;      // NN*FD bf16 copy of gemm output

  dim3 B(256);
  const int gE    = (NE + 255) / 256;    // 2344
  const int gGemm = (NN / 16 + 3) / 4;   // 782 blocks, 1 rt/wave
  const int gAgg  = NN / 16;             // 3125

  // zero deg + bn accumulators
  hipMemsetAsync(ws, 0, (50048 + 4096) * sizeof(float), stream);

  k_deg_scatter<<<gE, B, 0, stream>>>(dstI, deg);
  k_bsum<<<NB, B, 0, stream>>>(deg, bsum);
  k_bscan<<<1, B, 0, stream>>>(bsum, bbase);
  k_rowoff<<<NB, B, 0, stream>>>(deg, bbase, row_off, cursor);
  k_pre<<<PRE_FILL + PRE_CVT + 3, B, 0, stream>>>(srcI, dstI, deg, cursor, csr,
                                                  W1, W2, W3, w2, batch, gstart);

  // layer 1
  k_gemm<0><<<gGemm, B, 0, stream>>>(x, nullptr, w2, bufA, hb);
  k_agg<1><<<gAgg, B, 0, stream>>>(bufA, hb, deg, b1, row_off, csr, bufB, bnA);

  // layer 2 (BN+ReLU+musc-reduce fused into GEMM)
  k_gemm<1><<<gGemm, B, 0, stream>>>(bufB, bnA, w2 + 32768, bufA, hb);
  k_agg<1><<<gAgg, B, 0, stream>>>(bufA, hb, deg, b2, row_off, csr, bufB, bnB);

  // layer 3
  k_gemm<1><<<gGemm, B, 0, stream>>>(bufB, bnB, w2 + 65536, bufA, hb);
  k_agg<0><<<gAgg, B, 0, stream>>>(bufA, hb, deg, b3, row_off, csr, bufB, nullptr);

  // pool + head
  k_poolfinal<<<NG, 512, 0, stream>>>(bufB, gstart, Wlin, blin, out);
}

// Round 12
// 250.028 us; speedup vs baseline: 2.0739x; 1.0383x over previous
//
#include <hip/hip_runtime.h>
#include <hip/hip_bf16.h>

#define NN 50000
#define NE 600000
#define FD 128
#define NG 512
#define NC 10
static constexpr float EPS_BN = 1e-5f;

typedef __bf16 bf16x8 __attribute__((ext_vector_type(8)));
typedef float f32x4 __attribute__((ext_vector_type(4)));

__device__ __forceinline__ unsigned short f2bf(float x) {
  unsigned u = __float_as_uint(x);
  u = (u + 0x7FFFu + ((u >> 16) & 1u)) >> 16;
  return (unsigned short)u;
}
__device__ __forceinline__ float bf2f(unsigned short h) {
  return __uint_as_float(((unsigned)h) << 16);
}

// ---------------- degree (deg memset to 0; holds in-edge count) ----------------
__global__ __launch_bounds__(256) void k_deg_scatter(const int* __restrict__ dst, float* __restrict__ deg) {
  int e = blockIdx.x * 256 + threadIdx.x;
  if (e < NE) unsafeAtomicAdd(&deg[dst[e]], 1.0f);
}

// ---------------- CSR build: multi-block exclusive scan of in-edge counts ----------------
#define NB 196   // ceil(50000/256)
__global__ __launch_bounds__(256) void k_bsum(const float* __restrict__ deg, int* __restrict__ bsum) {
  __shared__ int s[256];
  int t = threadIdx.x, i = blockIdx.x * 256 + t;
  s[t] = (i < NN) ? (int)deg[i] : 0;
  __syncthreads();
  for (int o = 128; o > 0; o >>= 1) { if (t < o) s[t] += s[t + o]; __syncthreads(); }
  if (t == 0) bsum[blockIdx.x] = s[0];
}

__global__ __launch_bounds__(256) void k_bscan(const int* __restrict__ bsum, int* __restrict__ bbase) {
  __shared__ int s[256];
  int t = threadIdx.x;
  int v = (t < NB) ? bsum[t] : 0;
  s[t] = v; __syncthreads();
  for (int o = 1; o < 256; o <<= 1) {
    int a = (t >= o) ? s[t - o] : 0; __syncthreads();
    s[t] += a; __syncthreads();
  }
  if (t < NB) bbase[t] = s[t] - v;
}

// also transforms deg (count) -> dinv = rsqrt(count+1)
__global__ __launch_bounds__(256) void k_rowoff(float* __restrict__ deg, const int* __restrict__ bbase,
                                                int* __restrict__ row_off, int* __restrict__ cursor) {
  __shared__ int s[256];
  int t = threadIdx.x, i = blockIdx.x * 256 + t;
  float dv = (i < NN) ? deg[i] : 0.f;
  int c = (int)dv;
  s[t] = c; __syncthreads();
  for (int o = 1; o < 256; o <<= 1) {
    int a = (t >= o) ? s[t - o] : 0; __syncthreads();
    s[t] += a; __syncthreads();
  }
  int excl = s[t] - c + bbase[blockIdx.x];
  if (i <= NN) {
    row_off[i] = excl;
    if (i < NN) {
      cursor[i] = excl;
      deg[i] = rsqrtf(dv + 1.0f);
    }
  }
}

// ---------------- fused preamble: CSR fill + weight cvt(pre-swizzled) + gstart ----------------
#define PRE_FILL 2344
#define PRE_CVT  48
__global__ __launch_bounds__(256) void k_pre(const int* __restrict__ src, const int* __restrict__ dst,
                                             const float* __restrict__ dinv, int* __restrict__ cursor,
                                             int2* __restrict__ csr,
                                             const float* __restrict__ W1, const float* __restrict__ W2,
                                             const float* __restrict__ W3, unsigned short* __restrict__ w2,
                                             const int* __restrict__ batch, int* __restrict__ gstart) {
  int b = blockIdx.x, t = threadIdx.x;
  if (b < PRE_FILL) {
    int e = b * 256 + t;
    if (e >= NE) return;
    int s = src[e], d = dst[e];
    float nrm = dinv[s] * dinv[d];
    int pos = atomicAdd(&cursor[d], 1);
    csr[pos] = make_int2(s, __float_as_int(nrm));
  } else if (b < PRE_FILL + PRE_CVT) {
    int bb = b - PRE_FILL;
    int m = bb >> 4;
    const float* W = (m == 0) ? W1 : ((m == 1) ? W2 : W3);
    int i = (bb & 15) * 256 + t;           // 0..4095, 4 elems each
    float4 v = ((const float4*)W)[i];
    ushort4 hv, lv;
    hv.x = f2bf(v.x); lv.x = f2bf(v.x - bf2f(hv.x));
    hv.y = f2bf(v.y); lv.y = f2bf(v.y - bf2f(hv.y));
    hv.z = f2bf(v.z); lv.z = f2bf(v.z - bf2f(hv.z));
    hv.w = f2bf(v.w); lv.w = f2bf(v.w - bf2f(hv.w));
    int e0 = i * 4, row = e0 >> 7, col = e0 & 127;
    int sc_ = ((col & 120) ^ ((row & 7) << 3)) | (col & 7);   // 16B-group XOR swizzle
    unsigned short* base = w2 + m * 32768 + row * FD + sc_;
    *(ushort4*)base = hv;
    *(ushort4*)(base + 16384) = lv;
  } else {
    int g = (b - PRE_FILL - PRE_CVT) * 256 + t;
    if (g > NG) return;
    int lo = 0, hi = NN;
    while (lo < hi) {
      int mid = (lo + hi) >> 1;
      if (batch[mid] < g) lo = mid + 1; else hi = mid;
    }
    gstart[g] = lo;
  }
}

// ---------------- MFMA GEMM: W LDS-staged, 1 row-tile/wave; writes ONLY bf16 hb ----------------
template <int BN>
__global__ __launch_bounds__(256) void k_gemm(const float* __restrict__ in, const float* __restrict__ bn8,
                                              const unsigned short* __restrict__ wsrc,
                                              unsigned short* __restrict__ hb) {
  __shared__ unsigned short w_lds[2 * FD * FD];   // 64KB, already swizzled
  __shared__ float s_musc[2 * FD];
  int t = threadIdx.x;
  {
    const uint4* s4 = (const uint4*)wsrc;
    uint4* d4 = (uint4*)w_lds;
#pragma unroll
    for (int c = 0; c < 16; ++c) d4[c * 256 + t] = s4[c * 256 + t];
  }
  if constexpr (BN != 0) {
    if (t < FD) {
      float s = 0.f, q = 0.f;
#pragma unroll
      for (int c = 0; c < 8; ++c) { s += bn8[c * FD + t]; q += bn8[1024 + c * FD + t]; }
      float m = s * (1.0f / NN);
      float v = fmaxf(q * (1.0f / NN) - m * m, 0.f);
      s_musc[t] = m;
      s_musc[FD + t] = rsqrtf(v + EPS_BN);
    }
  }
  __syncthreads();

  int w = t >> 6, l = t & 63;
  int rt = blockIdx.x * 4 + w;
  if (rt >= NN / 16) return;
  int r = l & 15, g = l >> 4;
  int ko = g * 8;
  f32x4 acc[8];
#pragma unroll
  for (int ct = 0; ct < 8; ++ct) acc[ct] = (f32x4){0.f, 0.f, 0.f, 0.f};

#pragma unroll
  for (int kk = 0; kk < FD; kk += 32) {
    float a0[8];
    {
      const float* p0 = in + (size_t)(rt * 16 + r) * FD + kk + ko;
      float4 x0 = *(const float4*)p0;
      float4 x1 = *(const float4*)(p0 + 4);
      a0[0] = x0.x; a0[1] = x0.y; a0[2] = x0.z; a0[3] = x0.w;
      a0[4] = x1.x; a0[5] = x1.y; a0[6] = x1.z; a0[7] = x1.w;
    }
    if constexpr (BN != 0) {
      const float* mp = s_musc + kk + ko;
      float4 m0 = *(const float4*)mp, m1 = *(const float4*)(mp + 4);
      float4 s0 = *(const float4*)(mp + FD), s1 = *(const float4*)(mp + FD + 4);
      float mu[8] = {m0.x, m0.y, m0.z, m0.w, m1.x, m1.y, m1.z, m1.w};
      float sc[8] = {s0.x, s0.y, s0.z, s0.w, s1.x, s1.y, s1.z, s1.w};
#pragma unroll
      for (int i = 0; i < 8; ++i)
        a0[i] = fmaxf((a0[i] - mu[i]) * sc[i], 0.f);
    }
    bf16x8 ah, al;
#pragma unroll
    for (int i = 0; i < 8; ++i) {
      __bf16 h0 = (__bf16)a0[i];
      ah[i] = h0; al[i] = (__bf16)(a0[i] - (float)h0);
    }
#pragma unroll
    for (int ct = 0; ct < 8; ++ct) {
      int row = ct * 16 + r;
      int idx = row * FD + ((kk + ko) ^ ((r & 7) << 3));
      bf16x8 bh = *(const bf16x8*)(w_lds + idx);
      bf16x8 bl = *(const bf16x8*)(w_lds + FD * FD + idx);
      acc[ct] = __builtin_amdgcn_mfma_f32_16x16x32_bf16(ah, bh, acc[ct], 0, 0, 0);
      acc[ct] = __builtin_amdgcn_mfma_f32_16x16x32_bf16(ah, bl, acc[ct], 0, 0, 0);
      acc[ct] = __builtin_amdgcn_mfma_f32_16x16x32_bf16(al, bh, acc[ct], 0, 0, 0);
    }
  }
  // C/D layout: col = lane&15 (=r), row = g*4 + reg
#pragma unroll
  for (int ct = 0; ct < 8; ++ct)
#pragma unroll
    for (int i = 0; i < 4; ++i)
      hb[(size_t)(rt * 16 + g * 4 + i) * FD + ct * 16 + r] = f2bf(acc[ct][i]);
}

// ---------------- aggregation: 16 lanes/node; all h reads from bf16 hb ----------------
template <int STATS>
__global__ __launch_bounds__(256) void k_agg(const unsigned short* __restrict__ hb,
                                             const float* __restrict__ dinv,
                                             const float* __restrict__ bias, const int* __restrict__ row_off,
                                             const int2* __restrict__ csr, float* __restrict__ out,
                                             float* __restrict__ bn8) {
  int t = threadIdx.x;
  int n = blockIdx.x * 16 + (t >> 4);
  int q = t & 15;
  const uint4* hb4 = (const uint4*)hb;
  float dv = dinv[n];
  float s2 = dv * dv;
  float4 acc0 = ((const float4*)bias)[q * 2];
  float4 acc1 = ((const float4*)bias)[q * 2 + 1];
  {
    uint4 pv = hb4[(size_t)n * 16 + q];
    acc0.x = fmaf(s2, __uint_as_float(pv.x << 16), acc0.x);
    acc0.y = fmaf(s2, __uint_as_float(pv.x & 0xffff0000u), acc0.y);
    acc0.z = fmaf(s2, __uint_as_float(pv.y << 16), acc0.z);
    acc0.w = fmaf(s2, __uint_as_float(pv.y & 0xffff0000u), acc0.w);
    acc1.x = fmaf(s2, __uint_as_float(pv.z << 16), acc1.x);
    acc1.y = fmaf(s2, __uint_as_float(pv.z & 0xffff0000u), acc1.y);
    acc1.z = fmaf(s2, __uint_as_float(pv.w << 16), acc1.z);
    acc1.w = fmaf(s2, __uint_as_float(pv.w & 0xffff0000u), acc1.w);
  }
  int lo = row_off[n], hi = row_off[n + 1];
  for (int j = lo; j < hi; ++j) {
    int2 e = csr[j];
    float w = __int_as_float(e.y);
    uint4 pv = hb4[(size_t)e.x * 16 + q];
    acc0.x = fmaf(w, __uint_as_float(pv.x << 16), acc0.x);
    acc0.y = fmaf(w, __uint_as_float(pv.x & 0xffff0000u), acc0.y);
    acc0.z = fmaf(w, __uint_as_float(pv.y << 16), acc0.z);
    acc0.w = fmaf(w, __uint_as_float(pv.y & 0xffff0000u), acc0.w);
    acc1.x = fmaf(w, __uint_as_float(pv.z << 16), acc1.x);
    acc1.y = fmaf(w, __uint_as_float(pv.z & 0xffff0000u), acc1.y);
    acc1.z = fmaf(w, __uint_as_float(pv.w << 16), acc1.z);
    acc1.w = fmaf(w, __uint_as_float(pv.w & 0xffff0000u), acc1.w);
  }
  ((float4*)out)[(size_t)n * 32 + q * 2] = acc0;
  ((float4*)out)[(size_t)n * 32 + q * 2 + 1] = acc1;

  if constexpr (STATS != 0) {
    __shared__ float red_s[16][FD + 4], red_q[16][FD + 4];
    int slot = t >> 4, f = q * 8;
    red_s[slot][f + 0] = acc0.x; red_s[slot][f + 1] = acc0.y;
    red_s[slot][f + 2] = acc0.z; red_s[slot][f + 3] = acc0.w;
    red_s[slot][f + 4] = acc1.x; red_s[slot][f + 5] = acc1.y;
    red_s[slot][f + 6] = acc1.z; red_s[slot][f + 7] = acc1.w;
    red_q[slot][f + 0] = acc0.x * acc0.x; red_q[slot][f + 1] = acc0.y * acc0.y;
    red_q[slot][f + 2] = acc0.z * acc0.z; red_q[slot][f + 3] = acc0.w * acc0.w;
    red_q[slot][f + 4] = acc1.x * acc1.x; red_q[slot][f + 5] = acc1.y * acc1.y;
    red_q[slot][f + 6] = acc1.z * acc1.z; red_q[slot][f + 7] = acc1.w * acc1.w;
    __syncthreads();
    if (t < FD) {
      float s = 0.f, qq = 0.f;
#pragma unroll
      for (int m = 0; m < 16; ++m) { s += red_s[m][t]; qq += red_q[m][t]; }
      int c = (blockIdx.x & 7) * FD + t;
      unsafeAtomicAdd(&bn8[c], s);
      unsafeAtomicAdd(&bn8[1024 + c], qq);
    }
  }
}

// ---------------- fused pool/head ----------------
__global__ __launch_bounds__(512) void k_poolfinal(const float* __restrict__ h, const int* __restrict__ gstart,
                                                   const float* __restrict__ Wlin, const float* __restrict__ blin,
                                                   float* __restrict__ out) {
  __shared__ float ps[4][FD];
  __shared__ float pp[FD];
  int g = blockIdx.x, t = threadIdx.x;
  int part = t >> 7, f = t & 127;
  int lo = gstart[g], hi = gstart[g + 1];
  float s = 0.f;
  for (int n = lo + part; n < hi; n += 4) s += h[(size_t)n * FD + f];
  ps[part][f] = s;
  __syncthreads();
  if (t < FD) {
    float tot = ps[0][t] + ps[1][t] + ps[2][t] + ps[3][t];
    pp[t] = tot * (1.0f / fmaxf((float)(hi - lo), 1.0f));
  }
  __syncthreads();
  if (t < NC) {
    float a = blin[t];
    for (int k = 0; k < FD; ++k) a = fmaf(pp[k], Wlin[t * FD + k], a);
    out[g * NC + t] = a;
  }
}

// ---------------- launch ----------------
extern "C" void kernel_launch(void* const* d_in, const int* in_sizes, int n_in,
                              void* d_out, int out_size, void* d_ws, size_t ws_size,
                              hipStream_t stream) {
  const float* x    = (const float*)d_in[0];
  const int*   ei   = (const int*)d_in[1];
  const int*   batch= (const int*)d_in[2];
  const float* W1   = (const float*)d_in[3];
  const float* b1   = (const float*)d_in[4];
  const float* W2   = (const float*)d_in[5];
  const float* b2   = (const float*)d_in[6];
  const float* W3   = (const float*)d_in[7];
  const float* b3   = (const float*)d_in[8];
  const float* Wlin = (const float*)d_in[9];
  const float* blin = (const float*)d_in[10];
  float* out = (float*)d_out;
  float* ws  = (float*)d_ws;

  const int* srcI = ei;
  const int* dstI = ei + NE;

  float* deg    = ws;                       // 50048; count then dinv
  float* bnA    = ws + 50048;               // 2048 (sum8 | sq8)
  float* bnB    = bnA + 2048;               // 2048
  float* bufB   = bnB + 2048;               // NN*FD fp32 (agg out / gemm A in)
  int2*  csr    = (int2*)(bufB + NN * FD);  // NE int2
  int*   row_off= (int*)(csr + NE);         // 50048
  int*   cursor = row_off + 50048;          // 50048
  int*   gstart = cursor + 50048;           // 1024
  int*   bsum   = gstart + 1024;            // 256
  int*   bbase  = bsum + 256;               // 256
  unsigned short* w2 = (unsigned short*)(bbase + 256);  // 3*32768, pre-swizzled [hi|lo]
  unsigned short* hb = w2 + 3 * 32768;      // NN*FD bf16 gemm output

  dim3 B(256);
  const int gE    = (NE + 255) / 256;    // 2344
  const int gGemm = (NN / 16 + 3) / 4;   // 782 blocks, 1 rt/wave
  const int gAgg  = NN / 16;             // 3125

  // zero deg + bn accumulators
  hipMemsetAsync(ws, 0, (50048 + 4096) * sizeof(float), stream);

  k_deg_scatter<<<gE, B, 0, stream>>>(dstI, deg);
  k_bsum<<<NB, B, 0, stream>>>(deg, bsum);
  k_bscan<<<1, B, 0, stream>>>(bsum, bbase);
  k_rowoff<<<NB, B, 0, stream>>>(deg, bbase, row_off, cursor);
  k_pre<<<PRE_FILL + PRE_CVT + 3, B, 0, stream>>>(srcI, dstI, deg, cursor, csr,
                                                  W1, W2, W3, w2, batch, gstart);

  // layer 1
  k_gemm<0><<<gGemm, B, 0, stream>>>(x, nullptr, w2, hb);
  k_agg<1><<<gAgg, B, 0, stream>>>(hb, deg, b1, row_off, csr, bufB, bnA);

  // layer 2 (BN+ReLU+musc-reduce fused into GEMM)
  k_gemm<1><<<gGemm, B, 0, stream>>>(bufB, bnA, w2 + 32768, hb);
  k_agg<1><<<gAgg, B, 0, stream>>>(hb, deg, b2, row_off, csr, bufB, bnB);

  // layer 3
  k_gemm<1><<<gGemm, B, 0, stream>>>(bufB, bnB, w2 + 65536, hb);
  k_agg<0><<<gAgg, B, 0, stream>>>(hb, deg, b3, row_off, csr, bufB, nullptr);

  // pool + head
  k_poolfinal<<<NG, 512, 0, stream>>>(bufB, gstart, Wlin, blin, out);
}

// Round 13
// 246.944 us; speedup vs baseline: 2.0998x; 1.0125x over previous
//
#include <hip/hip_runtime.h>
#include <hip/hip_bf16.h>

#define NN 50000
#define NE 600000
#define FD 128
#define NG 512
#define NC 10
static constexpr float EPS_BN = 1e-5f;

typedef __bf16 bf16x8 __attribute__((ext_vector_type(8)));
typedef float f32x4 __attribute__((ext_vector_type(4)));

__device__ __forceinline__ unsigned short f2bf(float x) {
  unsigned u = __float_as_uint(x);
  u = (u + 0x7FFFu + ((u >> 16) & 1u)) >> 16;
  return (unsigned short)u;
}
__device__ __forceinline__ float bf2f(unsigned short h) {
  return __uint_as_float(((unsigned)h) << 16);
}

// ---------------- degree (deg memset to 0; holds in-edge count) ----------------
__global__ __launch_bounds__(256) void k_deg_scatter(const int* __restrict__ dst, float* __restrict__ deg) {
  int e = blockIdx.x * 256 + threadIdx.x;
  if (e < NE) unsafeAtomicAdd(&deg[dst[e]], 1.0f);
}

// ---------------- CSR build: multi-block exclusive scan of in-edge counts ----------------
#define NB 196   // ceil(50000/256)
__global__ __launch_bounds__(256) void k_bsum(const float* __restrict__ deg, int* __restrict__ bsum) {
  __shared__ int s[256];
  int t = threadIdx.x, i = blockIdx.x * 256 + t;
  s[t] = (i < NN) ? (int)deg[i] : 0;
  __syncthreads();
  for (int o = 128; o > 0; o >>= 1) { if (t < o) s[t] += s[t + o]; __syncthreads(); }
  if (t == 0) bsum[blockIdx.x] = s[0];
}

__global__ __launch_bounds__(256) void k_bscan(const int* __restrict__ bsum, int* __restrict__ bbase) {
  __shared__ int s[256];
  int t = threadIdx.x;
  int v = (t < NB) ? bsum[t] : 0;
  s[t] = v; __syncthreads();
  for (int o = 1; o < 256; o <<= 1) {
    int a = (t >= o) ? s[t - o] : 0; __syncthreads();
    s[t] += a; __syncthreads();
  }
  if (t < NB) bbase[t] = s[t] - v;
}

// also transforms deg (count) -> dinv = rsqrt(count+1)
__global__ __launch_bounds__(256) void k_rowoff(float* __restrict__ deg, const int* __restrict__ bbase,
                                                int* __restrict__ row_off, int* __restrict__ cursor) {
  __shared__ int s[256];
  int t = threadIdx.x, i = blockIdx.x * 256 + t;
  float dv = (i < NN) ? deg[i] : 0.f;
  int c = (int)dv;
  s[t] = c; __syncthreads();
  for (int o = 1; o < 256; o <<= 1) {
    int a = (t >= o) ? s[t - o] : 0; __syncthreads();
    s[t] += a; __syncthreads();
  }
  int excl = s[t] - c + bbase[blockIdx.x];
  if (i <= NN) {
    row_off[i] = excl;
    if (i < NN) {
      cursor[i] = excl;
      deg[i] = rsqrtf(dv + 1.0f);
    }
  }
}

// ---------------- fused preamble: XCD-partitioned CSR fill + weight cvt + gstart ----------------
// fill: group g = blockIdx&7 owns dst range [g*6250,(g+1)*6250); each block strides 2048 edges
#define FILL_CHUNKS 293                       // 293*2048 >= 600000
#define PRE_FILL (8 * FILL_CHUNKS)            // 2344
#define PRE_CVT  48
#define DRANGE 6250
__global__ __launch_bounds__(256) void k_pre(const int* __restrict__ src, const int* __restrict__ dst,
                                             const float* __restrict__ dinv, int* __restrict__ cursor,
                                             int2* __restrict__ csr,
                                             const float* __restrict__ W1, const float* __restrict__ W2,
                                             const float* __restrict__ W3, unsigned short* __restrict__ w2,
                                             const int* __restrict__ batch, int* __restrict__ gstart) {
  int b = blockIdx.x, t = threadIdx.x;
  if (b < PRE_FILL) {
    int g = b & 7;
    int chunk = b >> 3;
    int dlo = g * DRANGE, dhi = dlo + DRANGE;
    int e0 = chunk * 2048;
#pragma unroll
    for (int i = 0; i < 8; ++i) {
      int e = e0 + i * 256 + t;
      if (e < NE) {
        int d = dst[e];
        if (d >= dlo && d < dhi) {
          int s = src[e];
          float nrm = dinv[s] * dinv[d];
          int pos = atomicAdd(&cursor[d], 1);
          csr[pos] = make_int2(s, __float_as_int(nrm));
        }
      }
    }
  } else if (b < PRE_FILL + PRE_CVT) {
    int bb = b - PRE_FILL;
    int m = bb >> 4;
    const float* W = (m == 0) ? W1 : ((m == 1) ? W2 : W3);
    int i = (bb & 15) * 256 + t;           // 0..4095, 4 elems each
    float4 v = ((const float4*)W)[i];
    ushort4 hv, lv;
    hv.x = f2bf(v.x); lv.x = f2bf(v.x - bf2f(hv.x));
    hv.y = f2bf(v.y); lv.y = f2bf(v.y - bf2f(hv.y));
    hv.z = f2bf(v.z); lv.z = f2bf(v.z - bf2f(hv.z));
    hv.w = f2bf(v.w); lv.w = f2bf(v.w - bf2f(hv.w));
    int e0 = i * 4, row = e0 >> 7, col = e0 & 127;
    int sc_ = ((col & 120) ^ ((row & 7) << 3)) | (col & 7);   // 16B-group XOR swizzle
    unsigned short* base = w2 + m * 32768 + row * FD + sc_;
    *(ushort4*)base = hv;
    *(ushort4*)(base + 16384) = lv;
  } else {
    int g = (b - PRE_FILL - PRE_CVT) * 256 + t;
    if (g > NG) return;
    int lo = 0, hi = NN;
    while (lo < hi) {
      int mid = (lo + hi) >> 1;
      if (batch[mid] < g) lo = mid + 1; else hi = mid;
    }
    gstart[g] = lo;
  }
}

// ---------------- MFMA GEMM: W LDS-staged, 1 row-tile/wave; writes ONLY bf16 hb ----------------
template <int BN>
__global__ __launch_bounds__(256) void k_gemm(const float* __restrict__ in, const float* __restrict__ bn8,
                                              const unsigned short* __restrict__ wsrc,
                                              unsigned short* __restrict__ hb) {
  __shared__ unsigned short w_lds[2 * FD * FD];   // 64KB, already swizzled
  __shared__ float s_musc[2 * FD];
  int t = threadIdx.x;
  {
    const uint4* s4 = (const uint4*)wsrc;
    uint4* d4 = (uint4*)w_lds;
#pragma unroll
    for (int c = 0; c < 16; ++c) d4[c * 256 + t] = s4[c * 256 + t];
  }
  if constexpr (BN != 0) {
    if (t < FD) {
      float s = 0.f, q = 0.f;
#pragma unroll
      for (int c = 0; c < 8; ++c) { s += bn8[c * FD + t]; q += bn8[1024 + c * FD + t]; }
      float m = s * (1.0f / NN);
      float v = fmaxf(q * (1.0f / NN) - m * m, 0.f);
      s_musc[t] = m;
      s_musc[FD + t] = rsqrtf(v + EPS_BN);
    }
  }
  __syncthreads();

  int w = t >> 6, l = t & 63;
  int rt = blockIdx.x * 4 + w;
  if (rt >= NN / 16) return;
  int r = l & 15, g = l >> 4;
  int ko = g * 8;
  f32x4 acc[8];
#pragma unroll
  for (int ct = 0; ct < 8; ++ct) acc[ct] = (f32x4){0.f, 0.f, 0.f, 0.f};

#pragma unroll
  for (int kk = 0; kk < FD; kk += 32) {
    float a0[8];
    {
      const float* p0 = in + (size_t)(rt * 16 + r) * FD + kk + ko;
      float4 x0 = *(const float4*)p0;
      float4 x1 = *(const float4*)(p0 + 4);
      a0[0] = x0.x; a0[1] = x0.y; a0[2] = x0.z; a0[3] = x0.w;
      a0[4] = x1.x; a0[5] = x1.y; a0[6] = x1.z; a0[7] = x1.w;
    }
    if constexpr (BN != 0) {
      const float* mp = s_musc + kk + ko;
      float4 m0 = *(const float4*)mp, m1 = *(const float4*)(mp + 4);
      float4 s0 = *(const float4*)(mp + FD), s1 = *(const float4*)(mp + FD + 4);
      float mu[8] = {m0.x, m0.y, m0.z, m0.w, m1.x, m1.y, m1.z, m1.w};
      float sc[8] = {s0.x, s0.y, s0.z, s0.w, s1.x, s1.y, s1.z, s1.w};
#pragma unroll
      for (int i = 0; i < 8; ++i)
        a0[i] = fmaxf((a0[i] - mu[i]) * sc[i], 0.f);
    }
    bf16x8 ah, al;
#pragma unroll
    for (int i = 0; i < 8; ++i) {
      __bf16 h0 = (__bf16)a0[i];
      ah[i] = h0; al[i] = (__bf16)(a0[i] - (float)h0);
    }
#pragma unroll
    for (int ct = 0; ct < 8; ++ct) {
      int row = ct * 16 + r;
      int idx = row * FD + ((kk + ko) ^ ((r & 7) << 3));
      bf16x8 bh = *(const bf16x8*)(w_lds + idx);
      bf16x8 bl = *(const bf16x8*)(w_lds + FD * FD + idx);
      acc[ct] = __builtin_amdgcn_mfma_f32_16x16x32_bf16(ah, bh, acc[ct], 0, 0, 0);
      acc[ct] = __builtin_amdgcn_mfma_f32_16x16x32_bf16(ah, bl, acc[ct], 0, 0, 0);
      acc[ct] = __builtin_amdgcn_mfma_f32_16x16x32_bf16(al, bh, acc[ct], 0, 0, 0);
    }
  }
  // C/D layout: col = lane&15 (=r), row = g*4 + reg
#pragma unroll
  for (int ct = 0; ct < 8; ++ct)
#pragma unroll
    for (int i = 0; i < 4; ++i)
      hb[(size_t)(rt * 16 + g * 4 + i) * FD + ct * 16 + r] = f2bf(acc[ct][i]);
}

// ---------------- aggregation: 16 lanes/node; all h reads from bf16 hb ----------------
template <int STATS>
__global__ __launch_bounds__(256) void k_agg(const unsigned short* __restrict__ hb,
                                             const float* __restrict__ dinv,
                                             const float* __restrict__ bias, const int* __restrict__ row_off,
                                             const int2* __restrict__ csr, float* __restrict__ out,
                                             float* __restrict__ bn8) {
  int t = threadIdx.x;
  int n = blockIdx.x * 16 + (t >> 4);
  int q = t & 15;
  const uint4* hb4 = (const uint4*)hb;
  float dv = dinv[n];
  float s2 = dv * dv;
  float4 acc0 = ((const float4*)bias)[q * 2];
  float4 acc1 = ((const float4*)bias)[q * 2 + 1];
  {
    uint4 pv = hb4[(size_t)n * 16 + q];
    acc0.x = fmaf(s2, __uint_as_float(pv.x << 16), acc0.x);
    acc0.y = fmaf(s2, __uint_as_float(pv.x & 0xffff0000u), acc0.y);
    acc0.z = fmaf(s2, __uint_as_float(pv.y << 16), acc0.z);
    acc0.w = fmaf(s2, __uint_as_float(pv.y & 0xffff0000u), acc0.w);
    acc1.x = fmaf(s2, __uint_as_float(pv.z << 16), acc1.x);
    acc1.y = fmaf(s2, __uint_as_float(pv.z & 0xffff0000u), acc1.y);
    acc1.z = fmaf(s2, __uint_as_float(pv.w << 16), acc1.z);
    acc1.w = fmaf(s2, __uint_as_float(pv.w & 0xffff0000u), acc1.w);
  }
  int lo = row_off[n], hi = row_off[n + 1];
  for (int j = lo; j < hi; ++j) {
    int2 e = csr[j];
    float w = __int_as_float(e.y);
    uint4 pv = hb4[(size_t)e.x * 16 + q];
    acc0.x = fmaf(w, __uint_as_float(pv.x << 16), acc0.x);
    acc0.y = fmaf(w, __uint_as_float(pv.x & 0xffff0000u), acc0.y);
    acc0.z = fmaf(w, __uint_as_float(pv.y << 16), acc0.z);
    acc0.w = fmaf(w, __uint_as_float(pv.y & 0xffff0000u), acc0.w);
    acc1.x = fmaf(w, __uint_as_float(pv.z << 16), acc1.x);
    acc1.y = fmaf(w, __uint_as_float(pv.z & 0xffff0000u), acc1.y);
    acc1.z = fmaf(w, __uint_as_float(pv.w << 16), acc1.z);
    acc1.w = fmaf(w, __uint_as_float(pv.w & 0xffff0000u), acc1.w);
  }
  ((float4*)out)[(size_t)n * 32 + q * 2] = acc0;
  ((float4*)out)[(size_t)n * 32 + q * 2 + 1] = acc1;

  if constexpr (STATS != 0) {
    __shared__ float red_s[16][FD + 4], red_q[16][FD + 4];
    int slot = t >> 4, f = q * 8;
    red_s[slot][f + 0] = acc0.x; red_s[slot][f + 1] = acc0.y;
    red_s[slot][f + 2] = acc0.z; red_s[slot][f + 3] = acc0.w;
    red_s[slot][f + 4] = acc1.x; red_s[slot][f + 5] = acc1.y;
    red_s[slot][f + 6] = acc1.z; red_s[slot][f + 7] = acc1.w;
    red_q[slot][f + 0] = acc0.x * acc0.x; red_q[slot][f + 1] = acc0.y * acc0.y;
    red_q[slot][f + 2] = acc0.z * acc0.z; red_q[slot][f + 3] = acc0.w * acc0.w;
    red_q[slot][f + 4] = acc1.x * acc1.x; red_q[slot][f + 5] = acc1.y * acc1.y;
    red_q[slot][f + 6] = acc1.z * acc1.z; red_q[slot][f + 7] = acc1.w * acc1.w;
    __syncthreads();
    if (t < FD) {
      float s = 0.f, qq = 0.f;
#pragma unroll
      for (int m = 0; m < 16; ++m) { s += red_s[m][t]; qq += red_q[m][t]; }
      int c = (blockIdx.x & 7) * FD + t;
      unsafeAtomicAdd(&bn8[c], s);
      unsafeAtomicAdd(&bn8[1024 + c], qq);
    }
  }
}

// ---------------- fused pool/head ----------------
__global__ __launch_bounds__(512) void k_poolfinal(const float* __restrict__ h, const int* __restrict__ gstart,
                                                   const float* __restrict__ Wlin, const float* __restrict__ blin,
                                                   float* __restrict__ out) {
  __shared__ float ps[4][FD];
  __shared__ float pp[FD];
  int g = blockIdx.x, t = threadIdx.x;
  int part = t >> 7, f = t & 127;
  int lo = gstart[g], hi = gstart[g + 1];
  float s = 0.f;
  for (int n = lo + part; n < hi; n += 4) s += h[(size_t)n * FD + f];
  ps[part][f] = s;
  __syncthreads();
  if (t < FD) {
    float tot = ps[0][t] + ps[1][t] + ps[2][t] + ps[3][t];
    pp[t] = tot * (1.0f / fmaxf((float)(hi - lo), 1.0f));
  }
  __syncthreads();
  if (t < NC) {
    float a = blin[t];
    for (int k = 0; k < FD; ++k) a = fmaf(pp[k], Wlin[t * FD + k], a);
    out[g * NC + t] = a;
  }
}

// ---------------- launch ----------------
extern "C" void kernel_launch(void* const* d_in, const int* in_sizes, int n_in,
                              void* d_out, int out_size, void* d_ws, size_t ws_size,
                              hipStream_t stream) {
  const float* x    = (const float*)d_in[0];
  const int*   ei   = (const int*)d_in[1];
  const int*   batch= (const int*)d_in[2];
  const float* W1   = (const float*)d_in[3];
  const float* b1   = (const float*)d_in[4];
  const float* W2   = (const float*)d_in[5];
  const float* b2   = (const float*)d_in[6];
  const float* W3   = (const float*)d_in[7];
  const float* b3   = (const float*)d_in[8];
  const float* Wlin = (const float*)d_in[9];
  const float* blin = (const float*)d_in[10];
  float* out = (float*)d_out;
  float* ws  = (float*)d_ws;

  const int* srcI = ei;
  const int* dstI = ei + NE;

  float* deg    = ws;                       // 50048; count then dinv
  float* bnA    = ws + 50048;               // 2048 (sum8 | sq8)
  float* bnB    = bnA + 2048;               // 2048
  float* bufB   = bnB + 2048;               // NN*FD fp32 (agg out / gemm A in)
  int2*  csr    = (int2*)(bufB + NN * FD);  // NE int2
  int*   row_off= (int*)(csr + NE);         // 50048
  int*   cursor = row_off + 50048;          // 50048
  int*   gstart = cursor + 50048;           // 1024
  int*   bsum   = gstart + 1024;            // 256
  int*   bbase  = bsum + 256;               // 256
  unsigned short* w2 = (unsigned short*)(bbase + 256);  // 3*32768, pre-swizzled [hi|lo]
  unsigned short* hb = w2 + 3 * 32768;      // NN*FD bf16 gemm output

  dim3 B(256);
  const int gE    = (NE + 255) / 256;    // 2344
  const int gGemm = (NN / 16 + 3) / 4;   // 782 blocks, 1 rt/wave
  const int gAgg  = NN / 16;             // 3125

  // zero deg + bn accumulators
  hipMemsetAsync(ws, 0, (50048 + 4096) * sizeof(float), stream);

  k_deg_scatter<<<gE, B, 0, stream>>>(dstI, deg);
  k_bsum<<<NB, B, 0, stream>>>(deg, bsum);
  k_bscan<<<1, B, 0, stream>>>(bsum, bbase);
  k_rowoff<<<NB, B, 0, stream>>>(deg, bbase, row_off, cursor);
  k_pre<<<PRE_FILL + PRE_CVT + 3, B, 0, stream>>>(srcI, dstI, deg, cursor, csr,
                                                  W1, W2, W3, w2, batch, gstart);

  // layer 1
  k_gemm<0><<<gGemm, B, 0, stream>>>(x, nullptr, w2, hb);
  k_agg<1><<<gAgg, B, 0, stream>>>(hb, deg, b1, row_off, csr, bufB, bnA);

  // layer 2 (BN+ReLU+musc-reduce fused into GEMM)
  k_gemm<1><<<gGemm, B, 0, stream>>>(bufB, bnA, w2 + 32768, hb);
  k_agg<1><<<gAgg, B, 0, stream>>>(hb, deg, b2, row_off, csr, bufB, bnB);

  // layer 3
  k_gemm<1><<<gGemm, B, 0, stream>>>(bufB, bnB, w2 + 65536, hb);
  k_agg<0><<<gAgg, B, 0, stream>>>(hb, deg, b3, row_off, csr, bufB, nullptr);

  // pool + head
  k_poolfinal<<<NG, 512, 0, stream>>>(bufB, gstart, Wlin, blin, out);
}

// Round 14
// 246.120 us; speedup vs baseline: 2.1068x; 1.0033x over previous
//
#include <hip/hip_runtime.h>
#include <hip/hip_bf16.h>

#define NN 50000
#define NE 600000
#define FD 128
#define NG 512
#define NC 10
static constexpr float EPS_BN = 1e-5f;

typedef __bf16 bf16x8 __attribute__((ext_vector_type(8)));
typedef float f32x4 __attribute__((ext_vector_type(4)));

__device__ __forceinline__ unsigned short f2bf(float x) {
  unsigned u = __float_as_uint(x);
  u = (u + 0x7FFFu + ((u >> 16) & 1u)) >> 16;
  return (unsigned short)u;
}
__device__ __forceinline__ float bf2f(unsigned short h) {
  return __uint_as_float(((unsigned)h) << 16);
}

// ---------------- zero deg + bn accumulators (replaces 41us runtime fillBuffer) ----------------
// zeroes 50048 (deg) + 2048 (bnA) + 2048 (bnB) floats = 13536 float4s
__global__ __launch_bounds__(256) void k_zero(float4* __restrict__ p) {
  int i = blockIdx.x * 256 + threadIdx.x;
  if (i < 13536) p[i] = make_float4(0.f, 0.f, 0.f, 0.f);
}

// ---------------- degree (deg zeroed; holds in-edge count) ----------------
__global__ __launch_bounds__(256) void k_deg_scatter(const int* __restrict__ dst, float* __restrict__ deg) {
  int e = blockIdx.x * 256 + threadIdx.x;
  if (e < NE) unsafeAtomicAdd(&deg[dst[e]], 1.0f);
}

// ---------------- CSR build: multi-block exclusive scan of in-edge counts ----------------
#define NB 196   // ceil(50000/256)
__global__ __launch_bounds__(256) void k_bsum(const float* __restrict__ deg, int* __restrict__ bsum) {
  __shared__ int s[256];
  int t = threadIdx.x, i = blockIdx.x * 256 + t;
  s[t] = (i < NN) ? (int)deg[i] : 0;
  __syncthreads();
  for (int o = 128; o > 0; o >>= 1) { if (t < o) s[t] += s[t + o]; __syncthreads(); }
  if (t == 0) bsum[blockIdx.x] = s[0];
}

__global__ __launch_bounds__(256) void k_bscan(const int* __restrict__ bsum, int* __restrict__ bbase) {
  __shared__ int s[256];
  int t = threadIdx.x;
  int v = (t < NB) ? bsum[t] : 0;
  s[t] = v; __syncthreads();
  for (int o = 1; o < 256; o <<= 1) {
    int a = (t >= o) ? s[t - o] : 0; __syncthreads();
    s[t] += a; __syncthreads();
  }
  if (t < NB) bbase[t] = s[t] - v;
}

// also transforms deg (count) -> dinv = rsqrt(count+1)
__global__ __launch_bounds__(256) void k_rowoff(float* __restrict__ deg, const int* __restrict__ bbase,
                                                int* __restrict__ row_off, int* __restrict__ cursor) {
  __shared__ int s[256];
  int t = threadIdx.x, i = blockIdx.x * 256 + t;
  float dv = (i < NN) ? deg[i] : 0.f;
  int c = (int)dv;
  s[t] = c; __syncthreads();
  for (int o = 1; o < 256; o <<= 1) {
    int a = (t >= o) ? s[t - o] : 0; __syncthreads();
    s[t] += a; __syncthreads();
  }
  int excl = s[t] - c + bbase[blockIdx.x];
  if (i <= NN) {
    row_off[i] = excl;
    if (i < NN) {
      cursor[i] = excl;
      deg[i] = rsqrtf(dv + 1.0f);
    }
  }
}

// ---------------- fused preamble: XCD-partitioned CSR fill + weight cvt + gstart ----------------
#define FILL_CHUNKS 293                       // 293*2048 >= 600000
#define PRE_FILL (8 * FILL_CHUNKS)            // 2344
#define PRE_CVT  48
#define DRANGE 6250
__global__ __launch_bounds__(256) void k_pre(const int* __restrict__ src, const int* __restrict__ dst,
                                             const float* __restrict__ dinv, int* __restrict__ cursor,
                                             int2* __restrict__ csr,
                                             const float* __restrict__ W1, const float* __restrict__ W2,
                                             const float* __restrict__ W3, unsigned short* __restrict__ w2,
                                             const int* __restrict__ batch, int* __restrict__ gstart) {
  int b = blockIdx.x, t = threadIdx.x;
  if (b < PRE_FILL) {
    int g = b & 7;
    int chunk = b >> 3;
    int dlo = g * DRANGE, dhi = dlo + DRANGE;
    int e0 = chunk * 2048;
#pragma unroll
    for (int i = 0; i < 8; ++i) {
      int e = e0 + i * 256 + t;
      if (e < NE) {
        int d = dst[e];
        if (d >= dlo && d < dhi) {
          int s = src[e];
          float nrm = dinv[s] * dinv[d];
          int pos = atomicAdd(&cursor[d], 1);
          csr[pos] = make_int2(s, __float_as_int(nrm));
        }
      }
    }
  } else if (b < PRE_FILL + PRE_CVT) {
    int bb = b - PRE_FILL;
    int m = bb >> 4;
    const float* W = (m == 0) ? W1 : ((m == 1) ? W2 : W3);
    int i = (bb & 15) * 256 + t;           // 0..4095, 4 elems each
    float4 v = ((const float4*)W)[i];
    ushort4 hv, lv;
    hv.x = f2bf(v.x); lv.x = f2bf(v.x - bf2f(hv.x));
    hv.y = f2bf(v.y); lv.y = f2bf(v.y - bf2f(hv.y));
    hv.z = f2bf(v.z); lv.z = f2bf(v.z - bf2f(hv.z));
    hv.w = f2bf(v.w); lv.w = f2bf(v.w - bf2f(hv.w));
    int e0 = i * 4, row = e0 >> 7, col = e0 & 127;
    int sc_ = ((col & 120) ^ ((row & 7) << 3)) | (col & 7);   // 16B-group XOR swizzle
    unsigned short* base = w2 + m * 32768 + row * FD + sc_;
    *(ushort4*)base = hv;
    *(ushort4*)(base + 16384) = lv;
  } else {
    int g = (b - PRE_FILL - PRE_CVT) * 256 + t;
    if (g > NG) return;
    int lo = 0, hi = NN;
    while (lo < hi) {
      int mid = (lo + hi) >> 1;
      if (batch[mid] < g) lo = mid + 1; else hi = mid;
    }
    gstart[g] = lo;
  }
}

// ---------------- MFMA GEMM: W LDS-staged, 1 row-tile/wave; writes ONLY bf16 hb ----------------
template <int BN>
__global__ __launch_bounds__(256) void k_gemm(const float* __restrict__ in, const float* __restrict__ bn8,
                                              const unsigned short* __restrict__ wsrc,
                                              unsigned short* __restrict__ hb) {
  __shared__ unsigned short w_lds[2 * FD * FD];   // 64KB, already swizzled
  __shared__ float s_musc[2 * FD];
  int t = threadIdx.x;
  {
    const uint4* s4 = (const uint4*)wsrc;
    uint4* d4 = (uint4*)w_lds;
#pragma unroll
    for (int c = 0; c < 16; ++c) d4[c * 256 + t] = s4[c * 256 + t];
  }
  if constexpr (BN != 0) {
    if (t < FD) {
      float s = 0.f, q = 0.f;
#pragma unroll
      for (int c = 0; c < 8; ++c) { s += bn8[c * FD + t]; q += bn8[1024 + c * FD + t]; }
      float m = s * (1.0f / NN);
      float v = fmaxf(q * (1.0f / NN) - m * m, 0.f);
      s_musc[t] = m;
      s_musc[FD + t] = rsqrtf(v + EPS_BN);
    }
  }
  __syncthreads();

  int w = t >> 6, l = t & 63;
  int rt = blockIdx.x * 4 + w;
  if (rt >= NN / 16) return;
  int r = l & 15, g = l >> 4;
  int ko = g * 8;
  f32x4 acc[8];
#pragma unroll
  for (int ct = 0; ct < 8; ++ct) acc[ct] = (f32x4){0.f, 0.f, 0.f, 0.f};

#pragma unroll
  for (int kk = 0; kk < FD; kk += 32) {
    float a0[8];
    {
      const float* p0 = in + (size_t)(rt * 16 + r) * FD + kk + ko;
      float4 x0 = *(const float4*)p0;
      float4 x1 = *(const float4*)(p0 + 4);
      a0[0] = x0.x; a0[1] = x0.y; a0[2] = x0.z; a0[3] = x0.w;
      a0[4] = x1.x; a0[5] = x1.y; a0[6] = x1.z; a0[7] = x1.w;
    }
    if constexpr (BN != 0) {
      const float* mp = s_musc + kk + ko;
      float4 m0 = *(const float4*)mp, m1 = *(const float4*)(mp + 4);
      float4 s0 = *(const float4*)(mp + FD), s1 = *(const float4*)(mp + FD + 4);
      float mu[8] = {m0.x, m0.y, m0.z, m0.w, m1.x, m1.y, m1.z, m1.w};
      float sc[8] = {s0.x, s0.y, s0.z, s0.w, s1.x, s1.y, s1.z, s1.w};
#pragma unroll
      for (int i = 0; i < 8; ++i)
        a0[i] = fmaxf((a0[i] - mu[i]) * sc[i], 0.f);
    }
    bf16x8 ah, al;
#pragma unroll
    for (int i = 0; i < 8; ++i) {
      __bf16 h0 = (__bf16)a0[i];
      ah[i] = h0; al[i] = (__bf16)(a0[i] - (float)h0);
    }
#pragma unroll
    for (int ct = 0; ct < 8; ++ct) {
      int row = ct * 16 + r;
      int idx = row * FD + ((kk + ko) ^ ((r & 7) << 3));
      bf16x8 bh = *(const bf16x8*)(w_lds + idx);
      bf16x8 bl = *(const bf16x8*)(w_lds + FD * FD + idx);
      acc[ct] = __builtin_amdgcn_mfma_f32_16x16x32_bf16(ah, bh, acc[ct], 0, 0, 0);
      acc[ct] = __builtin_amdgcn_mfma_f32_16x16x32_bf16(ah, bl, acc[ct], 0, 0, 0);
      acc[ct] = __builtin_amdgcn_mfma_f32_16x16x32_bf16(al, bh, acc[ct], 0, 0, 0);
    }
  }
  // C/D layout: col = lane&15 (=r), row = g*4 + reg
#pragma unroll
  for (int ct = 0; ct < 8; ++ct)
#pragma unroll
    for (int i = 0; i < 4; ++i)
      hb[(size_t)(rt * 16 + g * 4 + i) * FD + ct * 16 + r] = f2bf(acc[ct][i]);
}

// ---------------- aggregation: 16 lanes/node; all h reads from bf16 hb ----------------
template <int STATS>
__global__ __launch_bounds__(256) void k_agg(const unsigned short* __restrict__ hb,
                                             const float* __restrict__ dinv,
                                             const float* __restrict__ bias, const int* __restrict__ row_off,
                                             const int2* __restrict__ csr, float* __restrict__ out,
                                             float* __restrict__ bn8) {
  int t = threadIdx.x;
  int n = blockIdx.x * 16 + (t >> 4);
  int q = t & 15;
  const uint4* hb4 = (const uint4*)hb;
  float dv = dinv[n];
  float s2 = dv * dv;
  float4 acc0 = ((const float4*)bias)[q * 2];
  float4 acc1 = ((const float4*)bias)[q * 2 + 1];
  {
    uint4 pv = hb4[(size_t)n * 16 + q];
    acc0.x = fmaf(s2, __uint_as_float(pv.x << 16), acc0.x);
    acc0.y = fmaf(s2, __uint_as_float(pv.x & 0xffff0000u), acc0.y);
    acc0.z = fmaf(s2, __uint_as_float(pv.y << 16), acc0.z);
    acc0.w = fmaf(s2, __uint_as_float(pv.y & 0xffff0000u), acc0.w);
    acc1.x = fmaf(s2, __uint_as_float(pv.z << 16), acc1.x);
    acc1.y = fmaf(s2, __uint_as_float(pv.z & 0xffff0000u), acc1.y);
    acc1.z = fmaf(s2, __uint_as_float(pv.w << 16), acc1.z);
    acc1.w = fmaf(s2, __uint_as_float(pv.w & 0xffff0000u), acc1.w);
  }
  int lo = row_off[n], hi = row_off[n + 1];
  for (int j = lo; j < hi; ++j) {
    int2 e = csr[j];
    float w = __int_as_float(e.y);
    uint4 pv = hb4[(size_t)e.x * 16 + q];
    acc0.x = fmaf(w, __uint_as_float(pv.x << 16), acc0.x);
    acc0.y = fmaf(w, __uint_as_float(pv.x & 0xffff0000u), acc0.y);
    acc0.z = fmaf(w, __uint_as_float(pv.y << 16), acc0.z);
    acc0.w = fmaf(w, __uint_as_float(pv.y & 0xffff0000u), acc0.w);
    acc1.x = fmaf(w, __uint_as_float(pv.z << 16), acc1.x);
    acc1.y = fmaf(w, __uint_as_float(pv.z & 0xffff0000u), acc1.y);
    acc1.z = fmaf(w, __uint_as_float(pv.w << 16), acc1.z);
    acc1.w = fmaf(w, __uint_as_float(pv.w & 0xffff0000u), acc1.w);
  }
  ((float4*)out)[(size_t)n * 32 + q * 2] = acc0;
  ((float4*)out)[(size_t)n * 32 + q * 2 + 1] = acc1;

  if constexpr (STATS != 0) {
    __shared__ float red_s[16][FD + 4], red_q[16][FD + 4];
    int slot = t >> 4, f = q * 8;
    red_s[slot][f + 0] = acc0.x; red_s[slot][f + 1] = acc0.y;
    red_s[slot][f + 2] = acc0.z; red_s[slot][f + 3] = acc0.w;
    red_s[slot][f + 4] = acc1.x; red_s[slot][f + 5] = acc1.y;
    red_s[slot][f + 6] = acc1.z; red_s[slot][f + 7] = acc1.w;
    red_q[slot][f + 0] = acc0.x * acc0.x; red_q[slot][f + 1] = acc0.y * acc0.y;
    red_q[slot][f + 2] = acc0.z * acc0.z; red_q[slot][f + 3] = acc0.w * acc0.w;
    red_q[slot][f + 4] = acc1.x * acc1.x; red_q[slot][f + 5] = acc1.y * acc1.y;
    red_q[slot][f + 6] = acc1.z * acc1.z; red_q[slot][f + 7] = acc1.w * acc1.w;
    __syncthreads();
    if (t < FD) {
      float s = 0.f, qq = 0.f;
#pragma unroll
      for (int m = 0; m < 16; ++m) { s += red_s[m][t]; qq += red_q[m][t]; }
      int c = (blockIdx.x & 7) * FD + t;
      unsafeAtomicAdd(&bn8[c], s);
      unsafeAtomicAdd(&bn8[1024 + c], qq);
    }
  }
}

// ---------------- fused pool/head ----------------
__global__ __launch_bounds__(512) void k_poolfinal(const float* __restrict__ h, const int* __restrict__ gstart,
                                                   const float* __restrict__ Wlin, const float* __restrict__ blin,
                                                   float* __restrict__ out) {
  __shared__ float ps[4][FD];
  __shared__ float pp[FD];
  int g = blockIdx.x, t = threadIdx.x;
  int part = t >> 7, f = t & 127;
  int lo = gstart[g], hi = gstart[g + 1];
  float s = 0.f;
  for (int n = lo + part; n < hi; n += 4) s += h[(size_t)n * FD + f];
  ps[part][f] = s;
  __syncthreads();
  if (t < FD) {
    float tot = ps[0][t] + ps[1][t] + ps[2][t] + ps[3][t];
    pp[t] = tot * (1.0f / fmaxf((float)(hi - lo), 1.0f));
  }
  __syncthreads();
  if (t < NC) {
    float a = blin[t];
    for (int k = 0; k < FD; ++k) a = fmaf(pp[k], Wlin[t * FD + k], a);
    out[g * NC + t] = a;
  }
}

// ---------------- launch ----------------
extern "C" void kernel_launch(void* const* d_in, const int* in_sizes, int n_in,
                              void* d_out, int out_size, void* d_ws, size_t ws_size,
                              hipStream_t stream) {
  const float* x    = (const float*)d_in[0];
  const int*   ei   = (const int*)d_in[1];
  const int*   batch= (const int*)d_in[2];
  const float* W1   = (const float*)d_in[3];
  const float* b1   = (const float*)d_in[4];
  const float* W2   = (const float*)d_in[5];
  const float* b2   = (const float*)d_in[6];
  const float* W3   = (const float*)d_in[7];
  const float* b3   = (const float*)d_in[8];
  const float* Wlin = (const float*)d_in[9];
  const float* blin = (const float*)d_in[10];
  float* out = (float*)d_out;
  float* ws  = (float*)d_ws;

  const int* srcI = ei;
  const int* dstI = ei + NE;

  float* deg    = ws;                       // 50048; count then dinv
  float* bnA    = ws + 50048;               // 2048 (sum8 | sq8)
  float* bnB    = bnA + 2048;               // 2048
  float* bufB   = bnB + 2048;               // NN*FD fp32 (agg out / gemm A in)
  int2*  csr    = (int2*)(bufB + NN * FD);  // NE int2
  int*   row_off= (int*)(csr + NE);         // 50048
  int*   cursor = row_off + 50048;          // 50048
  int*   gstart = cursor + 50048;           // 1024
  int*   bsum   = gstart + 1024;            // 256
  int*   bbase  = bsum + 256;               // 256
  unsigned short* w2 = (unsigned short*)(bbase + 256);  // 3*32768, pre-swizzled [hi|lo]
  unsigned short* hb = w2 + 3 * 32768;      // NN*FD bf16 gemm output

  dim3 B(256);
  const int gE    = (NE + 255) / 256;    // 2344
  const int gGemm = (NN / 16 + 3) / 4;   // 782 blocks, 1 rt/wave
  const int gAgg  = NN / 16;             // 3125

  // zero deg + bn accumulators with our own kernel (runtime fillBuffer took ~41us in-graph)
  k_zero<<<53, B, 0, stream>>>((float4*)ws);

  k_deg_scatter<<<gE, B, 0, stream>>>(dstI, deg);
  k_bsum<<<NB, B, 0, stream>>>(deg, bsum);
  k_bscan<<<1, B, 0, stream>>>(bsum, bbase);
  k_rowoff<<<NB, B, 0, stream>>>(deg, bbase, row_off, cursor);
  k_pre<<<PRE_FILL + PRE_CVT + 3, B, 0, stream>>>(srcI, dstI, deg, cursor, csr,
                                                  W1, W2, W3, w2, batch, gstart);

  // layer 1
  k_gemm<0><<<gGemm, B, 0, stream>>>(x, nullptr, w2, hb);
  k_agg<1><<<gAgg, B, 0, stream>>>(hb, deg, b1, row_off, csr, bufB, bnA);

  // layer 2 (BN+ReLU+musc-reduce fused into GEMM)
  k_gemm<1><<<gGemm, B, 0, stream>>>(bufB, bnA, w2 + 32768, hb);
  k_agg<1><<<gAgg, B, 0, stream>>>(hb, deg, b2, row_off, csr, bufB, bnB);

  // layer 3
  k_gemm<1><<<gGemm, B, 0, stream>>>(bufB, bnB, w2 + 65536, hb);
  k_agg<0><<<gAgg, B, 0, stream>>>(hb, deg, b3, row_off, csr, bufB, nullptr);

  // pool + head
  k_poolfinal<<<NG, 512, 0, stream>>>(bufB, gstart, Wlin, blin, out);
}

// Round 15
// 241.838 us; speedup vs baseline: 2.1441x; 1.0177x over previous
//
#include <hip/hip_runtime.h>
#include <hip/hip_bf16.h>

#define NN 50000
#define NE 600000
#define FD 128
#define NG 512
#define NC 10
static constexpr float EPS_BN = 1e-5f;

typedef __bf16 bf16x8 __attribute__((ext_vector_type(8)));
typedef float f32x4 __attribute__((ext_vector_type(4)));

__device__ __forceinline__ unsigned short f2bf(float x) {
  unsigned u = __float_as_uint(x);
  u = (u + 0x7FFFu + ((u >> 16) & 1u)) >> 16;
  return (unsigned short)u;
}
__device__ __forceinline__ float bf2f(unsigned short h) {
  return __uint_as_float(((unsigned)h) << 16);
}

// ---------------- zero deg + bn accumulators ----------------
__global__ __launch_bounds__(256) void k_zero(float4* __restrict__ p) {
  int i = blockIdx.x * 256 + threadIdx.x;
  if (i < 13536) p[i] = make_float4(0.f, 0.f, 0.f, 0.f);
}

// ---------------- degree: XCD-partitioned scatter (group g=blockIdx&7 owns dst range) ----------------
#define FILL_CHUNKS 293                       // 293*2048 >= 600000
#define GRID_E8 (8 * FILL_CHUNKS)             // 2344
#define DRANGE 6250
__global__ __launch_bounds__(256) void k_deg_scatter(const int* __restrict__ dst, float* __restrict__ deg) {
  int b = blockIdx.x, t = threadIdx.x;
  int g = b & 7;
  int chunk = b >> 3;
  int dlo = g * DRANGE, dhi = dlo + DRANGE;
  int e0 = chunk * 2048;
#pragma unroll
  for (int i = 0; i < 8; ++i) {
    int e = e0 + i * 256 + t;
    if (e < NE) {
      int d = dst[e];
      if (d >= dlo && d < dhi) unsafeAtomicAdd(&deg[d], 1.0f);
    }
  }
}

// ---------------- CSR build: multi-block exclusive scan of in-edge counts ----------------
#define NB 196   // ceil(50000/256)
__global__ __launch_bounds__(256) void k_bsum(const float* __restrict__ deg, int* __restrict__ bsum) {
  __shared__ int s[256];
  int t = threadIdx.x, i = blockIdx.x * 256 + t;
  s[t] = (i < NN) ? (int)deg[i] : 0;
  __syncthreads();
  for (int o = 128; o > 0; o >>= 1) { if (t < o) s[t] += s[t + o]; __syncthreads(); }
  if (t == 0) bsum[blockIdx.x] = s[0];
}

__global__ __launch_bounds__(256) void k_bscan(const int* __restrict__ bsum, int* __restrict__ bbase) {
  __shared__ int s[256];
  int t = threadIdx.x;
  int v = (t < NB) ? bsum[t] : 0;
  s[t] = v; __syncthreads();
  for (int o = 1; o < 256; o <<= 1) {
    int a = (t >= o) ? s[t - o] : 0; __syncthreads();
    s[t] += a; __syncthreads();
  }
  if (t < NB) bbase[t] = s[t] - v;
}

// ---------------- rowoff (+dinv) fused with weight-cvt (hi only, pre-swizzled) and gstart ----------------
// blocks [0,196): rowoff; [196,244): cvt; [244,247): gstart
__global__ __launch_bounds__(256) void k_rowoff_cvt(float* __restrict__ deg, const int* __restrict__ bbase,
                                                    int* __restrict__ row_off, int* __restrict__ cursor,
                                                    const float* __restrict__ W1, const float* __restrict__ W2,
                                                    const float* __restrict__ W3, unsigned short* __restrict__ w2,
                                                    const int* __restrict__ batch, int* __restrict__ gstart) {
  int b = blockIdx.x, t = threadIdx.x;
  if (b < NB) {
    __shared__ int s[256];
    int i = b * 256 + t;
    float dv = (i < NN) ? deg[i] : 0.f;
    int c = (int)dv;
    s[t] = c; __syncthreads();
    for (int o = 1; o < 256; o <<= 1) {
      int a = (t >= o) ? s[t - o] : 0; __syncthreads();
      s[t] += a; __syncthreads();
    }
    int excl = s[t] - c + bbase[b];
    if (i <= NN) {
      row_off[i] = excl;
      if (i < NN) {
        cursor[i] = excl;
        deg[i] = rsqrtf(dv + 1.0f);
      }
    }
  } else if (b < NB + 48) {
    int bb = b - NB;
    int m = bb >> 4;
    const float* W = (m == 0) ? W1 : ((m == 1) ? W2 : W3);
    int i = (bb & 15) * 256 + t;           // 0..4095, 4 elems each
    float4 v = ((const float4*)W)[i];
    ushort4 hv;
    hv.x = f2bf(v.x); hv.y = f2bf(v.y); hv.z = f2bf(v.z); hv.w = f2bf(v.w);
    int e0 = i * 4, row = e0 >> 7, col = e0 & 127;
    int sc_ = ((col & 120) ^ ((row & 7) << 3)) | (col & 7);   // 16B-group XOR swizzle
    *(ushort4*)(w2 + m * FD * FD + row * FD + sc_) = hv;
  } else {
    int g = (b - NB - 48) * 256 + t;
    if (g > NG) return;
    int lo = 0, hi = NN;
    while (lo < hi) {
      int mid = (lo + hi) >> 1;
      if (batch[mid] < g) lo = mid + 1; else hi = mid;
    }
    gstart[g] = lo;
  }
}

// ---------------- CSR fill: XCD-partitioned ----------------
__global__ __launch_bounds__(256) void k_fill(const int* __restrict__ src, const int* __restrict__ dst,
                                              const float* __restrict__ dinv, int* __restrict__ cursor,
                                              int2* __restrict__ csr) {
  int b = blockIdx.x, t = threadIdx.x;
  int g = b & 7;
  int chunk = b >> 3;
  int dlo = g * DRANGE, dhi = dlo + DRANGE;
  int e0 = chunk * 2048;
#pragma unroll
  for (int i = 0; i < 8; ++i) {
    int e = e0 + i * 256 + t;
    if (e < NE) {
      int d = dst[e];
      if (d >= dlo && d < dhi) {
        int s = src[e];
        float nrm = dinv[s] * dinv[d];
        int pos = atomicAdd(&cursor[d], 1);
        csr[pos] = make_int2(s, __float_as_int(nrm));
      }
    }
  }
}

// ---------------- MFMA GEMM: W(bf16-hi) LDS-staged 32KB, x split hi+lo; writes bf16 hb ----------------
template <int BN>
__global__ __launch_bounds__(256) void k_gemm(const float* __restrict__ in, const float* __restrict__ bn8,
                                              const unsigned short* __restrict__ wsrc,
                                              unsigned short* __restrict__ hb) {
  __shared__ unsigned short w_lds[FD * FD];   // 32KB, pre-swizzled
  __shared__ float s_musc[2 * FD];
  int t = threadIdx.x;
  {
    const uint4* s4 = (const uint4*)wsrc;
    uint4* d4 = (uint4*)w_lds;
#pragma unroll
    for (int c = 0; c < 8; ++c) d4[c * 256 + t] = s4[c * 256 + t];
  }
  if constexpr (BN != 0) {
    if (t < FD) {
      float s = 0.f, q = 0.f;
#pragma unroll
      for (int c = 0; c < 8; ++c) { s += bn8[c * FD + t]; q += bn8[1024 + c * FD + t]; }
      float m = s * (1.0f / NN);
      float v = fmaxf(q * (1.0f / NN) - m * m, 0.f);
      s_musc[t] = m;
      s_musc[FD + t] = rsqrtf(v + EPS_BN);
    }
  }
  __syncthreads();

  int w = t >> 6, l = t & 63;
  int rt = blockIdx.x * 4 + w;
  if (rt >= NN / 16) return;
  int r = l & 15, g = l >> 4;
  int ko = g * 8;
  f32x4 acc[8];
#pragma unroll
  for (int ct = 0; ct < 8; ++ct) acc[ct] = (f32x4){0.f, 0.f, 0.f, 0.f};

#pragma unroll
  for (int kk = 0; kk < FD; kk += 32) {
    float a0[8];
    {
      const float* p0 = in + (size_t)(rt * 16 + r) * FD + kk + ko;
      float4 x0 = *(const float4*)p0;
      float4 x1 = *(const float4*)(p0 + 4);
      a0[0] = x0.x; a0[1] = x0.y; a0[2] = x0.z; a0[3] = x0.w;
      a0[4] = x1.x; a0[5] = x1.y; a0[6] = x1.z; a0[7] = x1.w;
    }
    if constexpr (BN != 0) {
      const float* mp = s_musc + kk + ko;
      float4 m0 = *(const float4*)mp, m1 = *(const float4*)(mp + 4);
      float4 s0 = *(const float4*)(mp + FD), s1 = *(const float4*)(mp + FD + 4);
      float mu[8] = {m0.x, m0.y, m0.z, m0.w, m1.x, m1.y, m1.z, m1.w};
      float sc[8] = {s0.x, s0.y, s0.z, s0.w, s1.x, s1.y, s1.z, s1.w};
#pragma unroll
      for (int i = 0; i < 8; ++i)
        a0[i] = fmaxf((a0[i] - mu[i]) * sc[i], 0.f);
    }
    bf16x8 ah, al;
#pragma unroll
    for (int i = 0; i < 8; ++i) {
      __bf16 h0 = (__bf16)a0[i];
      ah[i] = h0; al[i] = (__bf16)(a0[i] - (float)h0);
    }
#pragma unroll
    for (int ct = 0; ct < 8; ++ct) {
      int row = ct * 16 + r;
      int idx = row * FD + ((kk + ko) ^ ((r & 7) << 3));
      bf16x8 bh = *(const bf16x8*)(w_lds + idx);
      acc[ct] = __builtin_amdgcn_mfma_f32_16x16x32_bf16(ah, bh, acc[ct], 0, 0, 0);
      acc[ct] = __builtin_amdgcn_mfma_f32_16x16x32_bf16(al, bh, acc[ct], 0, 0, 0);
    }
  }
  // C/D layout: col = lane&15 (=r), row = g*4 + reg
#pragma unroll
  for (int ct = 0; ct < 8; ++ct)
#pragma unroll
    for (int i = 0; i < 4; ++i)
      hb[(size_t)(rt * 16 + g * 4 + i) * FD + ct * 16 + r] = f2bf(acc[ct][i]);
}

// ---------------- aggregation: 16 lanes/node; all h reads from bf16 hb ----------------
template <int STATS>
__global__ __launch_bounds__(256) void k_agg(const unsigned short* __restrict__ hb,
                                             const float* __restrict__ dinv,
                                             const float* __restrict__ bias, const int* __restrict__ row_off,
                                             const int2* __restrict__ csr, float* __restrict__ out,
                                             float* __restrict__ bn8) {
  int t = threadIdx.x;
  int n = blockIdx.x * 16 + (t >> 4);
  int q = t & 15;
  const uint4* hb4 = (const uint4*)hb;
  float dv = dinv[n];
  float s2 = dv * dv;
  float4 acc0 = ((const float4*)bias)[q * 2];
  float4 acc1 = ((const float4*)bias)[q * 2 + 1];
  {
    uint4 pv = hb4[(size_t)n * 16 + q];
    acc0.x = fmaf(s2, __uint_as_float(pv.x << 16), acc0.x);
    acc0.y = fmaf(s2, __uint_as_float(pv.x & 0xffff0000u), acc0.y);
    acc0.z = fmaf(s2, __uint_as_float(pv.y << 16), acc0.z);
    acc0.w = fmaf(s2, __uint_as_float(pv.y & 0xffff0000u), acc0.w);
    acc1.x = fmaf(s2, __uint_as_float(pv.z << 16), acc1.x);
    acc1.y = fmaf(s2, __uint_as_float(pv.z & 0xffff0000u), acc1.y);
    acc1.z = fmaf(s2, __uint_as_float(pv.w << 16), acc1.z);
    acc1.w = fmaf(s2, __uint_as_float(pv.w & 0xffff0000u), acc1.w);
  }
  int lo = row_off[n], hi = row_off[n + 1];
  for (int j = lo; j < hi; ++j) {
    int2 e = csr[j];
    float w = __int_as_float(e.y);
    uint4 pv = hb4[(size_t)e.x * 16 + q];
    acc0.x = fmaf(w, __uint_as_float(pv.x << 16), acc0.x);
    acc0.y = fmaf(w, __uint_as_float(pv.x & 0xffff0000u), acc0.y);
    acc0.z = fmaf(w, __uint_as_float(pv.y << 16), acc0.z);
    acc0.w = fmaf(w, __uint_as_float(pv.y & 0xffff0000u), acc0.w);
    acc1.x = fmaf(w, __uint_as_float(pv.z << 16), acc1.x);
    acc1.y = fmaf(w, __uint_as_float(pv.z & 0xffff0000u), acc1.y);
    acc1.z = fmaf(w, __uint_as_float(pv.w << 16), acc1.z);
    acc1.w = fmaf(w, __uint_as_float(pv.w & 0xffff0000u), acc1.w);
  }
  ((float4*)out)[(size_t)n * 32 + q * 2] = acc0;
  ((float4*)out)[(size_t)n * 32 + q * 2 + 1] = acc1;

  if constexpr (STATS != 0) {
    __shared__ float red_s[16][FD + 4], red_q[16][FD + 4];
    int slot = t >> 4, f = q * 8;
    red_s[slot][f + 0] = acc0.x; red_s[slot][f + 1] = acc0.y;
    red_s[slot][f + 2] = acc0.z; red_s[slot][f + 3] = acc0.w;
    red_s[slot][f + 4] = acc1.x; red_s[slot][f + 5] = acc1.y;
    red_s[slot][f + 6] = acc1.z; red_s[slot][f + 7] = acc1.w;
    red_q[slot][f + 0] = acc0.x * acc0.x; red_q[slot][f + 1] = acc0.y * acc0.y;
    red_q[slot][f + 2] = acc0.z * acc0.z; red_q[slot][f + 3] = acc0.w * acc0.w;
    red_q[slot][f + 4] = acc1.x * acc1.x; red_q[slot][f + 5] = acc1.y * acc1.y;
    red_q[slot][f + 6] = acc1.z * acc1.z; red_q[slot][f + 7] = acc1.w * acc1.w;
    __syncthreads();
    if (t < FD) {
      float s = 0.f, qq = 0.f;
#pragma unroll
      for (int m = 0; m < 16; ++m) { s += red_s[m][t]; qq += red_q[m][t]; }
      int c = (blockIdx.x & 7) * FD + t;
      unsafeAtomicAdd(&bn8[c], s);
      unsafeAtomicAdd(&bn8[1024 + c], qq);
    }
  }
}

// ---------------- fused pool/head ----------------
__global__ __launch_bounds__(512) void k_poolfinal(const float* __restrict__ h, const int* __restrict__ gstart,
                                                   const float* __restrict__ Wlin, const float* __restrict__ blin,
                                                   float* __restrict__ out) {
  __shared__ float ps[4][FD];
  __shared__ float pp[FD];
  int g = blockIdx.x, t = threadIdx.x;
  int part = t >> 7, f = t & 127;
  int lo = gstart[g], hi = gstart[g + 1];
  float s = 0.f;
  for (int n = lo + part; n < hi; n += 4) s += h[(size_t)n * FD + f];
  ps[part][f] = s;
  __syncthreads();
  if (t < FD) {
    float tot = ps[0][t] + ps[1][t] + ps[2][t] + ps[3][t];
    pp[t] = tot * (1.0f / fmaxf((float)(hi - lo), 1.0f));
  }
  __syncthreads();
  if (t < NC) {
    float a = blin[t];
    for (int k = 0; k < FD; ++k) a = fmaf(pp[k], Wlin[t * FD + k], a);
    out[g * NC + t] = a;
  }
}

// ---------------- launch ----------------
extern "C" void kernel_launch(void* const* d_in, const int* in_sizes, int n_in,
                              void* d_out, int out_size, void* d_ws, size_t ws_size,
                              hipStream_t stream) {
  const float* x    = (const float*)d_in[0];
  const int*   ei   = (const int*)d_in[1];
  const int*   batch= (const int*)d_in[2];
  const float* W1   = (const float*)d_in[3];
  const float* b1   = (const float*)d_in[4];
  const float* W2   = (const float*)d_in[5];
  const float* b2   = (const float*)d_in[6];
  const float* W3   = (const float*)d_in[7];
  const float* b3   = (const float*)d_in[8];
  const float* Wlin = (const float*)d_in[9];
  const float* blin = (const float*)d_in[10];
  float* out = (float*)d_out;
  float* ws  = (float*)d_ws;

  const int* srcI = ei;
  const int* dstI = ei + NE;

  float* deg    = ws;                       // 50048; count then dinv
  float* bnA    = ws + 50048;               // 2048 (sum8 | sq8)
  float* bnB    = bnA + 2048;               // 2048
  float* bufB   = bnB + 2048;               // NN*FD fp32 (agg out / gemm A in)
  int2*  csr    = (int2*)(bufB + NN * FD);  // NE int2
  int*   row_off= (int*)(csr + NE);         // 50048
  int*   cursor = row_off + 50048;          // 50048
  int*   gstart = cursor + 50048;           // 1024
  int*   bsum   = gstart + 1024;            // 256
  int*   bbase  = bsum + 256;               // 256
  unsigned short* w2 = (unsigned short*)(bbase + 256);  // 3*16384, pre-swizzled hi
  unsigned short* hb = w2 + 3 * FD * FD;    // NN*FD bf16 gemm output

  dim3 B(256);
  const int gGemm = (NN / 16 + 3) / 4;   // 782 blocks, 1 rt/wave
  const int gAgg  = NN / 16;             // 3125

  k_zero<<<53, B, 0, stream>>>((float4*)ws);
  k_deg_scatter<<<GRID_E8, B, 0, stream>>>(dstI, deg);
  k_bsum<<<NB, B, 0, stream>>>(deg, bsum);
  k_bscan<<<1, B, 0, stream>>>(bsum, bbase);
  k_rowoff_cvt<<<NB + 48 + 3, B, 0, stream>>>(deg, bbase, row_off, cursor,
                                              W1, W2, W3, w2, batch, gstart);
  k_fill<<<GRID_E8, B, 0, stream>>>(srcI, dstI, deg, cursor, csr);

  // layer 1
  k_gemm<0><<<gGemm, B, 0, stream>>>(x, nullptr, w2, hb);
  k_agg<1><<<gAgg, B, 0, stream>>>(hb, deg, b1, row_off, csr, bufB, bnA);

  // layer 2 (BN+ReLU+musc-reduce fused into GEMM)
  k_gemm<1><<<gGemm, B, 0, stream>>>(bufB, bnA, w2 + FD * FD, hb);
  k_agg<1><<<gAgg, B, 0, stream>>>(hb, deg, b2, row_off, csr, bufB, bnB);

  // layer 3
  k_gemm<1><<<gGemm, B, 0, stream>>>(bufB, bnB, w2 + 2 * FD * FD, hb);
  k_agg<0><<<gAgg, B, 0, stream>>>(hb, deg, b3, row_off, csr, bufB, nullptr);

  // pool + head
  k_poolfinal<<<NG, 512, 0, stream>>>(bufB, gstart, Wlin, blin, out);
}